// Round 11
// baseline (452.637 us; speedup 1.0000x reference)
//
#include <hip/hip_runtime.h>

// ---------------------------------------------------------------------------
// GraphMambaConv: N=32768 nodes, C=128, G=64 graphs x L=512, E=524288 edges,
// D_INNER=256, D_STATE=16, DT_RANK=8, D_CONV=4.
//
// Round 11:
//  - k_scan: grid-shape fix. 2048 blocks x 128 thr (16 d/block) -> ~7
//    blocks/CU = ~4 waves/SIMD (was 2). Same per-lane math; TLP doubles to
//    hide the exp->fma recurrence latency.
//  - gather in bf16: x16 = bf16(x) (one pass), gather reads x16, writes
//    agg16; h1/xz GEMMs copy-stage x16/agg16 (numerically identical to the
//    old cvt-staging).
//  - h1p/p2 stored bf16 (OBF GEMM out; k_add reads bf16).
// ---------------------------------------------------------------------------

#define NROWS 32768
#define CDIM  128
#define EDGES 524288
#define GL    512
#define SCH   32          // scan chunk (timesteps)
#define NCH   (GL / SCH)  // 16 chunks

typedef short s16x8 __attribute__((ext_vector_type(8)));
typedef float f32x4 __attribute__((ext_vector_type(4)));

__device__ __forceinline__ unsigned short f2bf(float f)
{
    unsigned u = __float_as_uint(f);
    u += 0x7FFF + ((u >> 16) & 1);          // RNE
    return (unsigned short)(u >> 16);
}

__device__ __forceinline__ float bf2f(unsigned short u)
{
    return __uint_as_float((unsigned)u << 16);
}

__device__ __forceinline__ unsigned cvt_pk_bf16(float lo, float hi)
{
    unsigned r;
    asm("v_cvt_pk_bf16_f32 %0, %1, %2" : "=v"(r) : "v"(lo), "v"(hi));
    return r;
}

__device__ __forceinline__ float exp2_fast(float x)
{
    float r;
    asm("v_exp_f32 %0, %1" : "=v"(r) : "v"(x));   // v_exp_f32 computes 2^x
    return r;
}

// ------------------------- CSR build: histogram ----------------------------
__global__ __launch_bounds__(256) void k_hist(const int* __restrict__ ei,
                                              int* __restrict__ deg)
{
    const int e = blockIdx.x * 1024 + threadIdx.x * 4;
    const int4 d4 = *(const int4*)&ei[EDGES + e];
    atomicAdd(&deg[d4.x], 1);
    atomicAdd(&deg[d4.y], 1);
    atomicAdd(&deg[d4.z], 1);
    atomicAdd(&deg[d4.w], 1);
}

// ---------------- CSR build: exclusive prefix scan (1 block) ---------------
__global__ __launch_bounds__(1024) void k_scanidx(const int* __restrict__ deg,
                                                  int* __restrict__ base,
                                                  int* __restrict__ cursor)
{
    __shared__ int ps[1024];
    const int tid = threadIdx.x;
    int loc[32];
    int s = 0;
#pragma unroll
    for (int i = 0; i < 32; ++i) { loc[i] = deg[tid * 32 + i]; s += loc[i]; }
    ps[tid] = s;
    __syncthreads();
    for (int off = 1; off < 1024; off <<= 1) {
        int v = (tid >= off) ? ps[tid - off] : 0;
        __syncthreads();
        ps[tid] += v;
        __syncthreads();
    }
    int run = tid ? ps[tid - 1] : 0;
#pragma unroll
    for (int i = 0; i < 32; ++i) {
        base[tid * 32 + i] = run;
        cursor[tid * 32 + i] = run;
        run += loc[i];
    }
    if (tid == 0) base[32768] = EDGES;
}

// ------------------------- CSR build: fill src lists -----------------------
__global__ __launch_bounds__(256) void k_fill(const int* __restrict__ ei,
                                              int* __restrict__ cursor,
                                              int* __restrict__ srcs)
{
    const int e = blockIdx.x * 1024 + threadIdx.x * 4;
    const int4 s4 = *(const int4*)&ei[e];
    const int4 d4 = *(const int4*)&ei[EDGES + e];
    int p;
    p = atomicAdd(&cursor[d4.x], 1); srcs[p] = s4.x;
    p = atomicAdd(&cursor[d4.y], 1); srcs[p] = s4.y;
    p = atomicAdd(&cursor[d4.z], 1); srcs[p] = s4.z;
    p = atomicAdd(&cursor[d4.w], 1); srcs[p] = s4.w;
}

// ------------------- x -> bf16 (one pass, 8 elems/thread) ------------------
__global__ __launch_bounds__(256) void k_prepx(const float* __restrict__ x,
                                               unsigned short* __restrict__ x16)
{
    const size_t i = ((size_t)blockIdx.x * 256 + threadIdx.x) * 8;
    float4 a = *(const float4*)&x[i];
    float4 b = *(const float4*)&x[i + 4];
    uint4 p;
    p.x = cvt_pk_bf16(a.x, a.y); p.y = cvt_pk_bf16(a.z, a.w);
    p.z = cvt_pk_bf16(b.x, b.y); p.w = cvt_pk_bf16(b.z, b.w);
    *(uint4*)&x16[i] = p;
}

// ---------------- gather (bf16 in/out, fp32 accumulate) --------------------
__global__ __launch_bounds__(256) void k_gather(const unsigned short* __restrict__ x16,
                                                const int* __restrict__ base,
                                                const int* __restrict__ srcs,
                                                unsigned short* __restrict__ agg16)
{
    const int node = blockIdx.x * 4 + (threadIdx.x >> 6);
    const int lane = threadIdx.x & 63;
    const int b0 = base[node], b1 = base[node + 1];
    float a0 = 0.f, a1 = 0.f;
    for (int i = b0; i < b1; ++i) {
        const int s = srcs[i];
        const unsigned v = *(const unsigned*)&x16[(size_t)s * 128 + lane * 2];
        a0 += bf2f((unsigned short)(v & 0xFFFF));
        a1 += bf2f((unsigned short)(v >> 16));
    }
    *(unsigned*)&agg16[(size_t)node * 128 + lane * 2] = cvt_pk_bf16(a0, a1);
}

// ---- merged weight prep: 5 transposes (bf16) in one launch, 552 blocks ----
__global__ __launch_bounds__(256) void k_prepw5(
    const float* __restrict__ Wa, unsigned short* __restrict__ Ta,
    const float* __restrict__ Wb, unsigned short* __restrict__ Tb,
    const float* __restrict__ Wc, unsigned short* __restrict__ Tc,
    const float* __restrict__ Wd, unsigned short* __restrict__ Td,
    const float* __restrict__ We, unsigned short* __restrict__ Te)
{
    const int idx = blockIdx.x * 256 + threadIdx.x;
    const float* W; unsigned short* T; int rel, ks, N;
    if (idx < 16384)       { W = Wa; T = Ta; rel = idx;          ks = 7; N = 128; }
    else if (idx < 32768)  { W = Wb; T = Tb; rel = idx - 16384;  ks = 7; N = 128; }
    else if (idx < 98304)  { W = Wc; T = Tc; rel = idx - 32768;  ks = 7; N = 512; }
    else if (idx < 108544) { W = Wd; T = Td; rel = idx - 98304;  ks = 8; N = 40;  }
    else                   { W = We; T = Te; rel = idx - 108544; ks = 8; N = 128; }
    const int K = 1 << ks;
    const int n = rel >> ks, k = rel & (K - 1);
    T[rel] = f2bf(W[(size_t)k * N + n]);
}

// ------------------------- MFMA GEMM (bf16 in, fp32 acc) --------------------
// out = epi( A0@W0 [+ A1@W1] [+bias] [+resid] ), optional column stats.
// A: MxK row-major, fp32 (ABF=0, cvt-staged) or bf16 (ABF=1, copy-staged).
// WT: NxK bf16 row-major. Out fp32 (OBF=0) or bf16 (OBF=1); stats/resid fp32.
// Tile 64x64, BK=64, 4 waves x (2x2 mfma_f32_16x16x32_bf16).
template<bool DUAL, int ACT, bool STAT, bool ABF, bool OBF>
__global__ __launch_bounds__(256)
void gemm_mfma(const void* __restrict__ A0, const unsigned short* __restrict__ W0T,
               const void* __restrict__ A1p, const unsigned short* __restrict__ W1Tp,
               int M, int N, int K, int ldo,
               const float* __restrict__ bias,
               const float* __restrict__ resid, int ldr,
               void* __restrict__ outp,
               float* __restrict__ sumP, float* __restrict__ sqP)
{
    __shared__ __align__(16) unsigned short As[64 * 72];  // [m][k], pad 8
    __shared__ __align__(16) unsigned short Bs[64 * 72];  // [n][k], pad 8
    __shared__ float sB[2][64];

    const int tid = threadIdx.x;
    const int m0 = blockIdx.x * 64;
    const int n0 = blockIdx.y * 64;

    const int sr = tid >> 2;             // staging row 0..63
    const int sk = (tid & 3) * 16;       // staging k base

    const int w  = tid >> 6, l = tid & 63;
    const int wr = (w >> 1) * 32, wc = (w & 1) * 32;
    const int fr = l & 15;               // frag row/col
    const int fk = (l >> 4) * 8;         // frag k base

    f32x4 acc[2][2];
#pragma unroll
    for (int i = 0; i < 2; ++i)
#pragma unroll
        for (int j = 0; j < 2; ++j) acc[i][j] = (f32x4){0.f, 0.f, 0.f, 0.f};

    const int npass = DUAL ? 2 : 1;
    for (int pass = 0; pass < npass; ++pass) {
        const void* A = (DUAL && pass) ? A1p : A0;
        const unsigned short* WT = (DUAL && pass) ? W1Tp : W0T;
        for (int k0 = 0; k0 < K; k0 += 64) {
            if (ABF) {   // stage A: straight bf16 copy
                const unsigned short* ap =
                    (const unsigned short*)A + (size_t)(m0 + sr) * K + k0 + sk;
                *(uint4*)&As[sr * 72 + sk]     = *(const uint4*)(ap);
                *(uint4*)&As[sr * 72 + sk + 8] = *(const uint4*)(ap + 8);
            } else {     // stage A: fp32 -> bf16 via v_cvt_pk_bf16_f32
                const float* ap = (const float*)A + (size_t)(m0 + sr) * K + k0 + sk;
                float4 v0 = *(const float4*)(ap);
                float4 v1 = *(const float4*)(ap + 4);
                float4 v2 = *(const float4*)(ap + 8);
                float4 v3 = *(const float4*)(ap + 12);
                uint4 pa, pb;
                pa.x = cvt_pk_bf16(v0.x, v0.y); pa.y = cvt_pk_bf16(v0.z, v0.w);
                pa.z = cvt_pk_bf16(v1.x, v1.y); pa.w = cvt_pk_bf16(v1.z, v1.w);
                pb.x = cvt_pk_bf16(v2.x, v2.y); pb.y = cvt_pk_bf16(v2.z, v2.w);
                pb.z = cvt_pk_bf16(v3.x, v3.y); pb.w = cvt_pk_bf16(v3.z, v3.w);
                *(uint4*)&As[sr * 72 + sk]     = pa;
                *(uint4*)&As[sr * 72 + sk + 8] = pb;
            }
            {   // stage B: straight bf16 copy from WT (zero-fill n >= N)
                const int nn = n0 + sr;
                if (nn < N) {
                    const unsigned short* wp = WT + (size_t)nn * K + k0 + sk;
                    uint4 w0 = *(const uint4*)(wp);
                    uint4 w1 = *(const uint4*)(wp + 8);
                    *(uint4*)&Bs[sr * 72 + sk]     = w0;
                    *(uint4*)&Bs[sr * 72 + sk + 8] = w1;
                } else {
                    uint4 z = make_uint4(0, 0, 0, 0);
                    *(uint4*)&Bs[sr * 72 + sk]     = z;
                    *(uint4*)&Bs[sr * 72 + sk + 8] = z;
                }
            }
            __syncthreads();
#pragma unroll
            for (int ks = 0; ks < 2; ++ks) {
                s16x8 a0 = *(const s16x8*)&As[(wr + fr     ) * 72 + ks * 32 + fk];
                s16x8 a1 = *(const s16x8*)&As[(wr + 16 + fr) * 72 + ks * 32 + fk];
                s16x8 b0 = *(const s16x8*)&Bs[(wc + fr     ) * 72 + ks * 32 + fk];
                s16x8 b1 = *(const s16x8*)&Bs[(wc + 16 + fr) * 72 + ks * 32 + fk];
                acc[0][0] = __builtin_amdgcn_mfma_f32_16x16x32_bf16(a0, b0, acc[0][0], 0, 0, 0);
                acc[0][1] = __builtin_amdgcn_mfma_f32_16x16x32_bf16(a0, b1, acc[0][1], 0, 0, 0);
                acc[1][0] = __builtin_amdgcn_mfma_f32_16x16x32_bf16(a1, b0, acc[1][0], 0, 0, 0);
                acc[1][1] = __builtin_amdgcn_mfma_f32_16x16x32_bf16(a1, b1, acc[1][1], 0, 0, 0);
            }
            __syncthreads();
        }
    }

    // ---- epilogue: C/D layout col=lane&15, row=(lane>>4)*4+reg ----
    const int orow = (l >> 4) * 4;
    float cs[2] = {0.f, 0.f}, cq[2] = {0.f, 0.f};
#pragma unroll
    for (int mt = 0; mt < 2; ++mt) {
#pragma unroll
        for (int nt = 0; nt < 2; ++nt) {
            const int cg = n0 + wc + nt * 16 + fr;
            if (cg < N) {
                const float bv = bias ? bias[cg] : 0.f;
#pragma unroll
                for (int r = 0; r < 4; ++r) {
                    const int rg = m0 + wr + mt * 16 + orow + r;
                    float v = acc[mt][nt][r] + bv;
                    if (resid) v += resid[(size_t)rg * ldr + cg];
                    if (ACT == 1)
                        v = 0.5f * v * (1.f + erff(v * 0.7071067811865475f));
                    if (OBF)
                        ((unsigned short*)outp)[(size_t)rg * ldo + cg] = f2bf(v);
                    else
                        ((float*)outp)[(size_t)rg * ldo + cg] = v;
                    if (STAT) { cs[nt] += v; cq[nt] += v * v; }
                }
            }
        }
    }
    if (STAT) {
        if (tid < 64) { sB[0][tid] = 0.f; sB[1][tid] = 0.f; }
        __syncthreads();
#pragma unroll
        for (int nt = 0; nt < 2; ++nt) {
            atomicAdd(&sB[0][wc + nt * 16 + fr], cs[nt]);
            atomicAdd(&sB[1][wc + nt * 16 + fr], cq[nt]);
        }
        __syncthreads();
        if (tid < 64 && (n0 + tid) < N) {
            atomicAdd(&sumP[n0 + tid], sB[0][tid]);
            atomicAdd(&sqP[n0 + tid],  sB[1][tid]);
        }
    }
}

// --------------------- causal conv + SiLU (bf16 in/out) --------------------
__global__ __launch_bounds__(256) void k_conv(const unsigned short* __restrict__ xz,
                                              const float* __restrict__ cw,
                                              const float* __restrict__ cb,
                                              unsigned short* __restrict__ xc)
{
    const int r = blockIdx.x;        // global row
    const int l = r & (GL - 1);      // position within graph
    const int d = threadIdx.x;       // 0..255
    float4 w4 = *(const float4*)&cw[d * 4];
    const float taps[4] = {w4.x, w4.y, w4.z, w4.w};
    float acc = cb[d];
#pragma unroll
    for (int k = 0; k < 4; ++k) {
        int ll = l - 3 + k;
        if (ll >= 0) acc += bf2f(xz[(size_t)(r - 3 + k) * 512 + d]) * taps[k];
    }
    float s = 1.f / (1.f + __expf(-acc));
    xc[(size_t)r * 256 + d] = f2bf(acc * s);
}

// ---------------- dt = softplus(proj[:,:8] @ dt_W + dt_b); B,C slices ------
__global__ __launch_bounds__(256) void k_dtbc(const float* __restrict__ proj,
                                              const float* __restrict__ dt_W,
                                              const float* __restrict__ dt_b,
                                              unsigned short* __restrict__ dtb,
                                              float* __restrict__ Bc,
                                              float* __restrict__ Cc)
{
    __shared__ float dtWS[8 * 256];
    __shared__ float dt_bS[256];
    __shared__ float projS[32 * 8];
    const int tid = threadIdx.x;
    const int r0 = blockIdx.x * 32;
    for (int i = tid; i < 2048; i += 256) dtWS[i] = dt_W[i];
    dt_bS[tid] = dt_b[tid];
    projS[tid] = proj[(size_t)(r0 + (tid >> 3)) * 40 + (tid & 7)];
    __syncthreads();

    const int c = tid;
    for (int rr = 0; rr < 32; ++rr) {
        float acc = dt_bS[c];
        const float* pr = &projS[rr * 8];
#pragma unroll
        for (int q = 0; q < 8; ++q) acc += pr[q] * dtWS[q * 256 + c];
        float e  = exp2_fast(-fabsf(acc) * 1.4426950408f);
        float sp = fmaxf(acc, 0.f) + 0.6931471806f * __log2f(1.f + e);
        dtb[(size_t)(r0 + rr) * 256 + c] = f2bf(sp);
    }
    // B = proj[:, 8:24], C = proj[:, 24:40]
    for (int e2 = tid; e2 < 1024; e2 += 256) {
        int rr = e2 >> 5, cc = e2 & 31;
        float v = proj[(size_t)(r0 + rr) * 40 + 8 + cc];
        if (cc < 16) Bc[(size_t)(r0 + rr) * 16 + cc] = v;
        else         Cc[(size_t)(r0 + rr) * 16 + cc - 16] = v;
    }
}

// ---------------- 8-lane-group sum via DPP (zero DS-pipe ops) ---------------
__device__ __forceinline__ float dpp_add8(float x)
{
    float y = x;
    int t;
    t = __builtin_amdgcn_update_dpp(0, __float_as_int(y), 0xB1, 0xF, 0xF, true);
    y += __int_as_float(t);
    t = __builtin_amdgcn_update_dpp(0, __float_as_int(y), 0x4E, 0xF, 0xF, true);
    y += __int_as_float(t);
    t = __builtin_amdgcn_update_dpp(0, __float_as_int(y), 0x141, 0xF, 0xF, true);
    y += __int_as_float(t);
    return y;
}

// ------------------------------ selective scan -----------------------------
// Block = (g, dblk16): 16 d x 16 states = 128 thr (2 waves); 2048 blocks ->
// ~7 blocks/CU = ~4 waves/SIMD (2x the TLP of the 512-block version; the
// exp->fma recurrence chain is latency-bound and needs the extra waves).
// Wave = 8 d x 8 sp-lanes; lane holds states {2sp, 2sp+1} in registers.
// LDS (fp32, converted at stage time), double-buffered, strides 36
// (conflict-free / 2-way on b128): dtT[16][36] | xcT[16][36] | BT[16][36] |
// CT[16][36]; ygL[32][20]. Global dt/xc/z/yg are bf16.
// NOTE: yg aliases dtb - chunk c+1's dtb rows are prefetched to regs before
// chunk c's yg writeout; blocks touch disjoint (g, d-slice) columns.
__global__ __launch_bounds__(128) void k_scan(
    const unsigned short* __restrict__ dtb,
    const unsigned short* __restrict__ xcb,
    const unsigned short* __restrict__ xzb,
    const float* __restrict__ Bb, const float* __restrict__ Cb,
    const float* __restrict__ A_log, const float* __restrict__ Dp,
    unsigned short* __restrict__ yg)
{
    // floats: buf0 [0,2304) | buf1 [2304,4608) | ygL [4608, 4608+32*20)
    __shared__ __align__(16) float lds[2 * 2304 + 32 * 20];

    const int g    = blockIdx.x >> 5;
    const int dblk = blockIdx.x & 31;
    const int tid  = threadIdx.x;
    const int lane = tid & 63;
    const int dl   = (tid >> 6) * 8 + (lane >> 3);   // local d 0..15
    const int sp   = lane & 7;                       // state-pair index
    const int d0   = dblk * 16;
    const int d    = d0 + dl;
    const size_t rbase = (size_t)g * GL;

    // staging coords
    const int sdd = tid & 15, stq = tid >> 4;        // dt/xc/B/C: col, t-quad
    const int szt = tid >> 2, szi = tid & 3;         // z / writeout

    const float L2E = 1.44269504088896f;
    const float aA0 = -__expf(A_log[d * 16 + 2 * sp]) * L2E;
    const float aA1 = -__expf(A_log[d * 16 + 2 * sp + 1]) * L2E;
    const float Dpd = Dp[d];
    float h0 = 0.f, h1 = 0.f;

    float rdt[4], rxc[4], rB[4], rC[4];
    ushort4 rz, zcur;

    // ---- prologue: load chunk 0 into registers ----
    {
        const size_t r0 = rbase;
#pragma unroll
        for (int j = 0; j < 4; ++j) {
            const size_t row = r0 + stq * 4 + j;
            rdt[j] = bf2f(dtb[row * 256 + d0 + sdd]);
            rxc[j] = bf2f(xcb[row * 256 + d0 + sdd]);
            rB[j]  = Bb[row * 16 + sdd];
            rC[j]  = Cb[row * 16 + sdd];
        }
        rz = *(const ushort4*)&xzb[(r0 + szt) * 512 + 256 + d0 + szi * 4];
    }
    zcur = rz;

    float* ygL = lds + 2 * 2304;

    for (int c = 0; c < NCH; ++c) {
        float* buf = lds + (c & 1) * 2304;
        // ---- commit staged registers to LDS (transposed fp32 tiles) ----
        *(float4*)&buf[sdd * 36 + stq * 4] =
            make_float4(rdt[0], rdt[1], rdt[2], rdt[3]);
        *(float4*)&buf[576 + sdd * 36 + stq * 4] =
            make_float4(rxc[0], rxc[1], rxc[2], rxc[3]);
        *(float4*)&buf[1152 + sdd * 36 + stq * 4] =
            make_float4(rB[0], rB[1], rB[2], rB[3]);
        *(float4*)&buf[1728 + sdd * 36 + stq * 4] =
            make_float4(rC[0], rC[1], rC[2], rC[3]);
        zcur = rz;
        __syncthreads();

        // ---- prefetch chunk c+1 (lands during the 32 steps below) ----
        if (c + 1 < NCH) {
            const size_t r0 = rbase + (size_t)(c + 1) * SCH;
#pragma unroll
            for (int j = 0; j < 4; ++j) {
                const size_t row = r0 + stq * 4 + j;
                rdt[j] = bf2f(dtb[row * 256 + d0 + sdd]);
                rxc[j] = bf2f(xcb[row * 256 + d0 + sdd]);
                rB[j]  = Bb[row * 16 + sdd];
                rC[j]  = Cb[row * 16 + sdd];
            }
            rz = *(const ushort4*)&xzb[(r0 + szt) * 512 + 256 + d0 + szi * 4];
        }

        // ---- 32 scan steps from LDS ----
        const float* pdt = buf + dl * 36;
        const float* pxc = buf + 576 + dl * 36;
        const float* pB0 = buf + 1152 + (2 * sp) * 36;
        const float* pB1 = buf + 1152 + (2 * sp + 1) * 36;
        const float* pC0 = buf + 1728 + (2 * sp) * 36;
        const float* pC1 = buf + 1728 + (2 * sp + 1) * 36;
        float yk[4] = {0.f, 0.f, 0.f, 0.f};
#pragma unroll
        for (int t4 = 0; t4 < 8; ++t4) {
            const float4 dt4 = *(const float4*)&pdt[t4 * 4];
            const float4 xc4 = *(const float4*)&pxc[t4 * 4];
            const float4 B04 = *(const float4*)&pB0[t4 * 4];
            const float4 B14 = *(const float4*)&pB1[t4 * 4];
            const float4 C04 = *(const float4*)&pC0[t4 * 4];
            const float4 C14 = *(const float4*)&pC1[t4 * 4];
#define SSTEP(J)                                                            \
            {                                                               \
                const float dt = ((const float*)&dt4)[J];                   \
                const float xc = ((const float*)&xc4)[J];                   \
                const float dtx = dt * xc;                                  \
                h0 = h0 * exp2_fast(dt * aA0) + dtx * ((const float*)&B04)[J]; \
                h1 = h1 * exp2_fast(dt * aA1) + dtx * ((const float*)&B14)[J]; \
                float yv = h0 * ((const float*)&C04)[J]                     \
                         + h1 * ((const float*)&C14)[J];                    \
                yv = dpp_add8(yv);                                          \
                yv = fmaf(xc, Dpd, yv);                                     \
                const int tt = t4 * 4 + (J);                                \
                yk[t4 >> 1] = (sp == (tt & 7)) ? yv : yk[t4 >> 1];          \
            }
            SSTEP(0) SSTEP(1) SSTEP(2) SSTEP(3)
#undef SSTEP
        }
        // stage captured y to LDS: lane sp holds t = 8k+sp for its d
#pragma unroll
        for (int k = 0; k < 4; ++k)
            ygL[(k * 8 + sp) * 20 + dl] = yk[k];
        __syncthreads();

        // ---- coalesced bf16 writeout with silu(z) from registers ----
        {
            const size_t rr0 = rbase + (size_t)c * SCH;
            float4 y4 = *(const float4*)&ygL[szt * 20 + szi * 4];
            float z0 = bf2f(zcur.x), z1 = bf2f(zcur.y);
            float z2 = bf2f(zcur.z), z3 = bf2f(zcur.w);
            float o0 = y4.x * (z0 / (1.f + __expf(-z0)));
            float o1 = y4.y * (z1 / (1.f + __expf(-z1)));
            float o2 = y4.z * (z2 / (1.f + __expf(-z2)));
            float o3 = y4.w * (z3 / (1.f + __expf(-z3)));
            uint2 packed;
            packed.x = cvt_pk_bf16(o0, o1);
            packed.y = cvt_pk_bf16(o2, o3);
            *(uint2*)&yg[(rr0 + szt) * 256 + d0 + szi * 4] = packed;
        }
    }
}

// ------- add + BN1/BN2 (params per-thread; bf16 h1p/p2 inputs) -------------
__global__ __launch_bounds__(256) void k_add(const unsigned short* __restrict__ h1p,
                                             const unsigned short* __restrict__ p2,
                                             const float* __restrict__ st,
                                             const float* __restrict__ g1,
                                             const float* __restrict__ be1,
                                             const float* __restrict__ g2,
                                             const float* __restrict__ be2,
                                             float* __restrict__ outp,
                                             float* __restrict__ sumP,
                                             float* __restrict__ sqP)
{
    const int c = threadIdx.x & 127, half = threadIdx.x >> 7;
    const float inv = 1.f / 32768.f;
    const float m1 = st[c] * inv, v1 = st[128 + c] * inv - m1 * m1;
    const float a1 = g1[c] * rsqrtf(v1 + 1e-5f), b1 = be1[c] - m1 * a1;
    const float m2 = st[256 + c] * inv, v2 = st[384 + c] * inv - m2 * m2;
    const float a2 = g2[c] * rsqrtf(v2 + 1e-5f), b2 = be2[c] - m2 * a2;

    const int rbase = blockIdx.x * 64 + half * 32;
    float s = 0.f, q = 0.f;
    for (int i = 0; i < 32; ++i) {
        size_t idx = (size_t)(rbase + i) * 128 + c;
        float v = bf2f(h1p[idx]) * a1 + b1 + bf2f(p2[idx]) * a2 + b2;
        outp[idx] = v; s += v; q += v * v;
    }
    __shared__ float sh[2][2][128];
    sh[0][half][c] = s; sh[1][half][c] = q;
    __syncthreads();
    if (threadIdx.x < 128) {
        atomicAdd(&sumP[c], sh[0][0][c] + sh[0][1][c]);
        atomicAdd(&sqP[c],  sh[1][0][c] + sh[1][1][c]);
    }
}

// ---- fold1: block-per-column; W1eT bf16 [256][128] + b1e fp32 -------------
__global__ __launch_bounds__(128) void k_fold1(
    const float* __restrict__ sumP, const float* __restrict__ sqP,
    const float* __restrict__ gam, const float* __restrict__ bet,
    const float* __restrict__ W1, const float* __restrict__ b1in,
    unsigned short* __restrict__ W1eT, float* __restrict__ b1e)
{
    __shared__ float red[128];
    const int n = blockIdx.x, k = threadIdx.x;
    const float inv = 1.f / 32768.f;
    const float m = sumP[k] * inv, v = sqP[k] * inv - m * m;
    const float a = gam[k] * rsqrtf(v + 1e-5f), bs = bet[k] - m * a;
    const float wv = W1[k * 256 + n];
    W1eT[n * 128 + k] = f2bf(a * wv);
    red[k] = bs * wv;
    __syncthreads();
    for (int s = 64; s > 0; s >>= 1) {
        if (k < s) red[k] += red[k + s];
        __syncthreads();
    }
    if (k == 0) b1e[n] = red[0] + b1in[n];
}

// ---- fold2: block-per-column; W2eT bf16 [128][256] + b2e fp32 -------------
__global__ __launch_bounds__(256) void k_fold2(
    const float* __restrict__ sumP, const float* __restrict__ sqP,
    const float* __restrict__ gam, const float* __restrict__ bet,
    const float* __restrict__ W2, const float* __restrict__ b2in,
    unsigned short* __restrict__ W2eT, float* __restrict__ b2e)
{
    __shared__ float red[256];
    const int n = blockIdx.x, k = threadIdx.x;
    const float inv = 1.f / 32768.f;
    const float m = sumP[k] * inv, v = sqP[k] * inv - m * m;
    const float a = gam[k] * rsqrtf(v + 1e-5f), bs = bet[k] - m * a;
    const float wv = W2[k * 128 + n];
    W2eT[n * 256 + k] = f2bf(a * wv);
    red[k] = bs * wv;
    __syncthreads();
    for (int s = 128; s > 0; s >>= 1) {
        if (k < s) red[k] += red[k + s];
        __syncthreads();
    }
    if (k == 0) b2e[n] = red[0] + b2in[n];
}

// ---------------- BN3 (params computed per-thread, amortized) ---------------
__global__ __launch_bounds__(256) void k_bn3(const float* __restrict__ out2,
                                             const float* __restrict__ sumP,
                                             const float* __restrict__ sqP,
                                             const float* __restrict__ gam,
                                             const float* __restrict__ bet,
                                             float* __restrict__ dout)
{
    const int cq = (threadIdx.x & 31) * 4;     // column quad
    const int rw = threadIdx.x >> 5;           // 0..7
    const float inv = 1.f / 32768.f;
    float a[4], b[4];
#pragma unroll
    for (int j = 0; j < 4; ++j) {
        float m = sumP[cq + j] * inv, v = sqP[cq + j] * inv - m * m;
        a[j] = gam[cq + j] * rsqrtf(v + 1e-5f);
        b[j] = bet[cq + j] - m * a[j];
    }
    const int r0 = blockIdx.x * 128 + rw;
#pragma unroll 4
    for (int k = 0; k < 16; ++k) {
        const size_t r = r0 + k * 8;
        float4 v = *(const float4*)&out2[r * 128 + cq];
        v.x = v.x * a[0] + b[0]; v.y = v.y * a[1] + b[1];
        v.z = v.z * a[2] + b[2]; v.w = v.w * a[3] + b[3];
        *(float4*)&dout[r * 128 + cq] = v;
    }
}

// ------------------------------- launch ------------------------------------
extern "C" void kernel_launch(void* const* d_in, const int* in_sizes, int n_in,
                              void* d_out, int out_size, void* d_ws, size_t ws_size,
                              hipStream_t stream)
{
    (void)in_sizes; (void)n_in; (void)out_size; (void)ws_size;
    const float* x      = (const float*)d_in[0];
    const int*   ei     = (const int*)d_in[1];
    // d_in[2] = batch (unused: equal-size sorted graphs == reshape)
    const float* W_root = (const float*)d_in[3];
    const float* W_rel  = (const float*)d_in[4];
    const float* b_rel  = (const float*)d_in[5];
    const float* n1_g = (const float*)d_in[6],  *n1_b = (const float*)d_in[7];
    const float* n2_g = (const float*)d_in[8],  *n2_b = (const float*)d_in[9];
    const float* n3_g = (const float*)d_in[10], *n3_b = (const float*)d_in[11];
    const float* m1_g = (const float*)d_in[12], *m1_b = (const float*)d_in[13];
    const float* W1   = (const float*)d_in[14], *b1   = (const float*)d_in[15];
    const float* m2_g = (const float*)d_in[16], *m2_b = (const float*)d_in[17];
    const float* W2   = (const float*)d_in[18], *b2   = (const float*)d_in[19];
    const float* in_W   = (const float*)d_in[20];
    const float* conv_w = (const float*)d_in[21], *conv_b = (const float*)d_in[22];
    const float* xproj_W= (const float*)d_in[23];
    const float* dt_W   = (const float*)d_in[24], *dt_b = (const float*)d_in[25];
    const float* A_log  = (const float*)d_in[26], *Dp   = (const float*)d_in[27];
    const float* out_W  = (const float*)d_in[28];

    float* ws = (float*)d_ws;
    // small region
    float* st  = ws;             // 2048 used (S1..S5 sums/sumsqs)
    float* b1e = ws + 8192;      // 256
    float* b2e = ws + 8448;      // 128
    // bf16 transposed weights (shorts)
    unsigned short* wsh   = (unsigned short*)(ws + 8704);
    unsigned short* WrelT  = wsh;            // 128x128 = 16384
    unsigned short* WrootT = wsh + 16384;    // 16384
    unsigned short* inWT   = wsh + 32768;    // 512x128 = 65536
    unsigned short* xprojT = wsh + 98304;    // 40x256  = 10240
    unsigned short* outWT  = wsh + 108544;   // 128x256 = 32768
    unsigned short* W1eT   = wsh + 141312;   // 256x128 = 32768
    unsigned short* W2eT   = wsh + 174080;   // 128x256 = 32768 (end 206848)
    // big buffers (float-unit offsets; bf16 buffers occupy half the floats)
    float* big = ws + 112640;
    unsigned short* agg16 = (unsigned short*)(big);             // 4.19M sh
    unsigned short* p216  = agg16;                              // reuse
    unsigned short* h1p16 = (unsigned short*)(big + 2097152);   // 4.19M sh
    unsigned short* x16   = (unsigned short*)(big + 4194304);   // 4.19M sh
    unsigned short* xz16  = (unsigned short*)(big + 6291456);   // 16.78M sh
    unsigned short* xc16  = (unsigned short*)(big + 14680064);  // 8.39M sh
    float* proj = big + 18874368;                               // 1.31M f
    unsigned short* dtb16 = (unsigned short*)(big + 20185088);  // 8.39M sh (yg alias)
    unsigned short* yg16  = dtb16;
    float* Bc   = big + 24379392;                               // 524288
    float* Cc   = big + 24903680;                               // 524288
    float* outb = big + 25427968;                               // fp32 4.19M
    float* out2 = big + 29622272;                               // fp32 4.19M
    unsigned short* g16   = (unsigned short*)(big + 33816576);  // 8.39M sh

    // CSR scratch lives in the h1p16 region (dead until the h1 GEMM writes it)
    int* ideg   = (int*)h1p16;            // 32768
    int* ibase  = ideg + 32768;           // 32769
    int* icur   = ideg + 65552;           // 32768 (16B-aligned)
    int* isrcs  = ideg + 98320;           // 524288

    hipMemsetAsync(st, 0, 2048 * sizeof(float), stream);
    hipMemsetAsync(ideg, 0, 32768 * sizeof(int), stream);

    // ---- preps: weights (bf16 transposes) + x -> bf16 ----
    k_prepw5<<<552, 256, 0, stream>>>(W_rel, WrelT, W_root, WrootT,
                                      in_W, inWT, xproj_W, xprojT,
                                      out_W, outWT);
    k_prepx<<<2048, 256, 0, stream>>>(x, x16);

    // ---- CSR build + gather (bf16) ----
    k_hist<<<512, 256, 0, stream>>>(ei, ideg);
    k_scanidx<<<1, 1024, 0, stream>>>(ideg, ibase, icur);
    k_fill<<<512, 256, 0, stream>>>(ei, icur, isrcs);
    k_gather<<<8192, 256, 0, stream>>>(x16, ibase, isrcs, agg16);

    // h1_pre = agg@W_rel + b_rel + x@W_root + x  [S1]  (bf16 A, bf16 out)
    gemm_mfma<true, 0, true, true, true><<<dim3(512, 2), 256, 0, stream>>>(
        agg16, WrelT, x16, WrootT, NROWS, 128, 128, 128,
        b_rel, x, 128, h1p16, st + 0, st + 128);
    // xz = x @ in_W  (bf16 A, bf16 out)
    gemm_mfma<false, 0, false, true, true><<<dim3(512, 8), 256, 0, stream>>>(
        x16, inWT, nullptr, nullptr, NROWS, 512, 128, 512,
        nullptr, nullptr, 0, xz16, nullptr, nullptr);
    k_conv<<<32768, 256, 0, stream>>>(xz16, conv_w, conv_b, xc16);
    // proj = xc @ xproj_W (bf16 A, fp32 out, N=40)
    gemm_mfma<false, 0, false, true, false><<<dim3(512, 1), 256, 0, stream>>>(
        xc16, xprojT, nullptr, nullptr, NROWS, 40, 256, 40,
        nullptr, nullptr, 0, proj, nullptr, nullptr);
    k_dtbc<<<1024, 256, 0, stream>>>(proj, dt_W, dt_b, dtb16, Bc, Cc);
    k_scan<<<2048, 128, 0, stream>>>(dtb16, xc16, xz16, Bc, Cc, A_log, Dp, yg16);
    // p2 = yg @ out_W + x  [S2]  (bf16 A, bf16 out)
    gemm_mfma<false, 0, true, true, true><<<dim3(512, 2), 256, 0, stream>>>(
        yg16, outWT, nullptr, nullptr, NROWS, 128, 256, 128,
        nullptr, x, 128, p216, st + 256, st + 384);
    // out = BN1(h1_pre) + BN2(p2)  [S3]  (BN params computed in-kernel)
    k_add<<<512, 256, 0, stream>>>(h1p16, p216, st, n1_g, n1_b, n2_g, n2_b,
                                   outb, st + 512, st + 640);
    k_fold1<<<256, 128, 0, stream>>>(st + 512, st + 640, m1_g, m1_b, W1, b1, W1eT, b1e);
    // g = gelu(out @ W1e + b1e)  [S4]  (fp32 A cvt-staged, bf16 out)
    gemm_mfma<false, 1, true, false, true><<<dim3(512, 4), 256, 0, stream>>>(
        outb, W1eT, nullptr, nullptr, NROWS, 256, 128, 256,
        b1e, nullptr, 0, g16, st + 768, st + 1024);
    k_fold2<<<128, 256, 0, stream>>>(st + 768, st + 1024, m2_g, m2_b, W2, b2, W2eT, b2e);
    // out2 = g @ W2e + b2e + out  [S5]  (bf16 A, fp32 out)
    gemm_mfma<false, 0, true, true, false><<<dim3(512, 2), 256, 0, stream>>>(
        g16, W2eT, nullptr, nullptr, NROWS, 128, 256, 128,
        b2e, outb, 128, out2, st + 1280, st + 1408);
    // d_out = BN3(out2)  (params computed in-kernel from S5)
    k_bn3<<<256, 256, 0, stream>>>(out2, st + 1280, st + 1408, n3_g, n3_b,
                                   (float*)d_out);
}

// Round 12
// 402.426 us; speedup vs baseline: 1.1248x; 1.1248x over previous
//
#include <hip/hip_runtime.h>

// ---------------------------------------------------------------------------
// GraphMambaConv: N=32768 nodes, C=128, G=64 graphs x L=512, E=524288 edges,
// D_INNER=256, D_STATE=16, DT_RANK=8, D_CONV=4.
//
// Round 12: REVERT k_scan to the round-10 shape (512 blocks x 256 thr,
// 32 d/block). Round 11's finer d-split (16 d/block) tripled FETCH: B/C
// rows are shared per-graph, so fetch scales with dblk count (x4 -> +96MB),
// and 16-ch slices read 32B of 64B sectors. Keep r11's independent wins:
// bf16 gather (half read bytes), bf16 h1p/p2, x16 prep.
// ---------------------------------------------------------------------------

#define NROWS 32768
#define CDIM  128
#define EDGES 524288
#define GL    512
#define SCH   32          // scan chunk (timesteps)
#define NCH   (GL / SCH)  // 16 chunks

typedef short s16x8 __attribute__((ext_vector_type(8)));
typedef float f32x4 __attribute__((ext_vector_type(4)));

__device__ __forceinline__ unsigned short f2bf(float f)
{
    unsigned u = __float_as_uint(f);
    u += 0x7FFF + ((u >> 16) & 1);          // RNE
    return (unsigned short)(u >> 16);
}

__device__ __forceinline__ float bf2f(unsigned short u)
{
    return __uint_as_float((unsigned)u << 16);
}

__device__ __forceinline__ unsigned cvt_pk_bf16(float lo, float hi)
{
    unsigned r;
    asm("v_cvt_pk_bf16_f32 %0, %1, %2" : "=v"(r) : "v"(lo), "v"(hi));
    return r;
}

__device__ __forceinline__ float exp2_fast(float x)
{
    float r;
    asm("v_exp_f32 %0, %1" : "=v"(r) : "v"(x));   // v_exp_f32 computes 2^x
    return r;
}

// ------------------------- CSR build: histogram ----------------------------
__global__ __launch_bounds__(256) void k_hist(const int* __restrict__ ei,
                                              int* __restrict__ deg)
{
    const int e = blockIdx.x * 1024 + threadIdx.x * 4;
    const int4 d4 = *(const int4*)&ei[EDGES + e];
    atomicAdd(&deg[d4.x], 1);
    atomicAdd(&deg[d4.y], 1);
    atomicAdd(&deg[d4.z], 1);
    atomicAdd(&deg[d4.w], 1);
}

// ---------------- CSR build: exclusive prefix scan (1 block) ---------------
__global__ __launch_bounds__(1024) void k_scanidx(const int* __restrict__ deg,
                                                  int* __restrict__ base,
                                                  int* __restrict__ cursor)
{
    __shared__ int ps[1024];
    const int tid = threadIdx.x;
    int loc[32];
    int s = 0;
#pragma unroll
    for (int i = 0; i < 32; ++i) { loc[i] = deg[tid * 32 + i]; s += loc[i]; }
    ps[tid] = s;
    __syncthreads();
    for (int off = 1; off < 1024; off <<= 1) {
        int v = (tid >= off) ? ps[tid - off] : 0;
        __syncthreads();
        ps[tid] += v;
        __syncthreads();
    }
    int run = tid ? ps[tid - 1] : 0;
#pragma unroll
    for (int i = 0; i < 32; ++i) {
        base[tid * 32 + i] = run;
        cursor[tid * 32 + i] = run;
        run += loc[i];
    }
    if (tid == 0) base[32768] = EDGES;
}

// ------------------------- CSR build: fill src lists -----------------------
__global__ __launch_bounds__(256) void k_fill(const int* __restrict__ ei,
                                              int* __restrict__ cursor,
                                              int* __restrict__ srcs)
{
    const int e = blockIdx.x * 1024 + threadIdx.x * 4;
    const int4 s4 = *(const int4*)&ei[e];
    const int4 d4 = *(const int4*)&ei[EDGES + e];
    int p;
    p = atomicAdd(&cursor[d4.x], 1); srcs[p] = s4.x;
    p = atomicAdd(&cursor[d4.y], 1); srcs[p] = s4.y;
    p = atomicAdd(&cursor[d4.z], 1); srcs[p] = s4.z;
    p = atomicAdd(&cursor[d4.w], 1); srcs[p] = s4.w;
}

// ------------------- x -> bf16 (one pass, 8 elems/thread) ------------------
__global__ __launch_bounds__(256) void k_prepx(const float* __restrict__ x,
                                               unsigned short* __restrict__ x16)
{
    const size_t i = ((size_t)blockIdx.x * 256 + threadIdx.x) * 8;
    float4 a = *(const float4*)&x[i];
    float4 b = *(const float4*)&x[i + 4];
    uint4 p;
    p.x = cvt_pk_bf16(a.x, a.y); p.y = cvt_pk_bf16(a.z, a.w);
    p.z = cvt_pk_bf16(b.x, b.y); p.w = cvt_pk_bf16(b.z, b.w);
    *(uint4*)&x16[i] = p;
}

// ---------------- gather (bf16 in/out, fp32 accumulate) --------------------
__global__ __launch_bounds__(256) void k_gather(const unsigned short* __restrict__ x16,
                                                const int* __restrict__ base,
                                                const int* __restrict__ srcs,
                                                unsigned short* __restrict__ agg16)
{
    const int node = blockIdx.x * 4 + (threadIdx.x >> 6);
    const int lane = threadIdx.x & 63;
    const int b0 = base[node], b1 = base[node + 1];
    float a0 = 0.f, a1 = 0.f;
    for (int i = b0; i < b1; ++i) {
        const int s = srcs[i];
        const unsigned v = *(const unsigned*)&x16[(size_t)s * 128 + lane * 2];
        a0 += bf2f((unsigned short)(v & 0xFFFF));
        a1 += bf2f((unsigned short)(v >> 16));
    }
    *(unsigned*)&agg16[(size_t)node * 128 + lane * 2] = cvt_pk_bf16(a0, a1);
}

// ---- merged weight prep: 5 transposes (bf16) in one launch, 552 blocks ----
__global__ __launch_bounds__(256) void k_prepw5(
    const float* __restrict__ Wa, unsigned short* __restrict__ Ta,
    const float* __restrict__ Wb, unsigned short* __restrict__ Tb,
    const float* __restrict__ Wc, unsigned short* __restrict__ Tc,
    const float* __restrict__ Wd, unsigned short* __restrict__ Td,
    const float* __restrict__ We, unsigned short* __restrict__ Te)
{
    const int idx = blockIdx.x * 256 + threadIdx.x;
    const float* W; unsigned short* T; int rel, ks, N;
    if (idx < 16384)       { W = Wa; T = Ta; rel = idx;          ks = 7; N = 128; }
    else if (idx < 32768)  { W = Wb; T = Tb; rel = idx - 16384;  ks = 7; N = 128; }
    else if (idx < 98304)  { W = Wc; T = Tc; rel = idx - 32768;  ks = 7; N = 512; }
    else if (idx < 108544) { W = Wd; T = Td; rel = idx - 98304;  ks = 8; N = 40;  }
    else                   { W = We; T = Te; rel = idx - 108544; ks = 8; N = 128; }
    const int K = 1 << ks;
    const int n = rel >> ks, k = rel & (K - 1);
    T[rel] = f2bf(W[(size_t)k * N + n]);
}

// ------------------------- MFMA GEMM (bf16 in, fp32 acc) --------------------
// out = epi( A0@W0 [+ A1@W1] [+bias] [+resid] ), optional column stats.
// A: MxK row-major, fp32 (ABF=0, cvt-staged) or bf16 (ABF=1, copy-staged).
// WT: NxK bf16 row-major. Out fp32 (OBF=0) or bf16 (OBF=1); stats/resid fp32.
// Tile 64x64, BK=64, 4 waves x (2x2 mfma_f32_16x16x32_bf16).
template<bool DUAL, int ACT, bool STAT, bool ABF, bool OBF>
__global__ __launch_bounds__(256)
void gemm_mfma(const void* __restrict__ A0, const unsigned short* __restrict__ W0T,
               const void* __restrict__ A1p, const unsigned short* __restrict__ W1Tp,
               int M, int N, int K, int ldo,
               const float* __restrict__ bias,
               const float* __restrict__ resid, int ldr,
               void* __restrict__ outp,
               float* __restrict__ sumP, float* __restrict__ sqP)
{
    __shared__ __align__(16) unsigned short As[64 * 72];  // [m][k], pad 8
    __shared__ __align__(16) unsigned short Bs[64 * 72];  // [n][k], pad 8
    __shared__ float sB[2][64];

    const int tid = threadIdx.x;
    const int m0 = blockIdx.x * 64;
    const int n0 = blockIdx.y * 64;

    const int sr = tid >> 2;             // staging row 0..63
    const int sk = (tid & 3) * 16;       // staging k base

    const int w  = tid >> 6, l = tid & 63;
    const int wr = (w >> 1) * 32, wc = (w & 1) * 32;
    const int fr = l & 15;               // frag row/col
    const int fk = (l >> 4) * 8;         // frag k base

    f32x4 acc[2][2];
#pragma unroll
    for (int i = 0; i < 2; ++i)
#pragma unroll
        for (int j = 0; j < 2; ++j) acc[i][j] = (f32x4){0.f, 0.f, 0.f, 0.f};

    const int npass = DUAL ? 2 : 1;
    for (int pass = 0; pass < npass; ++pass) {
        const void* A = (DUAL && pass) ? A1p : A0;
        const unsigned short* WT = (DUAL && pass) ? W1Tp : W0T;
        for (int k0 = 0; k0 < K; k0 += 64) {
            if (ABF) {   // stage A: straight bf16 copy
                const unsigned short* ap =
                    (const unsigned short*)A + (size_t)(m0 + sr) * K + k0 + sk;
                *(uint4*)&As[sr * 72 + sk]     = *(const uint4*)(ap);
                *(uint4*)&As[sr * 72 + sk + 8] = *(const uint4*)(ap + 8);
            } else {     // stage A: fp32 -> bf16 via v_cvt_pk_bf16_f32
                const float* ap = (const float*)A + (size_t)(m0 + sr) * K + k0 + sk;
                float4 v0 = *(const float4*)(ap);
                float4 v1 = *(const float4*)(ap + 4);
                float4 v2 = *(const float4*)(ap + 8);
                float4 v3 = *(const float4*)(ap + 12);
                uint4 pa, pb;
                pa.x = cvt_pk_bf16(v0.x, v0.y); pa.y = cvt_pk_bf16(v0.z, v0.w);
                pa.z = cvt_pk_bf16(v1.x, v1.y); pa.w = cvt_pk_bf16(v1.z, v1.w);
                pb.x = cvt_pk_bf16(v2.x, v2.y); pb.y = cvt_pk_bf16(v2.z, v2.w);
                pb.z = cvt_pk_bf16(v3.x, v3.y); pb.w = cvt_pk_bf16(v3.z, v3.w);
                *(uint4*)&As[sr * 72 + sk]     = pa;
                *(uint4*)&As[sr * 72 + sk + 8] = pb;
            }
            {   // stage B: straight bf16 copy from WT (zero-fill n >= N)
                const int nn = n0 + sr;
                if (nn < N) {
                    const unsigned short* wp = WT + (size_t)nn * K + k0 + sk;
                    uint4 w0 = *(const uint4*)(wp);
                    uint4 w1 = *(const uint4*)(wp + 8);
                    *(uint4*)&Bs[sr * 72 + sk]     = w0;
                    *(uint4*)&Bs[sr * 72 + sk + 8] = w1;
                } else {
                    uint4 z = make_uint4(0, 0, 0, 0);
                    *(uint4*)&Bs[sr * 72 + sk]     = z;
                    *(uint4*)&Bs[sr * 72 + sk + 8] = z;
                }
            }
            __syncthreads();
#pragma unroll
            for (int ks = 0; ks < 2; ++ks) {
                s16x8 a0 = *(const s16x8*)&As[(wr + fr     ) * 72 + ks * 32 + fk];
                s16x8 a1 = *(const s16x8*)&As[(wr + 16 + fr) * 72 + ks * 32 + fk];
                s16x8 b0 = *(const s16x8*)&Bs[(wc + fr     ) * 72 + ks * 32 + fk];
                s16x8 b1 = *(const s16x8*)&Bs[(wc + 16 + fr) * 72 + ks * 32 + fk];
                acc[0][0] = __builtin_amdgcn_mfma_f32_16x16x32_bf16(a0, b0, acc[0][0], 0, 0, 0);
                acc[0][1] = __builtin_amdgcn_mfma_f32_16x16x32_bf16(a0, b1, acc[0][1], 0, 0, 0);
                acc[1][0] = __builtin_amdgcn_mfma_f32_16x16x32_bf16(a1, b0, acc[1][0], 0, 0, 0);
                acc[1][1] = __builtin_amdgcn_mfma_f32_16x16x32_bf16(a1, b1, acc[1][1], 0, 0, 0);
            }
            __syncthreads();
        }
    }

    // ---- epilogue: C/D layout col=lane&15, row=(lane>>4)*4+reg ----
    const int orow = (l >> 4) * 4;
    float cs[2] = {0.f, 0.f}, cq[2] = {0.f, 0.f};
#pragma unroll
    for (int mt = 0; mt < 2; ++mt) {
#pragma unroll
        for (int nt = 0; nt < 2; ++nt) {
            const int cg = n0 + wc + nt * 16 + fr;
            if (cg < N) {
                const float bv = bias ? bias[cg] : 0.f;
#pragma unroll
                for (int r = 0; r < 4; ++r) {
                    const int rg = m0 + wr + mt * 16 + orow + r;
                    float v = acc[mt][nt][r] + bv;
                    if (resid) v += resid[(size_t)rg * ldr + cg];
                    if (ACT == 1)
                        v = 0.5f * v * (1.f + erff(v * 0.7071067811865475f));
                    if (OBF)
                        ((unsigned short*)outp)[(size_t)rg * ldo + cg] = f2bf(v);
                    else
                        ((float*)outp)[(size_t)rg * ldo + cg] = v;
                    if (STAT) { cs[nt] += v; cq[nt] += v * v; }
                }
            }
        }
    }
    if (STAT) {
        if (tid < 64) { sB[0][tid] = 0.f; sB[1][tid] = 0.f; }
        __syncthreads();
#pragma unroll
        for (int nt = 0; nt < 2; ++nt) {
            atomicAdd(&sB[0][wc + nt * 16 + fr], cs[nt]);
            atomicAdd(&sB[1][wc + nt * 16 + fr], cq[nt]);
        }
        __syncthreads();
        if (tid < 64 && (n0 + tid) < N) {
            atomicAdd(&sumP[n0 + tid], sB[0][tid]);
            atomicAdd(&sqP[n0 + tid],  sB[1][tid]);
        }
    }
}

// --------------------- causal conv + SiLU (bf16 in/out) --------------------
__global__ __launch_bounds__(256) void k_conv(const unsigned short* __restrict__ xz,
                                              const float* __restrict__ cw,
                                              const float* __restrict__ cb,
                                              unsigned short* __restrict__ xc)
{
    const int r = blockIdx.x;        // global row
    const int l = r & (GL - 1);      // position within graph
    const int d = threadIdx.x;       // 0..255
    float4 w4 = *(const float4*)&cw[d * 4];
    const float taps[4] = {w4.x, w4.y, w4.z, w4.w};
    float acc = cb[d];
#pragma unroll
    for (int k = 0; k < 4; ++k) {
        int ll = l - 3 + k;
        if (ll >= 0) acc += bf2f(xz[(size_t)(r - 3 + k) * 512 + d]) * taps[k];
    }
    float s = 1.f / (1.f + __expf(-acc));
    xc[(size_t)r * 256 + d] = f2bf(acc * s);
}

// ---------------- dt = softplus(proj[:,:8] @ dt_W + dt_b); B,C slices ------
__global__ __launch_bounds__(256) void k_dtbc(const float* __restrict__ proj,
                                              const float* __restrict__ dt_W,
                                              const float* __restrict__ dt_b,
                                              unsigned short* __restrict__ dtb,
                                              float* __restrict__ Bc,
                                              float* __restrict__ Cc)
{
    __shared__ float dtWS[8 * 256];
    __shared__ float dt_bS[256];
    __shared__ float projS[32 * 8];
    const int tid = threadIdx.x;
    const int r0 = blockIdx.x * 32;
    for (int i = tid; i < 2048; i += 256) dtWS[i] = dt_W[i];
    dt_bS[tid] = dt_b[tid];
    projS[tid] = proj[(size_t)(r0 + (tid >> 3)) * 40 + (tid & 7)];
    __syncthreads();

    const int c = tid;
    for (int rr = 0; rr < 32; ++rr) {
        float acc = dt_bS[c];
        const float* pr = &projS[rr * 8];
#pragma unroll
        for (int q = 0; q < 8; ++q) acc += pr[q] * dtWS[q * 256 + c];
        float e  = exp2_fast(-fabsf(acc) * 1.4426950408f);
        float sp = fmaxf(acc, 0.f) + 0.6931471806f * __log2f(1.f + e);
        dtb[(size_t)(r0 + rr) * 256 + c] = f2bf(sp);
    }
    // B = proj[:, 8:24], C = proj[:, 24:40]
    for (int e2 = tid; e2 < 1024; e2 += 256) {
        int rr = e2 >> 5, cc = e2 & 31;
        float v = proj[(size_t)(r0 + rr) * 40 + 8 + cc];
        if (cc < 16) Bc[(size_t)(r0 + rr) * 16 + cc] = v;
        else         Cc[(size_t)(r0 + rr) * 16 + cc - 16] = v;
    }
}

// ---------------- 8-lane-group sum via DPP (zero DS-pipe ops) ---------------
__device__ __forceinline__ float dpp_add8(float x)
{
    float y = x;
    int t;
    t = __builtin_amdgcn_update_dpp(0, __float_as_int(y), 0xB1, 0xF, 0xF, true);
    y += __int_as_float(t);
    t = __builtin_amdgcn_update_dpp(0, __float_as_int(y), 0x4E, 0xF, 0xF, true);
    y += __int_as_float(t);
    t = __builtin_amdgcn_update_dpp(0, __float_as_int(y), 0x141, 0xF, 0xF, true);
    y += __int_as_float(t);
    return y;
}

// ------------------------------ selective scan -----------------------------
// Round-10 config (restored): block = (g, dblk32): 32 d x 16 states = 256
// thr (4 waves); 512 blocks -> 2 blocks/CU. 32 d/block keeps B/C redundancy
// at x8 per graph and d-slices at 64B sectors (r11's 16 d/block tripled
// FETCH and regressed 2x).
// Wave = 8 d x 8 sp-lanes; lane holds states {2sp, 2sp+1} in registers.
// LDS (fp32, converted at stage time): dtT[32][36] | xcT[32][36] | BT[16][36]
// | CT[16][36], double-buffered; ygL[32][36]. Global dt/xc/z/yg are bf16.
// NOTE: yg aliases dtb - chunk c+1's dtb rows are prefetched to regs before
// chunk c's yg writeout; blocks touch disjoint (g, d-slice) columns.
__global__ __launch_bounds__(256) void k_scan(
    const unsigned short* __restrict__ dtb,
    const unsigned short* __restrict__ xcb,
    const unsigned short* __restrict__ xzb,
    const float* __restrict__ Bb, const float* __restrict__ Cb,
    const float* __restrict__ A_log, const float* __restrict__ Dp,
    unsigned short* __restrict__ yg)
{
    // floats: buf0 [0,3456) | buf1 [3456,6912) | ygL [6912, 6912+32*36)
    __shared__ __align__(16) float lds[2 * 3456 + 32 * 36];

    const int g    = blockIdx.x >> 3;
    const int dblk = blockIdx.x & 7;
    const int tid  = threadIdx.x;
    const int lane = tid & 63;
    const int dl   = (tid >> 6) * 8 + (lane >> 3);   // local d 0..31
    const int sp   = lane & 7;                       // state-pair index
    const int d0   = dblk * 32;
    const int d    = d0 + dl;
    const size_t rbase = (size_t)g * GL;

    // staging coords
    const int sdd = tid & 31, stq = tid >> 5;        // dt/xc: d-col, t-quad
    const int sbt = tid >> 4, sbi = tid & 15;        // B/C: t-row, state
    const int szt = tid >> 3, szi = tid & 7;         // z / writeout

    const float L2E = 1.44269504088896f;
    const float aA0 = -__expf(A_log[d * 16 + 2 * sp]) * L2E;
    const float aA1 = -__expf(A_log[d * 16 + 2 * sp + 1]) * L2E;
    const float Dpd = Dp[d];
    float h0 = 0.f, h1 = 0.f;

    float rdt[4], rxc[4];
    float rB0, rB1, rC0, rC1;
    ushort4 rz, zcur;

    // ---- prologue: load chunk 0 into registers ----
    {
        const size_t r0 = rbase;
#pragma unroll
        for (int j = 0; j < 4; ++j) {
            rdt[j] = bf2f(dtb[(r0 + stq * 4 + j) * 256 + d0 + sdd]);
            rxc[j] = bf2f(xcb[(r0 + stq * 4 + j) * 256 + d0 + sdd]);
        }
        rz  = *(const ushort4*)&xzb[(r0 + szt) * 512 + 256 + d0 + szi * 4];
        rB0 = Bb[(r0 + sbt) * 16 + sbi];
        rB1 = Bb[(r0 + sbt + 16) * 16 + sbi];
        rC0 = Cb[(r0 + sbt) * 16 + sbi];
        rC1 = Cb[(r0 + sbt + 16) * 16 + sbi];
    }
    zcur = rz;

    float* ygL = lds + 2 * 3456;

    for (int c = 0; c < NCH; ++c) {
        float* buf = lds + (c & 1) * 3456;
        // ---- commit staged registers to LDS (transposed fp32 tiles) ----
        *(float4*)&buf[sdd * 36 + stq * 4] =
            make_float4(rdt[0], rdt[1], rdt[2], rdt[3]);
        *(float4*)&buf[1152 + sdd * 36 + stq * 4] =
            make_float4(rxc[0], rxc[1], rxc[2], rxc[3]);
        buf[2304 + sbi * 36 + sbt]      = rB0;
        buf[2304 + sbi * 36 + sbt + 16] = rB1;
        buf[2880 + sbi * 36 + sbt]      = rC0;
        buf[2880 + sbi * 36 + sbt + 16] = rC1;
        zcur = rz;
        __syncthreads();

        // ---- prefetch chunk c+1 (lands during the 32 steps below) ----
        if (c + 1 < NCH) {
            const size_t r0 = rbase + (size_t)(c + 1) * SCH;
#pragma unroll
            for (int j = 0; j < 4; ++j) {
                rdt[j] = bf2f(dtb[(r0 + stq * 4 + j) * 256 + d0 + sdd]);
                rxc[j] = bf2f(xcb[(r0 + stq * 4 + j) * 256 + d0 + sdd]);
            }
            rz  = *(const ushort4*)&xzb[(r0 + szt) * 512 + 256 + d0 + szi * 4];
            rB0 = Bb[(r0 + sbt) * 16 + sbi];
            rB1 = Bb[(r0 + sbt + 16) * 16 + sbi];
            rC0 = Cb[(r0 + sbt) * 16 + sbi];
            rC1 = Cb[(r0 + sbt + 16) * 16 + sbi];
        }

        // ---- 32 scan steps from LDS ----
        const float* pdt = buf + dl * 36;
        const float* pxc = buf + 1152 + dl * 36;
        const float* pB0 = buf + 2304 + (2 * sp) * 36;
        const float* pB1 = buf + 2304 + (2 * sp + 1) * 36;
        const float* pC0 = buf + 2880 + (2 * sp) * 36;
        const float* pC1 = buf + 2880 + (2 * sp + 1) * 36;
        float yk[4] = {0.f, 0.f, 0.f, 0.f};
#pragma unroll
        for (int t4 = 0; t4 < 8; ++t4) {
            const float4 dt4 = *(const float4*)&pdt[t4 * 4];
            const float4 xc4 = *(const float4*)&pxc[t4 * 4];
            const float4 B04 = *(const float4*)&pB0[t4 * 4];
            const float4 B14 = *(const float4*)&pB1[t4 * 4];
            const float4 C04 = *(const float4*)&pC0[t4 * 4];
            const float4 C14 = *(const float4*)&pC1[t4 * 4];
#define SSTEP(J)                                                            \
            {                                                               \
                const float dt = ((const float*)&dt4)[J];                   \
                const float xc = ((const float*)&xc4)[J];                   \
                const float dtx = dt * xc;                                  \
                h0 = h0 * exp2_fast(dt * aA0) + dtx * ((const float*)&B04)[J]; \
                h1 = h1 * exp2_fast(dt * aA1) + dtx * ((const float*)&B14)[J]; \
                float yv = h0 * ((const float*)&C04)[J]                     \
                         + h1 * ((const float*)&C14)[J];                    \
                yv = dpp_add8(yv);                                          \
                yv = fmaf(xc, Dpd, yv);                                     \
                const int tt = t4 * 4 + (J);                                \
                yk[t4 >> 1] = (sp == (tt & 7)) ? yv : yk[t4 >> 1];          \
            }
            SSTEP(0) SSTEP(1) SSTEP(2) SSTEP(3)
#undef SSTEP
        }
        // stage captured y to LDS: lane sp holds t = 8k+sp for its d
#pragma unroll
        for (int k = 0; k < 4; ++k)
            ygL[(k * 8 + sp) * 36 + dl] = yk[k];
        __syncthreads();

        // ---- coalesced bf16 writeout with silu(z) from registers ----
        {
            const size_t rr0 = rbase + (size_t)c * SCH;
            float4 y4 = *(const float4*)&ygL[szt * 36 + szi * 4];
            float z0 = bf2f(zcur.x), z1 = bf2f(zcur.y);
            float z2 = bf2f(zcur.z), z3 = bf2f(zcur.w);
            float o0 = y4.x * (z0 / (1.f + __expf(-z0)));
            float o1 = y4.y * (z1 / (1.f + __expf(-z1)));
            float o2 = y4.z * (z2 / (1.f + __expf(-z2)));
            float o3 = y4.w * (z3 / (1.f + __expf(-z3)));
            uint2 packed;
            packed.x = cvt_pk_bf16(o0, o1);
            packed.y = cvt_pk_bf16(o2, o3);
            *(uint2*)&yg[(rr0 + szt) * 256 + d0 + szi * 4] = packed;
        }
    }
}

// ------- add + BN1/BN2 (params per-thread; bf16 h1p/p2 inputs) -------------
__global__ __launch_bounds__(256) void k_add(const unsigned short* __restrict__ h1p,
                                             const unsigned short* __restrict__ p2,
                                             const float* __restrict__ st,
                                             const float* __restrict__ g1,
                                             const float* __restrict__ be1,
                                             const float* __restrict__ g2,
                                             const float* __restrict__ be2,
                                             float* __restrict__ outp,
                                             float* __restrict__ sumP,
                                             float* __restrict__ sqP)
{
    const int c = threadIdx.x & 127, half = threadIdx.x >> 7;
    const float inv = 1.f / 32768.f;
    const float m1 = st[c] * inv, v1 = st[128 + c] * inv - m1 * m1;
    const float a1 = g1[c] * rsqrtf(v1 + 1e-5f), b1 = be1[c] - m1 * a1;
    const float m2 = st[256 + c] * inv, v2 = st[384 + c] * inv - m2 * m2;
    const float a2 = g2[c] * rsqrtf(v2 + 1e-5f), b2 = be2[c] - m2 * a2;

    const int rbase = blockIdx.x * 64 + half * 32;
    float s = 0.f, q = 0.f;
    for (int i = 0; i < 32; ++i) {
        size_t idx = (size_t)(rbase + i) * 128 + c;
        float v = bf2f(h1p[idx]) * a1 + b1 + bf2f(p2[idx]) * a2 + b2;
        outp[idx] = v; s += v; q += v * v;
    }
    __shared__ float sh[2][2][128];
    sh[0][half][c] = s; sh[1][half][c] = q;
    __syncthreads();
    if (threadIdx.x < 128) {
        atomicAdd(&sumP[c], sh[0][0][c] + sh[0][1][c]);
        atomicAdd(&sqP[c],  sh[1][0][c] + sh[1][1][c]);
    }
}

// ---- fold1: block-per-column; W1eT bf16 [256][128] + b1e fp32 -------------
__global__ __launch_bounds__(128) void k_fold1(
    const float* __restrict__ sumP, const float* __restrict__ sqP,
    const float* __restrict__ gam, const float* __restrict__ bet,
    const float* __restrict__ W1, const float* __restrict__ b1in,
    unsigned short* __restrict__ W1eT, float* __restrict__ b1e)
{
    __shared__ float red[128];
    const int n = blockIdx.x, k = threadIdx.x;
    const float inv = 1.f / 32768.f;
    const float m = sumP[k] * inv, v = sqP[k] * inv - m * m;
    const float a = gam[k] * rsqrtf(v + 1e-5f), bs = bet[k] - m * a;
    const float wv = W1[k * 256 + n];
    W1eT[n * 128 + k] = f2bf(a * wv);
    red[k] = bs * wv;
    __syncthreads();
    for (int s = 64; s > 0; s >>= 1) {
        if (k < s) red[k] += red[k + s];
        __syncthreads();
    }
    if (k == 0) b1e[n] = red[0] + b1in[n];
}

// ---- fold2: block-per-column; W2eT bf16 [128][256] + b2e fp32 -------------
__global__ __launch_bounds__(256) void k_fold2(
    const float* __restrict__ sumP, const float* __restrict__ sqP,
    const float* __restrict__ gam, const float* __restrict__ bet,
    const float* __restrict__ W2, const float* __restrict__ b2in,
    unsigned short* __restrict__ W2eT, float* __restrict__ b2e)
{
    __shared__ float red[256];
    const int n = blockIdx.x, k = threadIdx.x;
    const float inv = 1.f / 32768.f;
    const float m = sumP[k] * inv, v = sqP[k] * inv - m * m;
    const float a = gam[k] * rsqrtf(v + 1e-5f), bs = bet[k] - m * a;
    const float wv = W2[k * 128 + n];
    W2eT[n * 256 + k] = f2bf(a * wv);
    red[k] = bs * wv;
    __syncthreads();
    for (int s = 128; s > 0; s >>= 1) {
        if (k < s) red[k] += red[k + s];
        __syncthreads();
    }
    if (k == 0) b2e[n] = red[0] + b2in[n];
}

// ---------------- BN3 (params computed per-thread, amortized) ---------------
__global__ __launch_bounds__(256) void k_bn3(const float* __restrict__ out2,
                                             const float* __restrict__ sumP,
                                             const float* __restrict__ sqP,
                                             const float* __restrict__ gam,
                                             const float* __restrict__ bet,
                                             float* __restrict__ dout)
{
    const int cq = (threadIdx.x & 31) * 4;     // column quad
    const int rw = threadIdx.x >> 5;           // 0..7
    const float inv = 1.f / 32768.f;
    float a[4], b[4];
#pragma unroll
    for (int j = 0; j < 4; ++j) {
        float m = sumP[cq + j] * inv, v = sqP[cq + j] * inv - m * m;
        a[j] = gam[cq + j] * rsqrtf(v + 1e-5f);
        b[j] = bet[cq + j] - m * a[j];
    }
    const int r0 = blockIdx.x * 128 + rw;
#pragma unroll 4
    for (int k = 0; k < 16; ++k) {
        const size_t r = r0 + k * 8;
        float4 v = *(const float4*)&out2[r * 128 + cq];
        v.x = v.x * a[0] + b[0]; v.y = v.y * a[1] + b[1];
        v.z = v.z * a[2] + b[2]; v.w = v.w * a[3] + b[3];
        *(float4*)&dout[r * 128 + cq] = v;
    }
}

// ------------------------------- launch ------------------------------------
extern "C" void kernel_launch(void* const* d_in, const int* in_sizes, int n_in,
                              void* d_out, int out_size, void* d_ws, size_t ws_size,
                              hipStream_t stream)
{
    (void)in_sizes; (void)n_in; (void)out_size; (void)ws_size;
    const float* x      = (const float*)d_in[0];
    const int*   ei     = (const int*)d_in[1];
    // d_in[2] = batch (unused: equal-size sorted graphs == reshape)
    const float* W_root = (const float*)d_in[3];
    const float* W_rel  = (const float*)d_in[4];
    const float* b_rel  = (const float*)d_in[5];
    const float* n1_g = (const float*)d_in[6],  *n1_b = (const float*)d_in[7];
    const float* n2_g = (const float*)d_in[8],  *n2_b = (const float*)d_in[9];
    const float* n3_g = (const float*)d_in[10], *n3_b = (const float*)d_in[11];
    const float* m1_g = (const float*)d_in[12], *m1_b = (const float*)d_in[13];
    const float* W1   = (const float*)d_in[14], *b1   = (const float*)d_in[15];
    const float* m2_g = (const float*)d_in[16], *m2_b = (const float*)d_in[17];
    const float* W2   = (const float*)d_in[18], *b2   = (const float*)d_in[19];
    const float* in_W   = (const float*)d_in[20];
    const float* conv_w = (const float*)d_in[21], *conv_b = (const float*)d_in[22];
    const float* xproj_W= (const float*)d_in[23];
    const float* dt_W   = (const float*)d_in[24], *dt_b = (const float*)d_in[25];
    const float* A_log  = (const float*)d_in[26], *Dp   = (const float*)d_in[27];
    const float* out_W  = (const float*)d_in[28];

    float* ws = (float*)d_ws;
    // small region
    float* st  = ws;             // 2048 used (S1..S5 sums/sumsqs)
    float* b1e = ws + 8192;      // 256
    float* b2e = ws + 8448;      // 128
    // bf16 transposed weights (shorts)
    unsigned short* wsh   = (unsigned short*)(ws + 8704);
    unsigned short* WrelT  = wsh;            // 128x128 = 16384
    unsigned short* WrootT = wsh + 16384;    // 16384
    unsigned short* inWT   = wsh + 32768;    // 512x128 = 65536
    unsigned short* xprojT = wsh + 98304;    // 40x256  = 10240
    unsigned short* outWT  = wsh + 108544;   // 128x256 = 32768
    unsigned short* W1eT   = wsh + 141312;   // 256x128 = 32768
    unsigned short* W2eT   = wsh + 174080;   // 128x256 = 32768 (end 206848)
    // big buffers (float-unit offsets; bf16 buffers occupy half the floats)
    float* big = ws + 112640;
    unsigned short* agg16 = (unsigned short*)(big);             // 4.19M sh
    unsigned short* p216  = agg16;                              // reuse
    unsigned short* h1p16 = (unsigned short*)(big + 2097152);   // 4.19M sh
    unsigned short* x16   = (unsigned short*)(big + 4194304);   // 4.19M sh
    unsigned short* xz16  = (unsigned short*)(big + 6291456);   // 16.78M sh
    unsigned short* xc16  = (unsigned short*)(big + 14680064);  // 8.39M sh
    float* proj = big + 18874368;                               // 1.31M f
    unsigned short* dtb16 = (unsigned short*)(big + 20185088);  // 8.39M sh (yg alias)
    unsigned short* yg16  = dtb16;
    float* Bc   = big + 24379392;                               // 524288
    float* Cc   = big + 24903680;                               // 524288
    float* outb = big + 25427968;                               // fp32 4.19M
    float* out2 = big + 29622272;                               // fp32 4.19M
    unsigned short* g16   = (unsigned short*)(big + 33816576);  // 8.39M sh

    // CSR scratch lives in the h1p16 region (dead until the h1 GEMM writes it)
    int* ideg   = (int*)h1p16;            // 32768
    int* ibase  = ideg + 32768;           // 32769
    int* icur   = ideg + 65552;           // 32768 (16B-aligned)
    int* isrcs  = ideg + 98320;           // 524288

    hipMemsetAsync(st, 0, 2048 * sizeof(float), stream);
    hipMemsetAsync(ideg, 0, 32768 * sizeof(int), stream);

    // ---- preps: weights (bf16 transposes) + x -> bf16 ----
    k_prepw5<<<552, 256, 0, stream>>>(W_rel, WrelT, W_root, WrootT,
                                      in_W, inWT, xproj_W, xprojT,
                                      out_W, outWT);
    k_prepx<<<2048, 256, 0, stream>>>(x, x16);

    // ---- CSR build + gather (bf16) ----
    k_hist<<<512, 256, 0, stream>>>(ei, ideg);
    k_scanidx<<<1, 1024, 0, stream>>>(ideg, ibase, icur);
    k_fill<<<512, 256, 0, stream>>>(ei, icur, isrcs);
    k_gather<<<8192, 256, 0, stream>>>(x16, ibase, isrcs, agg16);

    // h1_pre = agg@W_rel + b_rel + x@W_root + x  [S1]  (bf16 A, bf16 out)
    gemm_mfma<true, 0, true, true, true><<<dim3(512, 2), 256, 0, stream>>>(
        agg16, WrelT, x16, WrootT, NROWS, 128, 128, 128,
        b_rel, x, 128, h1p16, st + 0, st + 128);
    // xz = x @ in_W  (bf16 A, bf16 out)
    gemm_mfma<false, 0, false, true, true><<<dim3(512, 8), 256, 0, stream>>>(
        x16, inWT, nullptr, nullptr, NROWS, 512, 128, 512,
        nullptr, nullptr, 0, xz16, nullptr, nullptr);
    k_conv<<<32768, 256, 0, stream>>>(xz16, conv_w, conv_b, xc16);
    // proj = xc @ xproj_W (bf16 A, fp32 out, N=40)
    gemm_mfma<false, 0, false, true, false><<<dim3(512, 1), 256, 0, stream>>>(
        xc16, xprojT, nullptr, nullptr, NROWS, 40, 256, 40,
        nullptr, nullptr, 0, proj, nullptr, nullptr);
    k_dtbc<<<1024, 256, 0, stream>>>(proj, dt_W, dt_b, dtb16, Bc, Cc);
    k_scan<<<512, 256, 0, stream>>>(dtb16, xc16, xz16, Bc, Cc, A_log, Dp, yg16);
    // p2 = yg @ out_W + x  [S2]  (bf16 A, bf16 out)
    gemm_mfma<false, 0, true, true, true><<<dim3(512, 2), 256, 0, stream>>>(
        yg16, outWT, nullptr, nullptr, NROWS, 128, 256, 128,
        nullptr, x, 128, p216, st + 256, st + 384);
    // out = BN1(h1_pre) + BN2(p2)  [S3]  (BN params computed in-kernel)
    k_add<<<512, 256, 0, stream>>>(h1p16, p216, st, n1_g, n1_b, n2_g, n2_b,
                                   outb, st + 512, st + 640);
    k_fold1<<<256, 128, 0, stream>>>(st + 512, st + 640, m1_g, m1_b, W1, b1, W1eT, b1e);
    // g = gelu(out @ W1e + b1e)  [S4]  (fp32 A cvt-staged, bf16 out)
    gemm_mfma<false, 1, true, false, true><<<dim3(512, 4), 256, 0, stream>>>(
        outb, W1eT, nullptr, nullptr, NROWS, 256, 128, 256,
        b1e, nullptr, 0, g16, st + 768, st + 1024);
    k_fold2<<<128, 256, 0, stream>>>(st + 768, st + 1024, m2_g, m2_b, W2, b2, W2eT, b2e);
    // out2 = g @ W2e + b2e + out  [S5]  (bf16 A, fp32 out)
    gemm_mfma<false, 0, true, true, false><<<dim3(512, 2), 256, 0, stream>>>(
        g16, W2eT, nullptr, nullptr, NROWS, 128, 256, 128,
        b2e, outb, 128, out2, st + 1280, st + 1408);
    // d_out = BN3(out2)  (params computed in-kernel from S5)
    k_bn3<<<256, 256, 0, stream>>>(out2, st + 1280, st + 1408, n3_g, n3_b,
                                   (float*)d_out);
}

// Round 13
// 398.048 us; speedup vs baseline: 1.1371x; 1.0110x over previous
//
#include <hip/hip_runtime.h>

// ---------------------------------------------------------------------------
// GraphMambaConv: N=32768 nodes, C=128, G=64 graphs x L=512, E=524288 edges,
// D_INNER=256, D_STATE=16, DT_RANK=8, D_CONV=4.
//
// Round 13: finish the bf16 conversion of all big streams (r12 was half-way):
//  - outb (out = BN1+BN2) stored bf16: k_add writes bf16, MLP1 copy-stages,
//    MLP2 residual reads bf16 (new RBF template flag).
//  - out2 stored bf16 (MLP2 OBF out; k_bn3 reads bf16; S5 stats fp32).
//  - h1/p2 GEMM residual reads x16 (bf16) instead of x fp32.
//  ~59MB fewer bytes @ ~1.6TB/s observed ≈ -35us. Scan unchanged (r10 cfg).
// ---------------------------------------------------------------------------

#define NROWS 32768
#define CDIM  128
#define EDGES 524288
#define GL    512
#define SCH   32          // scan chunk (timesteps)
#define NCH   (GL / SCH)  // 16 chunks

typedef short s16x8 __attribute__((ext_vector_type(8)));
typedef float f32x4 __attribute__((ext_vector_type(4)));

__device__ __forceinline__ unsigned short f2bf(float f)
{
    unsigned u = __float_as_uint(f);
    u += 0x7FFF + ((u >> 16) & 1);          // RNE
    return (unsigned short)(u >> 16);
}

__device__ __forceinline__ float bf2f(unsigned short u)
{
    return __uint_as_float((unsigned)u << 16);
}

__device__ __forceinline__ unsigned cvt_pk_bf16(float lo, float hi)
{
    unsigned r;
    asm("v_cvt_pk_bf16_f32 %0, %1, %2" : "=v"(r) : "v"(lo), "v"(hi));
    return r;
}

__device__ __forceinline__ float exp2_fast(float x)
{
    float r;
    asm("v_exp_f32 %0, %1" : "=v"(r) : "v"(x));   // v_exp_f32 computes 2^x
    return r;
}

// ------------------------- CSR build: histogram ----------------------------
__global__ __launch_bounds__(256) void k_hist(const int* __restrict__ ei,
                                              int* __restrict__ deg)
{
    const int e = blockIdx.x * 1024 + threadIdx.x * 4;
    const int4 d4 = *(const int4*)&ei[EDGES + e];
    atomicAdd(&deg[d4.x], 1);
    atomicAdd(&deg[d4.y], 1);
    atomicAdd(&deg[d4.z], 1);
    atomicAdd(&deg[d4.w], 1);
}

// ---------------- CSR build: exclusive prefix scan (1 block) ---------------
__global__ __launch_bounds__(1024) void k_scanidx(const int* __restrict__ deg,
                                                  int* __restrict__ base,
                                                  int* __restrict__ cursor)
{
    __shared__ int ps[1024];
    const int tid = threadIdx.x;
    int loc[32];
    int s = 0;
#pragma unroll
    for (int i = 0; i < 32; ++i) { loc[i] = deg[tid * 32 + i]; s += loc[i]; }
    ps[tid] = s;
    __syncthreads();
    for (int off = 1; off < 1024; off <<= 1) {
        int v = (tid >= off) ? ps[tid - off] : 0;
        __syncthreads();
        ps[tid] += v;
        __syncthreads();
    }
    int run = tid ? ps[tid - 1] : 0;
#pragma unroll
    for (int i = 0; i < 32; ++i) {
        base[tid * 32 + i] = run;
        cursor[tid * 32 + i] = run;
        run += loc[i];
    }
    if (tid == 0) base[32768] = EDGES;
}

// ------------------------- CSR build: fill src lists -----------------------
__global__ __launch_bounds__(256) void k_fill(const int* __restrict__ ei,
                                              int* __restrict__ cursor,
                                              int* __restrict__ srcs)
{
    const int e = blockIdx.x * 1024 + threadIdx.x * 4;
    const int4 s4 = *(const int4*)&ei[e];
    const int4 d4 = *(const int4*)&ei[EDGES + e];
    int p;
    p = atomicAdd(&cursor[d4.x], 1); srcs[p] = s4.x;
    p = atomicAdd(&cursor[d4.y], 1); srcs[p] = s4.y;
    p = atomicAdd(&cursor[d4.z], 1); srcs[p] = s4.z;
    p = atomicAdd(&cursor[d4.w], 1); srcs[p] = s4.w;
}

// ------------------- x -> bf16 (one pass, 8 elems/thread) ------------------
__global__ __launch_bounds__(256) void k_prepx(const float* __restrict__ x,
                                               unsigned short* __restrict__ x16)
{
    const size_t i = ((size_t)blockIdx.x * 256 + threadIdx.x) * 8;
    float4 a = *(const float4*)&x[i];
    float4 b = *(const float4*)&x[i + 4];
    uint4 p;
    p.x = cvt_pk_bf16(a.x, a.y); p.y = cvt_pk_bf16(a.z, a.w);
    p.z = cvt_pk_bf16(b.x, b.y); p.w = cvt_pk_bf16(b.z, b.w);
    *(uint4*)&x16[i] = p;
}

// ---------------- gather (bf16 in/out, fp32 accumulate) --------------------
__global__ __launch_bounds__(256) void k_gather(const unsigned short* __restrict__ x16,
                                                const int* __restrict__ base,
                                                const int* __restrict__ srcs,
                                                unsigned short* __restrict__ agg16)
{
    const int node = blockIdx.x * 4 + (threadIdx.x >> 6);
    const int lane = threadIdx.x & 63;
    const int b0 = base[node], b1 = base[node + 1];
    float a0 = 0.f, a1 = 0.f;
    for (int i = b0; i < b1; ++i) {
        const int s = srcs[i];
        const unsigned v = *(const unsigned*)&x16[(size_t)s * 128 + lane * 2];
        a0 += bf2f((unsigned short)(v & 0xFFFF));
        a1 += bf2f((unsigned short)(v >> 16));
    }
    *(unsigned*)&agg16[(size_t)node * 128 + lane * 2] = cvt_pk_bf16(a0, a1);
}

// ---- merged weight prep: 5 transposes (bf16) in one launch, 552 blocks ----
__global__ __launch_bounds__(256) void k_prepw5(
    const float* __restrict__ Wa, unsigned short* __restrict__ Ta,
    const float* __restrict__ Wb, unsigned short* __restrict__ Tb,
    const float* __restrict__ Wc, unsigned short* __restrict__ Tc,
    const float* __restrict__ Wd, unsigned short* __restrict__ Td,
    const float* __restrict__ We, unsigned short* __restrict__ Te)
{
    const int idx = blockIdx.x * 256 + threadIdx.x;
    const float* W; unsigned short* T; int rel, ks, N;
    if (idx < 16384)       { W = Wa; T = Ta; rel = idx;          ks = 7; N = 128; }
    else if (idx < 32768)  { W = Wb; T = Tb; rel = idx - 16384;  ks = 7; N = 128; }
    else if (idx < 98304)  { W = Wc; T = Tc; rel = idx - 32768;  ks = 7; N = 512; }
    else if (idx < 108544) { W = Wd; T = Td; rel = idx - 98304;  ks = 8; N = 40;  }
    else                   { W = We; T = Te; rel = idx - 108544; ks = 8; N = 128; }
    const int K = 1 << ks;
    const int n = rel >> ks, k = rel & (K - 1);
    T[rel] = f2bf(W[(size_t)k * N + n]);
}

// ------------------------- MFMA GEMM (bf16 in, fp32 acc) --------------------
// out = epi( A0@W0 [+ A1@W1] [+bias] [+resid] ), optional column stats.
// A: MxK row-major, fp32 (ABF=0, cvt-staged) or bf16 (ABF=1, copy-staged).
// WT: NxK bf16 row-major. Out fp32/bf16 (OBF). Resid fp32/bf16 (RBF).
// Tile 64x64, BK=64, 4 waves x (2x2 mfma_f32_16x16x32_bf16).
template<bool DUAL, int ACT, bool STAT, bool ABF, bool OBF, bool RBF>
__global__ __launch_bounds__(256)
void gemm_mfma(const void* __restrict__ A0, const unsigned short* __restrict__ W0T,
               const void* __restrict__ A1p, const unsigned short* __restrict__ W1Tp,
               int M, int N, int K, int ldo,
               const float* __restrict__ bias,
               const void* __restrict__ resid, int ldr,
               void* __restrict__ outp,
               float* __restrict__ sumP, float* __restrict__ sqP)
{
    __shared__ __align__(16) unsigned short As[64 * 72];  // [m][k], pad 8
    __shared__ __align__(16) unsigned short Bs[64 * 72];  // [n][k], pad 8
    __shared__ float sB[2][64];

    const int tid = threadIdx.x;
    const int m0 = blockIdx.x * 64;
    const int n0 = blockIdx.y * 64;

    const int sr = tid >> 2;             // staging row 0..63
    const int sk = (tid & 3) * 16;       // staging k base

    const int w  = tid >> 6, l = tid & 63;
    const int wr = (w >> 1) * 32, wc = (w & 1) * 32;
    const int fr = l & 15;               // frag row/col
    const int fk = (l >> 4) * 8;         // frag k base

    f32x4 acc[2][2];
#pragma unroll
    for (int i = 0; i < 2; ++i)
#pragma unroll
        for (int j = 0; j < 2; ++j) acc[i][j] = (f32x4){0.f, 0.f, 0.f, 0.f};

    const int npass = DUAL ? 2 : 1;
    for (int pass = 0; pass < npass; ++pass) {
        const void* A = (DUAL && pass) ? A1p : A0;
        const unsigned short* WT = (DUAL && pass) ? W1Tp : W0T;
        for (int k0 = 0; k0 < K; k0 += 64) {
            if (ABF) {   // stage A: straight bf16 copy
                const unsigned short* ap =
                    (const unsigned short*)A + (size_t)(m0 + sr) * K + k0 + sk;
                *(uint4*)&As[sr * 72 + sk]     = *(const uint4*)(ap);
                *(uint4*)&As[sr * 72 + sk + 8] = *(const uint4*)(ap + 8);
            } else {     // stage A: fp32 -> bf16 via v_cvt_pk_bf16_f32
                const float* ap = (const float*)A + (size_t)(m0 + sr) * K + k0 + sk;
                float4 v0 = *(const float4*)(ap);
                float4 v1 = *(const float4*)(ap + 4);
                float4 v2 = *(const float4*)(ap + 8);
                float4 v3 = *(const float4*)(ap + 12);
                uint4 pa, pb;
                pa.x = cvt_pk_bf16(v0.x, v0.y); pa.y = cvt_pk_bf16(v0.z, v0.w);
                pa.z = cvt_pk_bf16(v1.x, v1.y); pa.w = cvt_pk_bf16(v1.z, v1.w);
                pb.x = cvt_pk_bf16(v2.x, v2.y); pb.y = cvt_pk_bf16(v2.z, v2.w);
                pb.z = cvt_pk_bf16(v3.x, v3.y); pb.w = cvt_pk_bf16(v3.z, v3.w);
                *(uint4*)&As[sr * 72 + sk]     = pa;
                *(uint4*)&As[sr * 72 + sk + 8] = pb;
            }
            {   // stage B: straight bf16 copy from WT (zero-fill n >= N)
                const int nn = n0 + sr;
                if (nn < N) {
                    const unsigned short* wp = WT + (size_t)nn * K + k0 + sk;
                    uint4 w0 = *(const uint4*)(wp);
                    uint4 w1 = *(const uint4*)(wp + 8);
                    *(uint4*)&Bs[sr * 72 + sk]     = w0;
                    *(uint4*)&Bs[sr * 72 + sk + 8] = w1;
                } else {
                    uint4 z = make_uint4(0, 0, 0, 0);
                    *(uint4*)&Bs[sr * 72 + sk]     = z;
                    *(uint4*)&Bs[sr * 72 + sk + 8] = z;
                }
            }
            __syncthreads();
#pragma unroll
            for (int ks = 0; ks < 2; ++ks) {
                s16x8 a0 = *(const s16x8*)&As[(wr + fr     ) * 72 + ks * 32 + fk];
                s16x8 a1 = *(const s16x8*)&As[(wr + 16 + fr) * 72 + ks * 32 + fk];
                s16x8 b0 = *(const s16x8*)&Bs[(wc + fr     ) * 72 + ks * 32 + fk];
                s16x8 b1 = *(const s16x8*)&Bs[(wc + 16 + fr) * 72 + ks * 32 + fk];
                acc[0][0] = __builtin_amdgcn_mfma_f32_16x16x32_bf16(a0, b0, acc[0][0], 0, 0, 0);
                acc[0][1] = __builtin_amdgcn_mfma_f32_16x16x32_bf16(a0, b1, acc[0][1], 0, 0, 0);
                acc[1][0] = __builtin_amdgcn_mfma_f32_16x16x32_bf16(a1, b0, acc[1][0], 0, 0, 0);
                acc[1][1] = __builtin_amdgcn_mfma_f32_16x16x32_bf16(a1, b1, acc[1][1], 0, 0, 0);
            }
            __syncthreads();
        }
    }

    // ---- epilogue: C/D layout col=lane&15, row=(lane>>4)*4+reg ----
    const int orow = (l >> 4) * 4;
    float cs[2] = {0.f, 0.f}, cq[2] = {0.f, 0.f};
#pragma unroll
    for (int mt = 0; mt < 2; ++mt) {
#pragma unroll
        for (int nt = 0; nt < 2; ++nt) {
            const int cg = n0 + wc + nt * 16 + fr;
            if (cg < N) {
                const float bv = bias ? bias[cg] : 0.f;
#pragma unroll
                for (int r = 0; r < 4; ++r) {
                    const int rg = m0 + wr + mt * 16 + orow + r;
                    float v = acc[mt][nt][r] + bv;
                    if (resid) {
                        float rv = RBF
                            ? bf2f(((const unsigned short*)resid)[(size_t)rg * ldr + cg])
                            : ((const float*)resid)[(size_t)rg * ldr + cg];
                        v += rv;
                    }
                    if (ACT == 1)
                        v = 0.5f * v * (1.f + erff(v * 0.7071067811865475f));
                    if (OBF)
                        ((unsigned short*)outp)[(size_t)rg * ldo + cg] = f2bf(v);
                    else
                        ((float*)outp)[(size_t)rg * ldo + cg] = v;
                    if (STAT) { cs[nt] += v; cq[nt] += v * v; }
                }
            }
        }
    }
    if (STAT) {
        if (tid < 64) { sB[0][tid] = 0.f; sB[1][tid] = 0.f; }
        __syncthreads();
#pragma unroll
        for (int nt = 0; nt < 2; ++nt) {
            atomicAdd(&sB[0][wc + nt * 16 + fr], cs[nt]);
            atomicAdd(&sB[1][wc + nt * 16 + fr], cq[nt]);
        }
        __syncthreads();
        if (tid < 64 && (n0 + tid) < N) {
            atomicAdd(&sumP[n0 + tid], sB[0][tid]);
            atomicAdd(&sqP[n0 + tid],  sB[1][tid]);
        }
    }
}

// --------------------- causal conv + SiLU (bf16 in/out) --------------------
__global__ __launch_bounds__(256) void k_conv(const unsigned short* __restrict__ xz,
                                              const float* __restrict__ cw,
                                              const float* __restrict__ cb,
                                              unsigned short* __restrict__ xc)
{
    const int r = blockIdx.x;        // global row
    const int l = r & (GL - 1);      // position within graph
    const int d = threadIdx.x;       // 0..255
    float4 w4 = *(const float4*)&cw[d * 4];
    const float taps[4] = {w4.x, w4.y, w4.z, w4.w};
    float acc = cb[d];
#pragma unroll
    for (int k = 0; k < 4; ++k) {
        int ll = l - 3 + k;
        if (ll >= 0) acc += bf2f(xz[(size_t)(r - 3 + k) * 512 + d]) * taps[k];
    }
    float s = 1.f / (1.f + __expf(-acc));
    xc[(size_t)r * 256 + d] = f2bf(acc * s);
}

// ---------------- dt = softplus(proj[:,:8] @ dt_W + dt_b); B,C slices ------
__global__ __launch_bounds__(256) void k_dtbc(const float* __restrict__ proj,
                                              const float* __restrict__ dt_W,
                                              const float* __restrict__ dt_b,
                                              unsigned short* __restrict__ dtb,
                                              float* __restrict__ Bc,
                                              float* __restrict__ Cc)
{
    __shared__ float dtWS[8 * 256];
    __shared__ float dt_bS[256];
    __shared__ float projS[32 * 8];
    const int tid = threadIdx.x;
    const int r0 = blockIdx.x * 32;
    for (int i = tid; i < 2048; i += 256) dtWS[i] = dt_W[i];
    dt_bS[tid] = dt_b[tid];
    projS[tid] = proj[(size_t)(r0 + (tid >> 3)) * 40 + (tid & 7)];
    __syncthreads();

    const int c = tid;
    for (int rr = 0; rr < 32; ++rr) {
        float acc = dt_bS[c];
        const float* pr = &projS[rr * 8];
#pragma unroll
        for (int q = 0; q < 8; ++q) acc += pr[q] * dtWS[q * 256 + c];
        float e  = exp2_fast(-fabsf(acc) * 1.4426950408f);
        float sp = fmaxf(acc, 0.f) + 0.6931471806f * __log2f(1.f + e);
        dtb[(size_t)(r0 + rr) * 256 + c] = f2bf(sp);
    }
    // B = proj[:, 8:24], C = proj[:, 24:40]
    for (int e2 = tid; e2 < 1024; e2 += 256) {
        int rr = e2 >> 5, cc = e2 & 31;
        float v = proj[(size_t)(r0 + rr) * 40 + 8 + cc];
        if (cc < 16) Bc[(size_t)(r0 + rr) * 16 + cc] = v;
        else         Cc[(size_t)(r0 + rr) * 16 + cc - 16] = v;
    }
}

// ---------------- 8-lane-group sum via DPP (zero DS-pipe ops) ---------------
__device__ __forceinline__ float dpp_add8(float x)
{
    float y = x;
    int t;
    t = __builtin_amdgcn_update_dpp(0, __float_as_int(y), 0xB1, 0xF, 0xF, true);
    y += __int_as_float(t);
    t = __builtin_amdgcn_update_dpp(0, __float_as_int(y), 0x4E, 0xF, 0xF, true);
    y += __int_as_float(t);
    t = __builtin_amdgcn_update_dpp(0, __float_as_int(y), 0x141, 0xF, 0xF, true);
    y += __int_as_float(t);
    return y;
}

// ------------------------------ selective scan -----------------------------
// Round-10 config: block = (g, dblk32): 32 d x 16 states = 256 thr (4 waves);
// 512 blocks -> 2 blocks/CU. (r11's 16 d/block tripled FETCH via B/C
// redundancy; do not split d finer.)
// NOTE: yg aliases dtb - chunk c+1's dtb rows are prefetched to regs before
// chunk c's yg writeout; blocks touch disjoint (g, d-slice) columns.
__global__ __launch_bounds__(256) void k_scan(
    const unsigned short* __restrict__ dtb,
    const unsigned short* __restrict__ xcb,
    const unsigned short* __restrict__ xzb,
    const float* __restrict__ Bb, const float* __restrict__ Cb,
    const float* __restrict__ A_log, const float* __restrict__ Dp,
    unsigned short* __restrict__ yg)
{
    // floats: buf0 [0,3456) | buf1 [3456,6912) | ygL [6912, 6912+32*36)
    __shared__ __align__(16) float lds[2 * 3456 + 32 * 36];

    const int g    = blockIdx.x >> 3;
    const int dblk = blockIdx.x & 7;
    const int tid  = threadIdx.x;
    const int lane = tid & 63;
    const int dl   = (tid >> 6) * 8 + (lane >> 3);   // local d 0..31
    const int sp   = lane & 7;                       // state-pair index
    const int d0   = dblk * 32;
    const int d    = d0 + dl;
    const size_t rbase = (size_t)g * GL;

    // staging coords
    const int sdd = tid & 31, stq = tid >> 5;        // dt/xc: d-col, t-quad
    const int sbt = tid >> 4, sbi = tid & 15;        // B/C: t-row, state
    const int szt = tid >> 3, szi = tid & 7;         // z / writeout

    const float L2E = 1.44269504088896f;
    const float aA0 = -__expf(A_log[d * 16 + 2 * sp]) * L2E;
    const float aA1 = -__expf(A_log[d * 16 + 2 * sp + 1]) * L2E;
    const float Dpd = Dp[d];
    float h0 = 0.f, h1 = 0.f;

    float rdt[4], rxc[4];
    float rB0, rB1, rC0, rC1;
    ushort4 rz, zcur;

    // ---- prologue: load chunk 0 into registers ----
    {
        const size_t r0 = rbase;
#pragma unroll
        for (int j = 0; j < 4; ++j) {
            rdt[j] = bf2f(dtb[(r0 + stq * 4 + j) * 256 + d0 + sdd]);
            rxc[j] = bf2f(xcb[(r0 + stq * 4 + j) * 256 + d0 + sdd]);
        }
        rz  = *(const ushort4*)&xzb[(r0 + szt) * 512 + 256 + d0 + szi * 4];
        rB0 = Bb[(r0 + sbt) * 16 + sbi];
        rB1 = Bb[(r0 + sbt + 16) * 16 + sbi];
        rC0 = Cb[(r0 + sbt) * 16 + sbi];
        rC1 = Cb[(r0 + sbt + 16) * 16 + sbi];
    }
    zcur = rz;

    float* ygL = lds + 2 * 3456;

    for (int c = 0; c < NCH; ++c) {
        float* buf = lds + (c & 1) * 3456;
        // ---- commit staged registers to LDS (transposed fp32 tiles) ----
        *(float4*)&buf[sdd * 36 + stq * 4] =
            make_float4(rdt[0], rdt[1], rdt[2], rdt[3]);
        *(float4*)&buf[1152 + sdd * 36 + stq * 4] =
            make_float4(rxc[0], rxc[1], rxc[2], rxc[3]);
        buf[2304 + sbi * 36 + sbt]      = rB0;
        buf[2304 + sbi * 36 + sbt + 16] = rB1;
        buf[2880 + sbi * 36 + sbt]      = rC0;
        buf[2880 + sbi * 36 + sbt + 16] = rC1;
        zcur = rz;
        __syncthreads();

        // ---- prefetch chunk c+1 (lands during the 32 steps below) ----
        if (c + 1 < NCH) {
            const size_t r0 = rbase + (size_t)(c + 1) * SCH;
#pragma unroll
            for (int j = 0; j < 4; ++j) {
                rdt[j] = bf2f(dtb[(r0 + stq * 4 + j) * 256 + d0 + sdd]);
                rxc[j] = bf2f(xcb[(r0 + stq * 4 + j) * 256 + d0 + sdd]);
            }
            rz  = *(const ushort4*)&xzb[(r0 + szt) * 512 + 256 + d0 + szi * 4];
            rB0 = Bb[(r0 + sbt) * 16 + sbi];
            rB1 = Bb[(r0 + sbt + 16) * 16 + sbi];
            rC0 = Cb[(r0 + sbt) * 16 + sbi];
            rC1 = Cb[(r0 + sbt + 16) * 16 + sbi];
        }

        // ---- 32 scan steps from LDS ----
        const float* pdt = buf + dl * 36;
        const float* pxc = buf + 1152 + dl * 36;
        const float* pB0 = buf + 2304 + (2 * sp) * 36;
        const float* pB1 = buf + 2304 + (2 * sp + 1) * 36;
        const float* pC0 = buf + 2880 + (2 * sp) * 36;
        const float* pC1 = buf + 2880 + (2 * sp + 1) * 36;
        float yk[4] = {0.f, 0.f, 0.f, 0.f};
#pragma unroll
        for (int t4 = 0; t4 < 8; ++t4) {
            const float4 dt4 = *(const float4*)&pdt[t4 * 4];
            const float4 xc4 = *(const float4*)&pxc[t4 * 4];
            const float4 B04 = *(const float4*)&pB0[t4 * 4];
            const float4 B14 = *(const float4*)&pB1[t4 * 4];
            const float4 C04 = *(const float4*)&pC0[t4 * 4];
            const float4 C14 = *(const float4*)&pC1[t4 * 4];
#define SSTEP(J)                                                            \
            {                                                               \
                const float dt = ((const float*)&dt4)[J];                   \
                const float xc = ((const float*)&xc4)[J];                   \
                const float dtx = dt * xc;                                  \
                h0 = h0 * exp2_fast(dt * aA0) + dtx * ((const float*)&B04)[J]; \
                h1 = h1 * exp2_fast(dt * aA1) + dtx * ((const float*)&B14)[J]; \
                float yv = h0 * ((const float*)&C04)[J]                     \
                         + h1 * ((const float*)&C14)[J];                    \
                yv = dpp_add8(yv);                                          \
                yv = fmaf(xc, Dpd, yv);                                     \
                const int tt = t4 * 4 + (J);                                \
                yk[t4 >> 1] = (sp == (tt & 7)) ? yv : yk[t4 >> 1];          \
            }
            SSTEP(0) SSTEP(1) SSTEP(2) SSTEP(3)
#undef SSTEP
        }
        // stage captured y to LDS: lane sp holds t = 8k+sp for its d
#pragma unroll
        for (int k = 0; k < 4; ++k)
            ygL[(k * 8 + sp) * 36 + dl] = yk[k];
        __syncthreads();

        // ---- coalesced bf16 writeout with silu(z) from registers ----
        {
            const size_t rr0 = rbase + (size_t)c * SCH;
            float4 y4 = *(const float4*)&ygL[szt * 36 + szi * 4];
            float z0 = bf2f(zcur.x), z1 = bf2f(zcur.y);
            float z2 = bf2f(zcur.z), z3 = bf2f(zcur.w);
            float o0 = y4.x * (z0 / (1.f + __expf(-z0)));
            float o1 = y4.y * (z1 / (1.f + __expf(-z1)));
            float o2 = y4.z * (z2 / (1.f + __expf(-z2)));
            float o3 = y4.w * (z3 / (1.f + __expf(-z3)));
            uint2 packed;
            packed.x = cvt_pk_bf16(o0, o1);
            packed.y = cvt_pk_bf16(o2, o3);
            *(uint2*)&yg[(rr0 + szt) * 256 + d0 + szi * 4] = packed;
        }
    }
}

// --- add + BN1/BN2 (params per-thread; bf16 in, bf16 out, fp32 stats) ------
__global__ __launch_bounds__(256) void k_add(const unsigned short* __restrict__ h1p,
                                             const unsigned short* __restrict__ p2,
                                             const float* __restrict__ st,
                                             const float* __restrict__ g1,
                                             const float* __restrict__ be1,
                                             const float* __restrict__ g2,
                                             const float* __restrict__ be2,
                                             unsigned short* __restrict__ outp,
                                             float* __restrict__ sumP,
                                             float* __restrict__ sqP)
{
    const int c = threadIdx.x & 127, half = threadIdx.x >> 7;
    const float inv = 1.f / 32768.f;
    const float m1 = st[c] * inv, v1 = st[128 + c] * inv - m1 * m1;
    const float a1 = g1[c] * rsqrtf(v1 + 1e-5f), b1 = be1[c] - m1 * a1;
    const float m2 = st[256 + c] * inv, v2 = st[384 + c] * inv - m2 * m2;
    const float a2 = g2[c] * rsqrtf(v2 + 1e-5f), b2 = be2[c] - m2 * a2;

    const int rbase = blockIdx.x * 64 + half * 32;
    float s = 0.f, q = 0.f;
    for (int i = 0; i < 32; ++i) {
        size_t idx = (size_t)(rbase + i) * 128 + c;
        float v = bf2f(h1p[idx]) * a1 + b1 + bf2f(p2[idx]) * a2 + b2;
        outp[idx] = f2bf(v); s += v; q += v * v;
    }
    __shared__ float sh[2][2][128];
    sh[0][half][c] = s; sh[1][half][c] = q;
    __syncthreads();
    if (threadIdx.x < 128) {
        atomicAdd(&sumP[c], sh[0][0][c] + sh[0][1][c]);
        atomicAdd(&sqP[c],  sh[1][0][c] + sh[1][1][c]);
    }
}

// ---- fold1: block-per-column; W1eT bf16 [256][128] + b1e fp32 -------------
__global__ __launch_bounds__(128) void k_fold1(
    const float* __restrict__ sumP, const float* __restrict__ sqP,
    const float* __restrict__ gam, const float* __restrict__ bet,
    const float* __restrict__ W1, const float* __restrict__ b1in,
    unsigned short* __restrict__ W1eT, float* __restrict__ b1e)
{
    __shared__ float red[128];
    const int n = blockIdx.x, k = threadIdx.x;
    const float inv = 1.f / 32768.f;
    const float m = sumP[k] * inv, v = sqP[k] * inv - m * m;
    const float a = gam[k] * rsqrtf(v + 1e-5f), bs = bet[k] - m * a;
    const float wv = W1[k * 256 + n];
    W1eT[n * 128 + k] = f2bf(a * wv);
    red[k] = bs * wv;
    __syncthreads();
    for (int s = 64; s > 0; s >>= 1) {
        if (k < s) red[k] += red[k + s];
        __syncthreads();
    }
    if (k == 0) b1e[n] = red[0] + b1in[n];
}

// ---- fold2: block-per-column; W2eT bf16 [128][256] + b2e fp32 -------------
__global__ __launch_bounds__(256) void k_fold2(
    const float* __restrict__ sumP, const float* __restrict__ sqP,
    const float* __restrict__ gam, const float* __restrict__ bet,
    const float* __restrict__ W2, const float* __restrict__ b2in,
    unsigned short* __restrict__ W2eT, float* __restrict__ b2e)
{
    __shared__ float red[256];
    const int n = blockIdx.x, k = threadIdx.x;
    const float inv = 1.f / 32768.f;
    const float m = sumP[k] * inv, v = sqP[k] * inv - m * m;
    const float a = gam[k] * rsqrtf(v + 1e-5f), bs = bet[k] - m * a;
    const float wv = W2[k * 128 + n];
    W2eT[n * 256 + k] = f2bf(a * wv);
    red[k] = bs * wv;
    __syncthreads();
    for (int s = 128; s > 0; s >>= 1) {
        if (k < s) red[k] += red[k + s];
        __syncthreads();
    }
    if (k == 0) b2e[n] = red[0] + b2in[n];
}

// ------------- BN3 (params per-thread, amortized; bf16 input) ---------------
__global__ __launch_bounds__(256) void k_bn3(const unsigned short* __restrict__ out2,
                                             const float* __restrict__ sumP,
                                             const float* __restrict__ sqP,
                                             const float* __restrict__ gam,
                                             const float* __restrict__ bet,
                                             float* __restrict__ dout)
{
    const int cq = (threadIdx.x & 31) * 4;     // column quad
    const int rw = threadIdx.x >> 5;           // 0..7
    const float inv = 1.f / 32768.f;
    float a[4], b[4];
#pragma unroll
    for (int j = 0; j < 4; ++j) {
        float m = sumP[cq + j] * inv, v = sqP[cq + j] * inv - m * m;
        a[j] = gam[cq + j] * rsqrtf(v + 1e-5f);
        b[j] = bet[cq + j] - m * a[j];
    }
    const int r0 = blockIdx.x * 128 + rw;
#pragma unroll 4
    for (int k = 0; k < 16; ++k) {
        const size_t r = r0 + k * 8;
        ushort4 u = *(const ushort4*)&out2[r * 128 + cq];
        float4 v;
        v.x = bf2f(u.x) * a[0] + b[0]; v.y = bf2f(u.y) * a[1] + b[1];
        v.z = bf2f(u.z) * a[2] + b[2]; v.w = bf2f(u.w) * a[3] + b[3];
        *(float4*)&dout[r * 128 + cq] = v;
    }
}

// ------------------------------- launch ------------------------------------
extern "C" void kernel_launch(void* const* d_in, const int* in_sizes, int n_in,
                              void* d_out, int out_size, void* d_ws, size_t ws_size,
                              hipStream_t stream)
{
    (void)in_sizes; (void)n_in; (void)out_size; (void)ws_size;
    const float* x      = (const float*)d_in[0];
    const int*   ei     = (const int*)d_in[1];
    // d_in[2] = batch (unused: equal-size sorted graphs == reshape)
    const float* W_root = (const float*)d_in[3];
    const float* W_rel  = (const float*)d_in[4];
    const float* b_rel  = (const float*)d_in[5];
    const float* n1_g = (const float*)d_in[6],  *n1_b = (const float*)d_in[7];
    const float* n2_g = (const float*)d_in[8],  *n2_b = (const float*)d_in[9];
    const float* n3_g = (const float*)d_in[10], *n3_b = (const float*)d_in[11];
    const float* m1_g = (const float*)d_in[12], *m1_b = (const float*)d_in[13];
    const float* W1   = (const float*)d_in[14], *b1   = (const float*)d_in[15];
    const float* m2_g = (const float*)d_in[16], *m2_b = (const float*)d_in[17];
    const float* W2   = (const float*)d_in[18], *b2   = (const float*)d_in[19];
    const float* in_W   = (const float*)d_in[20];
    const float* conv_w = (const float*)d_in[21], *conv_b = (const float*)d_in[22];
    const float* xproj_W= (const float*)d_in[23];
    const float* dt_W   = (const float*)d_in[24], *dt_b = (const float*)d_in[25];
    const float* A_log  = (const float*)d_in[26], *Dp   = (const float*)d_in[27];
    const float* out_W  = (const float*)d_in[28];

    float* ws = (float*)d_ws;
    // small region
    float* st  = ws;             // 2048 used (S1..S5 sums/sumsqs)
    float* b1e = ws + 8192;      // 256
    float* b2e = ws + 8448;      // 128
    // bf16 transposed weights (shorts)
    unsigned short* wsh   = (unsigned short*)(ws + 8704);
    unsigned short* WrelT  = wsh;            // 128x128 = 16384
    unsigned short* WrootT = wsh + 16384;    // 16384
    unsigned short* inWT   = wsh + 32768;    // 512x128 = 65536
    unsigned short* xprojT = wsh + 98304;    // 40x256  = 10240
    unsigned short* outWT  = wsh + 108544;   // 128x256 = 32768
    unsigned short* W1eT   = wsh + 141312;   // 256x128 = 32768
    unsigned short* W2eT   = wsh + 174080;   // 128x256 = 32768 (end 206848)
    // big buffers (float-unit offsets; bf16 buffers occupy half the floats)
    float* big = ws + 112640;
    unsigned short* agg16 = (unsigned short*)(big);             // 4.19M sh
    unsigned short* p216  = agg16;                              // reuse
    unsigned short* h1p16 = (unsigned short*)(big + 2097152);   // 4.19M sh
    unsigned short* x16   = (unsigned short*)(big + 4194304);   // 4.19M sh
    unsigned short* xz16  = (unsigned short*)(big + 6291456);   // 16.78M sh
    unsigned short* xc16  = (unsigned short*)(big + 14680064);  // 8.39M sh
    float* proj = big + 18874368;                               // 1.31M f
    unsigned short* dtb16 = (unsigned short*)(big + 20185088);  // 8.39M sh (yg alias)
    unsigned short* yg16  = dtb16;
    float* Bc   = big + 24379392;                               // 524288
    float* Cc   = big + 24903680;                               // 524288
    unsigned short* outb16 = (unsigned short*)(big + 25427968); // 4.19M sh
    unsigned short* out216 = (unsigned short*)(big + 27525120); // 4.19M sh
    unsigned short* g16    = (unsigned short*)(big + 29622272); // 8.39M sh

    // CSR scratch lives in the h1p16 region (dead until the h1 GEMM writes it)
    int* ideg   = (int*)h1p16;            // 32768
    int* ibase  = ideg + 32768;           // 32769
    int* icur   = ideg + 65552;           // 32768 (16B-aligned)
    int* isrcs  = ideg + 98320;           // 524288

    hipMemsetAsync(st, 0, 2048 * sizeof(float), stream);
    hipMemsetAsync(ideg, 0, 32768 * sizeof(int), stream);

    // ---- preps: weights (bf16 transposes) + x -> bf16 ----
    k_prepw5<<<552, 256, 0, stream>>>(W_rel, WrelT, W_root, WrootT,
                                      in_W, inWT, xproj_W, xprojT,
                                      out_W, outWT);
    k_prepx<<<2048, 256, 0, stream>>>(x, x16);

    // ---- CSR build + gather (bf16) ----
    k_hist<<<512, 256, 0, stream>>>(ei, ideg);
    k_scanidx<<<1, 1024, 0, stream>>>(ideg, ibase, icur);
    k_fill<<<512, 256, 0, stream>>>(ei, icur, isrcs);
    k_gather<<<8192, 256, 0, stream>>>(x16, ibase, isrcs, agg16);

    // h1_pre = agg@W_rel + b_rel + x@W_root + x  [S1]  (bf16 A/resid/out)
    gemm_mfma<true, 0, true, true, true, true><<<dim3(512, 2), 256, 0, stream>>>(
        agg16, WrelT, x16, WrootT, NROWS, 128, 128, 128,
        b_rel, x16, 128, h1p16, st + 0, st + 128);
    // xz = x @ in_W  (bf16 A, bf16 out)
    gemm_mfma<false, 0, false, true, true, false><<<dim3(512, 8), 256, 0, stream>>>(
        x16, inWT, nullptr, nullptr, NROWS, 512, 128, 512,
        nullptr, nullptr, 0, xz16, nullptr, nullptr);
    k_conv<<<32768, 256, 0, stream>>>(xz16, conv_w, conv_b, xc16);
    // proj = xc @ xproj_W (bf16 A, fp32 out, N=40)
    gemm_mfma<false, 0, false, true, false, false><<<dim3(512, 1), 256, 0, stream>>>(
        xc16, xprojT, nullptr, nullptr, NROWS, 40, 256, 40,
        nullptr, nullptr, 0, proj, nullptr, nullptr);
    k_dtbc<<<1024, 256, 0, stream>>>(proj, dt_W, dt_b, dtb16, Bc, Cc);
    k_scan<<<512, 256, 0, stream>>>(dtb16, xc16, xz16, Bc, Cc, A_log, Dp, yg16);
    // p2 = yg @ out_W + x  [S2]  (bf16 A/resid/out)
    gemm_mfma<false, 0, true, true, true, true><<<dim3(512, 2), 256, 0, stream>>>(
        yg16, outWT, nullptr, nullptr, NROWS, 128, 256, 128,
        nullptr, x16, 128, p216, st + 256, st + 384);
    // out = BN1(h1_pre) + BN2(p2)  [S3]  (bf16 out)
    k_add<<<512, 256, 0, stream>>>(h1p16, p216, st, n1_g, n1_b, n2_g, n2_b,
                                   outb16, st + 512, st + 640);
    k_fold1<<<256, 128, 0, stream>>>(st + 512, st + 640, m1_g, m1_b, W1, b1, W1eT, b1e);
    // g = gelu(out @ W1e + b1e)  [S4]  (bf16 A copy-staged, bf16 out)
    gemm_mfma<false, 1, true, true, true, false><<<dim3(512, 4), 256, 0, stream>>>(
        outb16, W1eT, nullptr, nullptr, NROWS, 256, 128, 256,
        b1e, nullptr, 0, g16, st + 768, st + 1024);
    k_fold2<<<128, 256, 0, stream>>>(st + 768, st + 1024, m2_g, m2_b, W2, b2, W2eT, b2e);
    // out2 = g @ W2e + b2e + out  [S5]  (bf16 A/resid, bf16 out)
    gemm_mfma<false, 0, true, true, true, true><<<dim3(512, 2), 256, 0, stream>>>(
        g16, W2eT, nullptr, nullptr, NROWS, 128, 256, 128,
        b2e, outb16, 128, out216, st + 1280, st + 1408);
    // d_out = BN3(out2)  (params computed in-kernel from S5)
    k_bn3<<<256, 256, 0, stream>>>(out216, st + 1280, st + 1408, n3_g, n3_b,
                                   (float*)d_out);
}

// Round 14
// 381.921 us; speedup vs baseline: 1.1852x; 1.0422x over previous
//
#include <hip/hip_runtime.h>

// ---------------------------------------------------------------------------
// GraphMambaConv: N=32768 nodes, C=128, G=64 graphs x L=512, E=524288 edges,
// D_INNER=256, D_STATE=16, DT_RANK=8, D_CONV=4.
//
// Round 14: intermediates are L3-resident (r13's -59MB gave only -4us), so
// the non-scan kernels are per-block-overhead bound, not BW bound.
//  - GEMM tile 64x64 -> 128x64 (256 thr): 8 MFMA/wave/K-step (2x barrier &
//    staging amortization), B-traffic per output halves. All A-ops bf16.
//  - B/C stored bf16: scan reads them 8x/graph (quantified in r11) -> halves
//    that redundant fetch (~-14MB scan FETCH).
// ---------------------------------------------------------------------------

#define NROWS 32768
#define CDIM  128
#define EDGES 524288
#define GL    512
#define SCH   32          // scan chunk (timesteps)
#define NCH   (GL / SCH)  // 16 chunks

typedef short s16x8 __attribute__((ext_vector_type(8)));
typedef float f32x4 __attribute__((ext_vector_type(4)));

__device__ __forceinline__ unsigned short f2bf(float f)
{
    unsigned u = __float_as_uint(f);
    u += 0x7FFF + ((u >> 16) & 1);          // RNE
    return (unsigned short)(u >> 16);
}

__device__ __forceinline__ float bf2f(unsigned short u)
{
    return __uint_as_float((unsigned)u << 16);
}

__device__ __forceinline__ unsigned cvt_pk_bf16(float lo, float hi)
{
    unsigned r;
    asm("v_cvt_pk_bf16_f32 %0, %1, %2" : "=v"(r) : "v"(lo), "v"(hi));
    return r;
}

__device__ __forceinline__ float exp2_fast(float x)
{
    float r;
    asm("v_exp_f32 %0, %1" : "=v"(r) : "v"(x));   // v_exp_f32 computes 2^x
    return r;
}

// ------------------------- CSR build: histogram ----------------------------
__global__ __launch_bounds__(256) void k_hist(const int* __restrict__ ei,
                                              int* __restrict__ deg)
{
    const int e = blockIdx.x * 1024 + threadIdx.x * 4;
    const int4 d4 = *(const int4*)&ei[EDGES + e];
    atomicAdd(&deg[d4.x], 1);
    atomicAdd(&deg[d4.y], 1);
    atomicAdd(&deg[d4.z], 1);
    atomicAdd(&deg[d4.w], 1);
}

// ---------------- CSR build: exclusive prefix scan (1 block) ---------------
__global__ __launch_bounds__(1024) void k_scanidx(const int* __restrict__ deg,
                                                  int* __restrict__ base,
                                                  int* __restrict__ cursor)
{
    __shared__ int ps[1024];
    const int tid = threadIdx.x;
    int loc[32];
    int s = 0;
#pragma unroll
    for (int i = 0; i < 32; ++i) { loc[i] = deg[tid * 32 + i]; s += loc[i]; }
    ps[tid] = s;
    __syncthreads();
    for (int off = 1; off < 1024; off <<= 1) {
        int v = (tid >= off) ? ps[tid - off] : 0;
        __syncthreads();
        ps[tid] += v;
        __syncthreads();
    }
    int run = tid ? ps[tid - 1] : 0;
#pragma unroll
    for (int i = 0; i < 32; ++i) {
        base[tid * 32 + i] = run;
        cursor[tid * 32 + i] = run;
        run += loc[i];
    }
    if (tid == 0) base[32768] = EDGES;
}

// ------------------------- CSR build: fill src lists -----------------------
__global__ __launch_bounds__(256) void k_fill(const int* __restrict__ ei,
                                              int* __restrict__ cursor,
                                              int* __restrict__ srcs)
{
    const int e = blockIdx.x * 1024 + threadIdx.x * 4;
    const int4 s4 = *(const int4*)&ei[e];
    const int4 d4 = *(const int4*)&ei[EDGES + e];
    int p;
    p = atomicAdd(&cursor[d4.x], 1); srcs[p] = s4.x;
    p = atomicAdd(&cursor[d4.y], 1); srcs[p] = s4.y;
    p = atomicAdd(&cursor[d4.z], 1); srcs[p] = s4.z;
    p = atomicAdd(&cursor[d4.w], 1); srcs[p] = s4.w;
}

// ------------------- x -> bf16 (one pass, 8 elems/thread) ------------------
__global__ __launch_bounds__(256) void k_prepx(const float* __restrict__ x,
                                               unsigned short* __restrict__ x16)
{
    const size_t i = ((size_t)blockIdx.x * 256 + threadIdx.x) * 8;
    float4 a = *(const float4*)&x[i];
    float4 b = *(const float4*)&x[i + 4];
    uint4 p;
    p.x = cvt_pk_bf16(a.x, a.y); p.y = cvt_pk_bf16(a.z, a.w);
    p.z = cvt_pk_bf16(b.x, b.y); p.w = cvt_pk_bf16(b.z, b.w);
    *(uint4*)&x16[i] = p;
}

// ---------------- gather (bf16 in/out, fp32 accumulate) --------------------
__global__ __launch_bounds__(256) void k_gather(const unsigned short* __restrict__ x16,
                                                const int* __restrict__ base,
                                                const int* __restrict__ srcs,
                                                unsigned short* __restrict__ agg16)
{
    const int node = blockIdx.x * 4 + (threadIdx.x >> 6);
    const int lane = threadIdx.x & 63;
    const int b0 = base[node], b1 = base[node + 1];
    float a0 = 0.f, a1 = 0.f;
    for (int i = b0; i < b1; ++i) {
        const int s = srcs[i];
        const unsigned v = *(const unsigned*)&x16[(size_t)s * 128 + lane * 2];
        a0 += bf2f((unsigned short)(v & 0xFFFF));
        a1 += bf2f((unsigned short)(v >> 16));
    }
    *(unsigned*)&agg16[(size_t)node * 128 + lane * 2] = cvt_pk_bf16(a0, a1);
}

// ---- merged weight prep: 5 transposes (bf16) in one launch, 552 blocks ----
__global__ __launch_bounds__(256) void k_prepw5(
    const float* __restrict__ Wa, unsigned short* __restrict__ Ta,
    const float* __restrict__ Wb, unsigned short* __restrict__ Tb,
    const float* __restrict__ Wc, unsigned short* __restrict__ Tc,
    const float* __restrict__ Wd, unsigned short* __restrict__ Td,
    const float* __restrict__ We, unsigned short* __restrict__ Te)
{
    const int idx = blockIdx.x * 256 + threadIdx.x;
    const float* W; unsigned short* T; int rel, ks, N;
    if (idx < 16384)       { W = Wa; T = Ta; rel = idx;          ks = 7; N = 128; }
    else if (idx < 32768)  { W = Wb; T = Tb; rel = idx - 16384;  ks = 7; N = 128; }
    else if (idx < 98304)  { W = Wc; T = Tc; rel = idx - 32768;  ks = 7; N = 512; }
    else if (idx < 108544) { W = Wd; T = Td; rel = idx - 98304;  ks = 8; N = 40;  }
    else                   { W = We; T = Te; rel = idx - 108544; ks = 8; N = 128; }
    const int K = 1 << ks;
    const int n = rel >> ks, k = rel & (K - 1);
    T[rel] = f2bf(W[(size_t)k * N + n]);
}

// ------------------------- MFMA GEMM (bf16 in, fp32 acc) --------------------
// out = epi( A0@W0 [+ A1@W1] [+bias] [+resid] ), optional column stats.
// A: MxK bf16 row-major (copy-staged). WT: NxK bf16 row-major.
// Out fp32/bf16 (OBF). Resid fp32/bf16 (RBF).
// Tile 128x64, BK=64, 4 waves each 64x32 -> 8 mfma_f32_16x16x32_bf16/K-step.
template<bool DUAL, int ACT, bool STAT, bool OBF, bool RBF>
__global__ __launch_bounds__(256)
void gemm_mfma(const unsigned short* __restrict__ A0,
               const unsigned short* __restrict__ W0T,
               const unsigned short* __restrict__ A1p,
               const unsigned short* __restrict__ W1Tp,
               int M, int N, int K, int ldo,
               const float* __restrict__ bias,
               const void* __restrict__ resid, int ldr,
               void* __restrict__ outp,
               float* __restrict__ sumP, float* __restrict__ sqP)
{
    __shared__ __align__(16) unsigned short As[128 * 72];  // [m][k], pad 8
    __shared__ __align__(16) unsigned short Bs[64 * 72];   // [n][k], pad 8
    __shared__ float sB[2][64];

    const int tid = threadIdx.x;
    const int m0 = blockIdx.x * 128;
    const int n0 = blockIdx.y * 64;

    const int ar = tid >> 1, ak = (tid & 1) * 32;   // A staging: 32 elems/thr
    const int br = tid >> 2, bk = (tid & 3) * 16;   // B staging: 16 elems/thr

    const int w  = tid >> 6, l = tid & 63;
    const int wr = (w >> 1) * 64, wc = (w & 1) * 32;
    const int fr = l & 15;               // frag row/col
    const int fk = (l >> 4) * 8;         // frag k base

    f32x4 acc[4][2];
#pragma unroll
    for (int i = 0; i < 4; ++i)
#pragma unroll
        for (int j = 0; j < 2; ++j) acc[i][j] = (f32x4){0.f, 0.f, 0.f, 0.f};

    const int npass = DUAL ? 2 : 1;
    for (int pass = 0; pass < npass; ++pass) {
        const unsigned short* A = (DUAL && pass) ? A1p : A0;
        const unsigned short* WT = (DUAL && pass) ? W1Tp : W0T;
        for (int k0 = 0; k0 < K; k0 += 64) {
            {   // stage A: straight bf16 copy, 4x uint4 per thread
                const unsigned short* ap = A + (size_t)(m0 + ar) * K + k0 + ak;
                *(uint4*)&As[ar * 72 + ak]      = *(const uint4*)(ap);
                *(uint4*)&As[ar * 72 + ak + 8]  = *(const uint4*)(ap + 8);
                *(uint4*)&As[ar * 72 + ak + 16] = *(const uint4*)(ap + 16);
                *(uint4*)&As[ar * 72 + ak + 24] = *(const uint4*)(ap + 24);
            }
            {   // stage B: bf16 copy from WT (zero-fill n >= N)
                const int nn = n0 + br;
                if (nn < N) {
                    const unsigned short* wp = WT + (size_t)nn * K + k0 + bk;
                    *(uint4*)&Bs[br * 72 + bk]     = *(const uint4*)(wp);
                    *(uint4*)&Bs[br * 72 + bk + 8] = *(const uint4*)(wp + 8);
                } else {
                    uint4 z = make_uint4(0, 0, 0, 0);
                    *(uint4*)&Bs[br * 72 + bk]     = z;
                    *(uint4*)&Bs[br * 72 + bk + 8] = z;
                }
            }
            __syncthreads();
#pragma unroll
            for (int ks = 0; ks < 2; ++ks) {
                s16x8 b0 = *(const s16x8*)&Bs[(wc + fr     ) * 72 + ks * 32 + fk];
                s16x8 b1 = *(const s16x8*)&Bs[(wc + 16 + fr) * 72 + ks * 32 + fk];
#pragma unroll
                for (int mt = 0; mt < 4; ++mt) {
                    s16x8 a = *(const s16x8*)&As[(wr + mt * 16 + fr) * 72 + ks * 32 + fk];
                    acc[mt][0] = __builtin_amdgcn_mfma_f32_16x16x32_bf16(a, b0, acc[mt][0], 0, 0, 0);
                    acc[mt][1] = __builtin_amdgcn_mfma_f32_16x16x32_bf16(a, b1, acc[mt][1], 0, 0, 0);
                }
            }
            __syncthreads();
        }
    }

    // ---- epilogue: C/D layout col=lane&15, row=(lane>>4)*4+reg ----
    const int orow = (l >> 4) * 4;
    float cs[2] = {0.f, 0.f}, cq[2] = {0.f, 0.f};
#pragma unroll
    for (int mt = 0; mt < 4; ++mt) {
#pragma unroll
        for (int nt = 0; nt < 2; ++nt) {
            const int cg = n0 + wc + nt * 16 + fr;
            if (cg < N) {
                const float bv = bias ? bias[cg] : 0.f;
#pragma unroll
                for (int r = 0; r < 4; ++r) {
                    const int rg = m0 + wr + mt * 16 + orow + r;
                    float v = acc[mt][nt][r] + bv;
                    if (resid) {
                        float rv = RBF
                            ? bf2f(((const unsigned short*)resid)[(size_t)rg * ldr + cg])
                            : ((const float*)resid)[(size_t)rg * ldr + cg];
                        v += rv;
                    }
                    if (ACT == 1)
                        v = 0.5f * v * (1.f + erff(v * 0.7071067811865475f));
                    if (OBF)
                        ((unsigned short*)outp)[(size_t)rg * ldo + cg] = f2bf(v);
                    else
                        ((float*)outp)[(size_t)rg * ldo + cg] = v;
                    if (STAT) { cs[nt] += v; cq[nt] += v * v; }
                }
            }
        }
    }
    if (STAT) {
        if (tid < 64) { sB[0][tid] = 0.f; sB[1][tid] = 0.f; }
        __syncthreads();
#pragma unroll
        for (int nt = 0; nt < 2; ++nt) {
            atomicAdd(&sB[0][wc + nt * 16 + fr], cs[nt]);
            atomicAdd(&sB[1][wc + nt * 16 + fr], cq[nt]);
        }
        __syncthreads();
        if (tid < 64 && (n0 + tid) < N) {
            atomicAdd(&sumP[n0 + tid], sB[0][tid]);
            atomicAdd(&sqP[n0 + tid],  sB[1][tid]);
        }
    }
}

// --------------------- causal conv + SiLU (bf16 in/out) --------------------
__global__ __launch_bounds__(256) void k_conv(const unsigned short* __restrict__ xz,
                                              const float* __restrict__ cw,
                                              const float* __restrict__ cb,
                                              unsigned short* __restrict__ xc)
{
    const int r = blockIdx.x;        // global row
    const int l = r & (GL - 1);      // position within graph
    const int d = threadIdx.x;       // 0..255
    float4 w4 = *(const float4*)&cw[d * 4];
    const float taps[4] = {w4.x, w4.y, w4.z, w4.w};
    float acc = cb[d];
#pragma unroll
    for (int k = 0; k < 4; ++k) {
        int ll = l - 3 + k;
        if (ll >= 0) acc += bf2f(xz[(size_t)(r - 3 + k) * 512 + d]) * taps[k];
    }
    float s = 1.f / (1.f + __expf(-acc));
    xc[(size_t)r * 256 + d] = f2bf(acc * s);
}

// ---------------- dt = softplus(proj[:,:8] @ dt_W + dt_b); B,C slices ------
__global__ __launch_bounds__(256) void k_dtbc(const float* __restrict__ proj,
                                              const float* __restrict__ dt_W,
                                              const float* __restrict__ dt_b,
                                              unsigned short* __restrict__ dtb,
                                              unsigned short* __restrict__ Bc,
                                              unsigned short* __restrict__ Cc)
{
    __shared__ float dtWS[8 * 256];
    __shared__ float dt_bS[256];
    __shared__ float projS[32 * 8];
    const int tid = threadIdx.x;
    const int r0 = blockIdx.x * 32;
    for (int i = tid; i < 2048; i += 256) dtWS[i] = dt_W[i];
    dt_bS[tid] = dt_b[tid];
    projS[tid] = proj[(size_t)(r0 + (tid >> 3)) * 40 + (tid & 7)];
    __syncthreads();

    const int c = tid;
    for (int rr = 0; rr < 32; ++rr) {
        float acc = dt_bS[c];
        const float* pr = &projS[rr * 8];
#pragma unroll
        for (int q = 0; q < 8; ++q) acc += pr[q] * dtWS[q * 256 + c];
        float e  = exp2_fast(-fabsf(acc) * 1.4426950408f);
        float sp = fmaxf(acc, 0.f) + 0.6931471806f * __log2f(1.f + e);
        dtb[(size_t)(r0 + rr) * 256 + c] = f2bf(sp);
    }
    // B = proj[:, 8:24], C = proj[:, 24:40]  (bf16)
    for (int e2 = tid; e2 < 1024; e2 += 256) {
        int rr = e2 >> 5, cc = e2 & 31;
        float v = proj[(size_t)(r0 + rr) * 40 + 8 + cc];
        if (cc < 16) Bc[(size_t)(r0 + rr) * 16 + cc] = f2bf(v);
        else         Cc[(size_t)(r0 + rr) * 16 + cc - 16] = f2bf(v);
    }
}

// ---------------- 8-lane-group sum via DPP (zero DS-pipe ops) ---------------
__device__ __forceinline__ float dpp_add8(float x)
{
    float y = x;
    int t;
    t = __builtin_amdgcn_update_dpp(0, __float_as_int(y), 0xB1, 0xF, 0xF, true);
    y += __int_as_float(t);
    t = __builtin_amdgcn_update_dpp(0, __float_as_int(y), 0x4E, 0xF, 0xF, true);
    y += __int_as_float(t);
    t = __builtin_amdgcn_update_dpp(0, __float_as_int(y), 0x141, 0xF, 0xF, true);
    y += __int_as_float(t);
    return y;
}

// ------------------------------ selective scan -----------------------------
// Round-10 config: block = (g, dblk32): 32 d x 16 states = 256 thr (4 waves);
// 512 blocks -> 2 blocks/CU. (Finer d-split triples FETCH via B/C
// redundancy — r11.) B/C now bf16 (halves the 8x-redundant B/C fetch).
// NOTE: yg aliases dtb - chunk c+1's dtb rows are prefetched to regs before
// chunk c's yg writeout; blocks touch disjoint (g, d-slice) columns.
__global__ __launch_bounds__(256) void k_scan(
    const unsigned short* __restrict__ dtb,
    const unsigned short* __restrict__ xcb,
    const unsigned short* __restrict__ xzb,
    const unsigned short* __restrict__ Bb,
    const unsigned short* __restrict__ Cb,
    const float* __restrict__ A_log, const float* __restrict__ Dp,
    unsigned short* __restrict__ yg)
{
    // floats: buf0 [0,3456) | buf1 [3456,6912) | ygL [6912, 6912+32*36)
    __shared__ __align__(16) float lds[2 * 3456 + 32 * 36];

    const int g    = blockIdx.x >> 3;
    const int dblk = blockIdx.x & 7;
    const int tid  = threadIdx.x;
    const int lane = tid & 63;
    const int dl   = (tid >> 6) * 8 + (lane >> 3);   // local d 0..31
    const int sp   = lane & 7;                       // state-pair index
    const int d0   = dblk * 32;
    const int d    = d0 + dl;
    const size_t rbase = (size_t)g * GL;

    // staging coords
    const int sdd = tid & 31, stq = tid >> 5;        // dt/xc: d-col, t-quad
    const int sbt = tid >> 4, sbi = tid & 15;        // B/C: t-row, state
    const int szt = tid >> 3, szi = tid & 7;         // z / writeout

    const float L2E = 1.44269504088896f;
    const float aA0 = -__expf(A_log[d * 16 + 2 * sp]) * L2E;
    const float aA1 = -__expf(A_log[d * 16 + 2 * sp + 1]) * L2E;
    const float Dpd = Dp[d];
    float h0 = 0.f, h1 = 0.f;

    float rdt[4], rxc[4];
    float rB0, rB1, rC0, rC1;
    ushort4 rz, zcur;

    // ---- prologue: load chunk 0 into registers ----
    {
        const size_t r0 = rbase;
#pragma unroll
        for (int j = 0; j < 4; ++j) {
            rdt[j] = bf2f(dtb[(r0 + stq * 4 + j) * 256 + d0 + sdd]);
            rxc[j] = bf2f(xcb[(r0 + stq * 4 + j) * 256 + d0 + sdd]);
        }
        rz  = *(const ushort4*)&xzb[(r0 + szt) * 512 + 256 + d0 + szi * 4];
        rB0 = bf2f(Bb[(r0 + sbt) * 16 + sbi]);
        rB1 = bf2f(Bb[(r0 + sbt + 16) * 16 + sbi]);
        rC0 = bf2f(Cb[(r0 + sbt) * 16 + sbi]);
        rC1 = bf2f(Cb[(r0 + sbt + 16) * 16 + sbi]);
    }
    zcur = rz;

    float* ygL = lds + 2 * 3456;

    for (int c = 0; c < NCH; ++c) {
        float* buf = lds + (c & 1) * 3456;
        // ---- commit staged registers to LDS (transposed fp32 tiles) ----
        *(float4*)&buf[sdd * 36 + stq * 4] =
            make_float4(rdt[0], rdt[1], rdt[2], rdt[3]);
        *(float4*)&buf[1152 + sdd * 36 + stq * 4] =
            make_float4(rxc[0], rxc[1], rxc[2], rxc[3]);
        buf[2304 + sbi * 36 + sbt]      = rB0;
        buf[2304 + sbi * 36 + sbt + 16] = rB1;
        buf[2880 + sbi * 36 + sbt]      = rC0;
        buf[2880 + sbi * 36 + sbt + 16] = rC1;
        zcur = rz;
        __syncthreads();

        // ---- prefetch chunk c+1 (lands during the 32 steps below) ----
        if (c + 1 < NCH) {
            const size_t r0 = rbase + (size_t)(c + 1) * SCH;
#pragma unroll
            for (int j = 0; j < 4; ++j) {
                rdt[j] = bf2f(dtb[(r0 + stq * 4 + j) * 256 + d0 + sdd]);
                rxc[j] = bf2f(xcb[(r0 + stq * 4 + j) * 256 + d0 + sdd]);
            }
            rz  = *(const ushort4*)&xzb[(r0 + szt) * 512 + 256 + d0 + szi * 4];
            rB0 = bf2f(Bb[(r0 + sbt) * 16 + sbi]);
            rB1 = bf2f(Bb[(r0 + sbt + 16) * 16 + sbi]);
            rC0 = bf2f(Cb[(r0 + sbt) * 16 + sbi]);
            rC1 = bf2f(Cb[(r0 + sbt + 16) * 16 + sbi]);
        }

        // ---- 32 scan steps from LDS ----
        const float* pdt = buf + dl * 36;
        const float* pxc = buf + 1152 + dl * 36;
        const float* pB0 = buf + 2304 + (2 * sp) * 36;
        const float* pB1 = buf + 2304 + (2 * sp + 1) * 36;
        const float* pC0 = buf + 2880 + (2 * sp) * 36;
        const float* pC1 = buf + 2880 + (2 * sp + 1) * 36;
        float yk[4] = {0.f, 0.f, 0.f, 0.f};
#pragma unroll
        for (int t4 = 0; t4 < 8; ++t4) {
            const float4 dt4 = *(const float4*)&pdt[t4 * 4];
            const float4 xc4 = *(const float4*)&pxc[t4 * 4];
            const float4 B04 = *(const float4*)&pB0[t4 * 4];
            const float4 B14 = *(const float4*)&pB1[t4 * 4];
            const float4 C04 = *(const float4*)&pC0[t4 * 4];
            const float4 C14 = *(const float4*)&pC1[t4 * 4];
#define SSTEP(J)                                                            \
            {                                                               \
                const float dt = ((const float*)&dt4)[J];                   \
                const float xc = ((const float*)&xc4)[J];                   \
                const float dtx = dt * xc;                                  \
                h0 = h0 * exp2_fast(dt * aA0) + dtx * ((const float*)&B04)[J]; \
                h1 = h1 * exp2_fast(dt * aA1) + dtx * ((const float*)&B14)[J]; \
                float yv = h0 * ((const float*)&C04)[J]                     \
                         + h1 * ((const float*)&C14)[J];                    \
                yv = dpp_add8(yv);                                          \
                yv = fmaf(xc, Dpd, yv);                                     \
                const int tt = t4 * 4 + (J);                                \
                yk[t4 >> 1] = (sp == (tt & 7)) ? yv : yk[t4 >> 1];          \
            }
            SSTEP(0) SSTEP(1) SSTEP(2) SSTEP(3)
#undef SSTEP
        }
        // stage captured y to LDS: lane sp holds t = 8k+sp for its d
#pragma unroll
        for (int k = 0; k < 4; ++k)
            ygL[(k * 8 + sp) * 36 + dl] = yk[k];
        __syncthreads();

        // ---- coalesced bf16 writeout with silu(z) from registers ----
        {
            const size_t rr0 = rbase + (size_t)c * SCH;
            float4 y4 = *(const float4*)&ygL[szt * 36 + szi * 4];
            float z0 = bf2f(zcur.x), z1 = bf2f(zcur.y);
            float z2 = bf2f(zcur.z), z3 = bf2f(zcur.w);
            float o0 = y4.x * (z0 / (1.f + __expf(-z0)));
            float o1 = y4.y * (z1 / (1.f + __expf(-z1)));
            float o2 = y4.z * (z2 / (1.f + __expf(-z2)));
            float o3 = y4.w * (z3 / (1.f + __expf(-z3)));
            uint2 packed;
            packed.x = cvt_pk_bf16(o0, o1);
            packed.y = cvt_pk_bf16(o2, o3);
            *(uint2*)&yg[(rr0 + szt) * 256 + d0 + szi * 4] = packed;
        }
    }
}

// --- add + BN1/BN2 (params per-thread; bf16 in, bf16 out, fp32 stats) ------
__global__ __launch_bounds__(256) void k_add(const unsigned short* __restrict__ h1p,
                                             const unsigned short* __restrict__ p2,
                                             const float* __restrict__ st,
                                             const float* __restrict__ g1,
                                             const float* __restrict__ be1,
                                             const float* __restrict__ g2,
                                             const float* __restrict__ be2,
                                             unsigned short* __restrict__ outp,
                                             float* __restrict__ sumP,
                                             float* __restrict__ sqP)
{
    const int c = threadIdx.x & 127, half = threadIdx.x >> 7;
    const float inv = 1.f / 32768.f;
    const float m1 = st[c] * inv, v1 = st[128 + c] * inv - m1 * m1;
    const float a1 = g1[c] * rsqrtf(v1 + 1e-5f), b1 = be1[c] - m1 * a1;
    const float m2 = st[256 + c] * inv, v2 = st[384 + c] * inv - m2 * m2;
    const float a2 = g2[c] * rsqrtf(v2 + 1e-5f), b2 = be2[c] - m2 * a2;

    const int rbase = blockIdx.x * 64 + half * 32;
    float s = 0.f, q = 0.f;
    for (int i = 0; i < 32; ++i) {
        size_t idx = (size_t)(rbase + i) * 128 + c;
        float v = bf2f(h1p[idx]) * a1 + b1 + bf2f(p2[idx]) * a2 + b2;
        outp[idx] = f2bf(v); s += v; q += v * v;
    }
    __shared__ float sh[2][2][128];
    sh[0][half][c] = s; sh[1][half][c] = q;
    __syncthreads();
    if (threadIdx.x < 128) {
        atomicAdd(&sumP[c], sh[0][0][c] + sh[0][1][c]);
        atomicAdd(&sqP[c],  sh[1][0][c] + sh[1][1][c]);
    }
}

// ---- fold1: block-per-column; W1eT bf16 [256][128] + b1e fp32 -------------
__global__ __launch_bounds__(128) void k_fold1(
    const float* __restrict__ sumP, const float* __restrict__ sqP,
    const float* __restrict__ gam, const float* __restrict__ bet,
    const float* __restrict__ W1, const float* __restrict__ b1in,
    unsigned short* __restrict__ W1eT, float* __restrict__ b1e)
{
    __shared__ float red[128];
    const int n = blockIdx.x, k = threadIdx.x;
    const float inv = 1.f / 32768.f;
    const float m = sumP[k] * inv, v = sqP[k] * inv - m * m;
    const float a = gam[k] * rsqrtf(v + 1e-5f), bs = bet[k] - m * a;
    const float wv = W1[k * 256 + n];
    W1eT[n * 128 + k] = f2bf(a * wv);
    red[k] = bs * wv;
    __syncthreads();
    for (int s = 64; s > 0; s >>= 1) {
        if (k < s) red[k] += red[k + s];
        __syncthreads();
    }
    if (k == 0) b1e[n] = red[0] + b1in[n];
}

// ---- fold2: block-per-column; W2eT bf16 [128][256] + b2e fp32 -------------
__global__ __launch_bounds__(256) void k_fold2(
    const float* __restrict__ sumP, const float* __restrict__ sqP,
    const float* __restrict__ gam, const float* __restrict__ bet,
    const float* __restrict__ W2, const float* __restrict__ b2in,
    unsigned short* __restrict__ W2eT, float* __restrict__ b2e)
{
    __shared__ float red[256];
    const int n = blockIdx.x, k = threadIdx.x;
    const float inv = 1.f / 32768.f;
    const float m = sumP[k] * inv, v = sqP[k] * inv - m * m;
    const float a = gam[k] * rsqrtf(v + 1e-5f), bs = bet[k] - m * a;
    const float wv = W2[k * 128 + n];
    W2eT[n * 256 + k] = f2bf(a * wv);
    red[k] = bs * wv;
    __syncthreads();
    for (int s = 128; s > 0; s >>= 1) {
        if (k < s) red[k] += red[k + s];
        __syncthreads();
    }
    if (k == 0) b2e[n] = red[0] + b2in[n];
}

// ------------- BN3 (params per-thread, amortized; bf16 input) ---------------
__global__ __launch_bounds__(256) void k_bn3(const unsigned short* __restrict__ out2,
                                             const float* __restrict__ sumP,
                                             const float* __restrict__ sqP,
                                             const float* __restrict__ gam,
                                             const float* __restrict__ bet,
                                             float* __restrict__ dout)
{
    const int cq = (threadIdx.x & 31) * 4;     // column quad
    const int rw = threadIdx.x >> 5;           // 0..7
    const float inv = 1.f / 32768.f;
    float a[4], b[4];
#pragma unroll
    for (int j = 0; j < 4; ++j) {
        float m = sumP[cq + j] * inv, v = sqP[cq + j] * inv - m * m;
        a[j] = gam[cq + j] * rsqrtf(v + 1e-5f);
        b[j] = bet[cq + j] - m * a[j];
    }
    const int r0 = blockIdx.x * 128 + rw;
#pragma unroll 4
    for (int k = 0; k < 16; ++k) {
        const size_t r = r0 + k * 8;
        ushort4 u = *(const ushort4*)&out2[r * 128 + cq];
        float4 v;
        v.x = bf2f(u.x) * a[0] + b[0]; v.y = bf2f(u.y) * a[1] + b[1];
        v.z = bf2f(u.z) * a[2] + b[2]; v.w = bf2f(u.w) * a[3] + b[3];
        *(float4*)&dout[r * 128 + cq] = v;
    }
}

// ------------------------------- launch ------------------------------------
extern "C" void kernel_launch(void* const* d_in, const int* in_sizes, int n_in,
                              void* d_out, int out_size, void* d_ws, size_t ws_size,
                              hipStream_t stream)
{
    (void)in_sizes; (void)n_in; (void)out_size; (void)ws_size;
    const float* x      = (const float*)d_in[0];
    const int*   ei     = (const int*)d_in[1];
    // d_in[2] = batch (unused: equal-size sorted graphs == reshape)
    const float* W_root = (const float*)d_in[3];
    const float* W_rel  = (const float*)d_in[4];
    const float* b_rel  = (const float*)d_in[5];
    const float* n1_g = (const float*)d_in[6],  *n1_b = (const float*)d_in[7];
    const float* n2_g = (const float*)d_in[8],  *n2_b = (const float*)d_in[9];
    const float* n3_g = (const float*)d_in[10], *n3_b = (const float*)d_in[11];
    const float* m1_g = (const float*)d_in[12], *m1_b = (const float*)d_in[13];
    const float* W1   = (const float*)d_in[14], *b1   = (const float*)d_in[15];
    const float* m2_g = (const float*)d_in[16], *m2_b = (const float*)d_in[17];
    const float* W2   = (const float*)d_in[18], *b2   = (const float*)d_in[19];
    const float* in_W   = (const float*)d_in[20];
    const float* conv_w = (const float*)d_in[21], *conv_b = (const float*)d_in[22];
    const float* xproj_W= (const float*)d_in[23];
    const float* dt_W   = (const float*)d_in[24], *dt_b = (const float*)d_in[25];
    const float* A_log  = (const float*)d_in[26], *Dp   = (const float*)d_in[27];
    const float* out_W  = (const float*)d_in[28];

    float* ws = (float*)d_ws;
    // small region
    float* st  = ws;             // 2048 used (S1..S5 sums/sumsqs)
    float* b1e = ws + 8192;      // 256
    float* b2e = ws + 8448;      // 128
    // bf16 transposed weights (shorts)
    unsigned short* wsh   = (unsigned short*)(ws + 8704);
    unsigned short* WrelT  = wsh;            // 128x128 = 16384
    unsigned short* WrootT = wsh + 16384;    // 16384
    unsigned short* inWT   = wsh + 32768;    // 512x128 = 65536
    unsigned short* xprojT = wsh + 98304;    // 40x256  = 10240
    unsigned short* outWT  = wsh + 108544;   // 128x256 = 32768
    unsigned short* W1eT   = wsh + 141312;   // 256x128 = 32768
    unsigned short* W2eT   = wsh + 174080;   // 128x256 = 32768 (end 206848)
    // big buffers (float-unit offsets; bf16 buffers occupy half the floats)
    float* big = ws + 112640;
    unsigned short* agg16 = (unsigned short*)(big);             // 4.19M sh
    unsigned short* p216  = agg16;                              // reuse
    unsigned short* h1p16 = (unsigned short*)(big + 2097152);   // 4.19M sh
    unsigned short* x16   = (unsigned short*)(big + 4194304);   // 4.19M sh
    unsigned short* xz16  = (unsigned short*)(big + 6291456);   // 16.78M sh
    unsigned short* xc16  = (unsigned short*)(big + 14680064);  // 8.39M sh
    float* proj = big + 18874368;                               // 1.31M f
    unsigned short* dtb16 = (unsigned short*)(big + 20185088);  // 8.39M sh (yg alias)
    unsigned short* yg16  = dtb16;
    unsigned short* Bc16  = (unsigned short*)(big + 24379392);  // 524288 sh
    unsigned short* Cc16  = (unsigned short*)(big + 24903680);  // 524288 sh
    unsigned short* outb16 = (unsigned short*)(big + 25427968); // 4.19M sh
    unsigned short* out216 = (unsigned short*)(big + 27525120); // 4.19M sh
    unsigned short* g16    = (unsigned short*)(big + 29622272); // 8.39M sh

    // CSR scratch lives in the h1p16 region (dead until the h1 GEMM writes it)
    int* ideg   = (int*)h1p16;            // 32768
    int* ibase  = ideg + 32768;           // 32769
    int* icur   = ideg + 65552;           // 32768 (16B-aligned)
    int* isrcs  = ideg + 98320;           // 524288

    hipMemsetAsync(st, 0, 2048 * sizeof(float), stream);
    hipMemsetAsync(ideg, 0, 32768 * sizeof(int), stream);

    // ---- preps: weights (bf16 transposes) + x -> bf16 ----
    k_prepw5<<<552, 256, 0, stream>>>(W_rel, WrelT, W_root, WrootT,
                                      in_W, inWT, xproj_W, xprojT,
                                      out_W, outWT);
    k_prepx<<<2048, 256, 0, stream>>>(x, x16);

    // ---- CSR build + gather (bf16) ----
    k_hist<<<512, 256, 0, stream>>>(ei, ideg);
    k_scanidx<<<1, 1024, 0, stream>>>(ideg, ibase, icur);
    k_fill<<<512, 256, 0, stream>>>(ei, icur, isrcs);
    k_gather<<<8192, 256, 0, stream>>>(x16, ibase, isrcs, agg16);

    // h1_pre = agg@W_rel + b_rel + x@W_root + x  [S1]  (bf16 A/resid/out)
    gemm_mfma<true, 0, true, true, true><<<dim3(256, 2), 256, 0, stream>>>(
        agg16, WrelT, x16, WrootT, NROWS, 128, 128, 128,
        b_rel, x16, 128, h1p16, st + 0, st + 128);
    // xz = x @ in_W  (bf16 A, bf16 out)
    gemm_mfma<false, 0, false, true, false><<<dim3(256, 8), 256, 0, stream>>>(
        x16, inWT, nullptr, nullptr, NROWS, 512, 128, 512,
        nullptr, nullptr, 0, xz16, nullptr, nullptr);
    k_conv<<<32768, 256, 0, stream>>>(xz16, conv_w, conv_b, xc16);
    // proj = xc @ xproj_W (bf16 A, fp32 out, N=40)
    gemm_mfma<false, 0, false, false, false><<<dim3(256, 1), 256, 0, stream>>>(
        xc16, xprojT, nullptr, nullptr, NROWS, 40, 256, 40,
        nullptr, nullptr, 0, proj, nullptr, nullptr);
    k_dtbc<<<1024, 256, 0, stream>>>(proj, dt_W, dt_b, dtb16, Bc16, Cc16);
    k_scan<<<512, 256, 0, stream>>>(dtb16, xc16, xz16, Bc16, Cc16, A_log, Dp, yg16);
    // p2 = yg @ out_W + x  [S2]  (bf16 A/resid/out)
    gemm_mfma<false, 0, true, true, true><<<dim3(256, 2), 256, 0, stream>>>(
        yg16, outWT, nullptr, nullptr, NROWS, 128, 256, 128,
        nullptr, x16, 128, p216, st + 256, st + 384);
    // out = BN1(h1_pre) + BN2(p2)  [S3]  (bf16 out)
    k_add<<<512, 256, 0, stream>>>(h1p16, p216, st, n1_g, n1_b, n2_g, n2_b,
                                   outb16, st + 512, st + 640);
    k_fold1<<<256, 128, 0, stream>>>(st + 512, st + 640, m1_g, m1_b, W1, b1, W1eT, b1e);
    // g = gelu(out @ W1e + b1e)  [S4]  (bf16 A, bf16 out)
    gemm_mfma<false, 1, true, true, false><<<dim3(256, 4), 256, 0, stream>>>(
        outb16, W1eT, nullptr, nullptr, NROWS, 256, 128, 256,
        b1e, nullptr, 0, g16, st + 768, st + 1024);
    k_fold2<<<128, 256, 0, stream>>>(st + 768, st + 1024, m2_g, m2_b, W2, b2, W2eT, b2e);
    // out2 = g @ W2e + b2e + out  [S5]  (bf16 A/resid, bf16 out)
    gemm_mfma<false, 0, true, true, true><<<dim3(256, 2), 256, 0, stream>>>(
        g16, W2eT, nullptr, nullptr, NROWS, 128, 256, 128,
        b2e, outb16, 128, out216, st + 1280, st + 1408);
    // d_out = BN3(out2)  (params computed in-kernel from S5)
    k_bn3<<<256, 256, 0, stream>>>(out216, st + 1280, st + 1408, n3_g, n3_b,
                                   (float*)d_out);
}

// Round 15
// 341.064 us; speedup vs baseline: 1.3271x; 1.1198x over previous
//
#include <hip/hip_runtime.h>

// ---------------------------------------------------------------------------
// GraphMambaConv: N=32768 nodes, C=128, G=64 graphs x L=512, E=524288 edges,
// D_INNER=256, D_STATE=16, DT_RANK=8, D_CONV=4.
//
// Round 15: overhead fixes in the sub-profile tier.
//  - k_gather: 4-deep edge ILP (4 independent row loads in flight; r11 had
//    regressed to 1 dependent load/iter).
//  - k_conv: 2 rows/block (window sharing: 5 loads per 2 outputs, was 8;
//    pairs never straddle graphs since GL even).
//  Scan kept at r10 config (~58us practical floor: issue/latency structural,
//  fetch-insensitive per r14 measurement).
// ---------------------------------------------------------------------------

#define NROWS 32768
#define CDIM  128
#define EDGES 524288
#define GL    512
#define SCH   32          // scan chunk (timesteps)
#define NCH   (GL / SCH)  // 16 chunks

typedef short s16x8 __attribute__((ext_vector_type(8)));
typedef float f32x4 __attribute__((ext_vector_type(4)));

__device__ __forceinline__ unsigned short f2bf(float f)
{
    unsigned u = __float_as_uint(f);
    u += 0x7FFF + ((u >> 16) & 1);          // RNE
    return (unsigned short)(u >> 16);
}

__device__ __forceinline__ float bf2f(unsigned short u)
{
    return __uint_as_float((unsigned)u << 16);
}

__device__ __forceinline__ unsigned cvt_pk_bf16(float lo, float hi)
{
    unsigned r;
    asm("v_cvt_pk_bf16_f32 %0, %1, %2" : "=v"(r) : "v"(lo), "v"(hi));
    return r;
}

__device__ __forceinline__ float exp2_fast(float x)
{
    float r;
    asm("v_exp_f32 %0, %1" : "=v"(r) : "v"(x));   // v_exp_f32 computes 2^x
    return r;
}

// ------------------------- CSR build: histogram ----------------------------
__global__ __launch_bounds__(256) void k_hist(const int* __restrict__ ei,
                                              int* __restrict__ deg)
{
    const int e = blockIdx.x * 1024 + threadIdx.x * 4;
    const int4 d4 = *(const int4*)&ei[EDGES + e];
    atomicAdd(&deg[d4.x], 1);
    atomicAdd(&deg[d4.y], 1);
    atomicAdd(&deg[d4.z], 1);
    atomicAdd(&deg[d4.w], 1);
}

// ---------------- CSR build: exclusive prefix scan (1 block) ---------------
__global__ __launch_bounds__(1024) void k_scanidx(const int* __restrict__ deg,
                                                  int* __restrict__ base,
                                                  int* __restrict__ cursor)
{
    __shared__ int ps[1024];
    const int tid = threadIdx.x;
    int loc[32];
    int s = 0;
#pragma unroll
    for (int i = 0; i < 32; ++i) { loc[i] = deg[tid * 32 + i]; s += loc[i]; }
    ps[tid] = s;
    __syncthreads();
    for (int off = 1; off < 1024; off <<= 1) {
        int v = (tid >= off) ? ps[tid - off] : 0;
        __syncthreads();
        ps[tid] += v;
        __syncthreads();
    }
    int run = tid ? ps[tid - 1] : 0;
#pragma unroll
    for (int i = 0; i < 32; ++i) {
        base[tid * 32 + i] = run;
        cursor[tid * 32 + i] = run;
        run += loc[i];
    }
    if (tid == 0) base[32768] = EDGES;
}

// ------------------------- CSR build: fill src lists -----------------------
__global__ __launch_bounds__(256) void k_fill(const int* __restrict__ ei,
                                              int* __restrict__ cursor,
                                              int* __restrict__ srcs)
{
    const int e = blockIdx.x * 1024 + threadIdx.x * 4;
    const int4 s4 = *(const int4*)&ei[e];
    const int4 d4 = *(const int4*)&ei[EDGES + e];
    int p;
    p = atomicAdd(&cursor[d4.x], 1); srcs[p] = s4.x;
    p = atomicAdd(&cursor[d4.y], 1); srcs[p] = s4.y;
    p = atomicAdd(&cursor[d4.z], 1); srcs[p] = s4.z;
    p = atomicAdd(&cursor[d4.w], 1); srcs[p] = s4.w;
}

// ------------------- x -> bf16 (one pass, 8 elems/thread) ------------------
__global__ __launch_bounds__(256) void k_prepx(const float* __restrict__ x,
                                               unsigned short* __restrict__ x16)
{
    const size_t i = ((size_t)blockIdx.x * 256 + threadIdx.x) * 8;
    float4 a = *(const float4*)&x[i];
    float4 b = *(const float4*)&x[i + 4];
    uint4 p;
    p.x = cvt_pk_bf16(a.x, a.y); p.y = cvt_pk_bf16(a.z, a.w);
    p.z = cvt_pk_bf16(b.x, b.y); p.w = cvt_pk_bf16(b.z, b.w);
    *(uint4*)&x16[i] = p;
}

// ------- gather (bf16 in/out, fp32 accumulate, 4-deep edge ILP) ------------
__global__ __launch_bounds__(256) void k_gather(const unsigned short* __restrict__ x16,
                                                const int* __restrict__ base,
                                                const int* __restrict__ srcs,
                                                unsigned short* __restrict__ agg16)
{
    const int node = blockIdx.x * 4 + (threadIdx.x >> 6);
    const int lane = threadIdx.x & 63;
    const int b0 = base[node], b1 = base[node + 1];
    float a0 = 0.f, a1 = 0.f, p0 = 0.f, p1 = 0.f;
    float q0 = 0.f, q1 = 0.f, r0 = 0.f, r1 = 0.f;
    int i = b0;
    for (; i + 4 <= b1; i += 4) {
        const int s0 = srcs[i],     s1 = srcs[i + 1];
        const int s2 = srcs[i + 2], s3 = srcs[i + 3];
        const unsigned v0 = *(const unsigned*)&x16[(size_t)s0 * 128 + lane * 2];
        const unsigned v1 = *(const unsigned*)&x16[(size_t)s1 * 128 + lane * 2];
        const unsigned v2 = *(const unsigned*)&x16[(size_t)s2 * 128 + lane * 2];
        const unsigned v3 = *(const unsigned*)&x16[(size_t)s3 * 128 + lane * 2];
        a0 += bf2f((unsigned short)(v0 & 0xFFFF)); a1 += bf2f((unsigned short)(v0 >> 16));
        p0 += bf2f((unsigned short)(v1 & 0xFFFF)); p1 += bf2f((unsigned short)(v1 >> 16));
        q0 += bf2f((unsigned short)(v2 & 0xFFFF)); q1 += bf2f((unsigned short)(v2 >> 16));
        r0 += bf2f((unsigned short)(v3 & 0xFFFF)); r1 += bf2f((unsigned short)(v3 >> 16));
    }
    for (; i < b1; ++i) {
        const int s = srcs[i];
        const unsigned v = *(const unsigned*)&x16[(size_t)s * 128 + lane * 2];
        a0 += bf2f((unsigned short)(v & 0xFFFF));
        a1 += bf2f((unsigned short)(v >> 16));
    }
    a0 += (p0 + q0) + r0;
    a1 += (p1 + q1) + r1;
    *(unsigned*)&agg16[(size_t)node * 128 + lane * 2] = cvt_pk_bf16(a0, a1);
}

// ---- merged weight prep: 5 transposes (bf16) in one launch, 552 blocks ----
__global__ __launch_bounds__(256) void k_prepw5(
    const float* __restrict__ Wa, unsigned short* __restrict__ Ta,
    const float* __restrict__ Wb, unsigned short* __restrict__ Tb,
    const float* __restrict__ Wc, unsigned short* __restrict__ Tc,
    const float* __restrict__ Wd, unsigned short* __restrict__ Td,
    const float* __restrict__ We, unsigned short* __restrict__ Te)
{
    const int idx = blockIdx.x * 256 + threadIdx.x;
    const float* W; unsigned short* T; int rel, ks, N;
    if (idx < 16384)       { W = Wa; T = Ta; rel = idx;          ks = 7; N = 128; }
    else if (idx < 32768)  { W = Wb; T = Tb; rel = idx - 16384;  ks = 7; N = 128; }
    else if (idx < 98304)  { W = Wc; T = Tc; rel = idx - 32768;  ks = 7; N = 512; }
    else if (idx < 108544) { W = Wd; T = Td; rel = idx - 98304;  ks = 8; N = 40;  }
    else                   { W = We; T = Te; rel = idx - 108544; ks = 8; N = 128; }
    const int K = 1 << ks;
    const int n = rel >> ks, k = rel & (K - 1);
    T[rel] = f2bf(W[(size_t)k * N + n]);
}

// ------------------------- MFMA GEMM (bf16 in, fp32 acc) --------------------
// out = epi( A0@W0 [+ A1@W1] [+bias] [+resid] ), optional column stats.
// A: MxK bf16 row-major (copy-staged). WT: NxK bf16 row-major.
// Out fp32/bf16 (OBF). Resid fp32/bf16 (RBF).
// Tile 128x64, BK=64, 4 waves each 64x32 -> 8 mfma_f32_16x16x32_bf16/K-step.
template<bool DUAL, int ACT, bool STAT, bool OBF, bool RBF>
__global__ __launch_bounds__(256)
void gemm_mfma(const unsigned short* __restrict__ A0,
               const unsigned short* __restrict__ W0T,
               const unsigned short* __restrict__ A1p,
               const unsigned short* __restrict__ W1Tp,
               int M, int N, int K, int ldo,
               const float* __restrict__ bias,
               const void* __restrict__ resid, int ldr,
               void* __restrict__ outp,
               float* __restrict__ sumP, float* __restrict__ sqP)
{
    __shared__ __align__(16) unsigned short As[128 * 72];  // [m][k], pad 8
    __shared__ __align__(16) unsigned short Bs[64 * 72];   // [n][k], pad 8
    __shared__ float sB[2][64];

    const int tid = threadIdx.x;
    const int m0 = blockIdx.x * 128;
    const int n0 = blockIdx.y * 64;

    const int ar = tid >> 1, ak = (tid & 1) * 32;   // A staging: 32 elems/thr
    const int br = tid >> 2, bk = (tid & 3) * 16;   // B staging: 16 elems/thr

    const int w  = tid >> 6, l = tid & 63;
    const int wr = (w >> 1) * 64, wc = (w & 1) * 32;
    const int fr = l & 15;               // frag row/col
    const int fk = (l >> 4) * 8;         // frag k base

    f32x4 acc[4][2];
#pragma unroll
    for (int i = 0; i < 4; ++i)
#pragma unroll
        for (int j = 0; j < 2; ++j) acc[i][j] = (f32x4){0.f, 0.f, 0.f, 0.f};

    const int npass = DUAL ? 2 : 1;
    for (int pass = 0; pass < npass; ++pass) {
        const unsigned short* A = (DUAL && pass) ? A1p : A0;
        const unsigned short* WT = (DUAL && pass) ? W1Tp : W0T;
        for (int k0 = 0; k0 < K; k0 += 64) {
            {   // stage A: straight bf16 copy, 4x uint4 per thread
                const unsigned short* ap = A + (size_t)(m0 + ar) * K + k0 + ak;
                *(uint4*)&As[ar * 72 + ak]      = *(const uint4*)(ap);
                *(uint4*)&As[ar * 72 + ak + 8]  = *(const uint4*)(ap + 8);
                *(uint4*)&As[ar * 72 + ak + 16] = *(const uint4*)(ap + 16);
                *(uint4*)&As[ar * 72 + ak + 24] = *(const uint4*)(ap + 24);
            }
            {   // stage B: bf16 copy from WT (zero-fill n >= N)
                const int nn = n0 + br;
                if (nn < N) {
                    const unsigned short* wp = WT + (size_t)nn * K + k0 + bk;
                    *(uint4*)&Bs[br * 72 + bk]     = *(const uint4*)(wp);
                    *(uint4*)&Bs[br * 72 + bk + 8] = *(const uint4*)(wp + 8);
                } else {
                    uint4 z = make_uint4(0, 0, 0, 0);
                    *(uint4*)&Bs[br * 72 + bk]     = z;
                    *(uint4*)&Bs[br * 72 + bk + 8] = z;
                }
            }
            __syncthreads();
#pragma unroll
            for (int ks = 0; ks < 2; ++ks) {
                s16x8 b0 = *(const s16x8*)&Bs[(wc + fr     ) * 72 + ks * 32 + fk];
                s16x8 b1 = *(const s16x8*)&Bs[(wc + 16 + fr) * 72 + ks * 32 + fk];
#pragma unroll
                for (int mt = 0; mt < 4; ++mt) {
                    s16x8 a = *(const s16x8*)&As[(wr + mt * 16 + fr) * 72 + ks * 32 + fk];
                    acc[mt][0] = __builtin_amdgcn_mfma_f32_16x16x32_bf16(a, b0, acc[mt][0], 0, 0, 0);
                    acc[mt][1] = __builtin_amdgcn_mfma_f32_16x16x32_bf16(a, b1, acc[mt][1], 0, 0, 0);
                }
            }
            __syncthreads();
        }
    }

    // ---- epilogue: C/D layout col=lane&15, row=(lane>>4)*4+reg ----
    const int orow = (l >> 4) * 4;
    float cs[2] = {0.f, 0.f}, cq[2] = {0.f, 0.f};
#pragma unroll
    for (int mt = 0; mt < 4; ++mt) {
#pragma unroll
        for (int nt = 0; nt < 2; ++nt) {
            const int cg = n0 + wc + nt * 16 + fr;
            if (cg < N) {
                const float bv = bias ? bias[cg] : 0.f;
#pragma unroll
                for (int r = 0; r < 4; ++r) {
                    const int rg = m0 + wr + mt * 16 + orow + r;
                    float v = acc[mt][nt][r] + bv;
                    if (resid) {
                        float rv = RBF
                            ? bf2f(((const unsigned short*)resid)[(size_t)rg * ldr + cg])
                            : ((const float*)resid)[(size_t)rg * ldr + cg];
                        v += rv;
                    }
                    if (ACT == 1)
                        v = 0.5f * v * (1.f + erff(v * 0.7071067811865475f));
                    if (OBF)
                        ((unsigned short*)outp)[(size_t)rg * ldo + cg] = f2bf(v);
                    else
                        ((float*)outp)[(size_t)rg * ldo + cg] = v;
                    if (STAT) { cs[nt] += v; cq[nt] += v * v; }
                }
            }
        }
    }
    if (STAT) {
        if (tid < 64) { sB[0][tid] = 0.f; sB[1][tid] = 0.f; }
        __syncthreads();
#pragma unroll
        for (int nt = 0; nt < 2; ++nt) {
            atomicAdd(&sB[0][wc + nt * 16 + fr], cs[nt]);
            atomicAdd(&sB[1][wc + nt * 16 + fr], cq[nt]);
        }
        __syncthreads();
        if (tid < 64 && (n0 + tid) < N) {
            atomicAdd(&sumP[n0 + tid], sB[0][tid]);
            atomicAdd(&sqP[n0 + tid],  sB[1][tid]);
        }
    }
}

// ----- causal conv + SiLU (bf16 in/out, 2 rows/block, shared window) -------
__global__ __launch_bounds__(256) void k_conv(const unsigned short* __restrict__ xz,
                                              const float* __restrict__ cw,
                                              const float* __restrict__ cb,
                                              unsigned short* __restrict__ xc)
{
    const int r0 = blockIdx.x * 2;    // even; pair never straddles a graph
    const int l0 = r0 & (GL - 1);
    const int d = threadIdx.x;        // 0..255
    float4 w4 = *(const float4*)&cw[d * 4];
    float vals[5];
#pragma unroll
    for (int j = 0; j < 5; ++j) {
        const int ll = l0 - 3 + j;
        vals[j] = (ll >= 0) ? bf2f(xz[(size_t)(r0 - 3 + j) * 512 + d]) : 0.f;
    }
    float acc0 = cb[d] + vals[0] * w4.x + vals[1] * w4.y
                       + vals[2] * w4.z + vals[3] * w4.w;
    float acc1 = cb[d] + vals[1] * w4.x + vals[2] * w4.y
                       + vals[3] * w4.z + vals[4] * w4.w;
    const float s0 = 1.f / (1.f + __expf(-acc0));
    const float s1 = 1.f / (1.f + __expf(-acc1));
    xc[(size_t)r0 * 256 + d]       = f2bf(acc0 * s0);
    xc[(size_t)(r0 + 1) * 256 + d] = f2bf(acc1 * s1);
}

// ---------------- dt = softplus(proj[:,:8] @ dt_W + dt_b); B,C slices ------
__global__ __launch_bounds__(256) void k_dtbc(const float* __restrict__ proj,
                                              const float* __restrict__ dt_W,
                                              const float* __restrict__ dt_b,
                                              unsigned short* __restrict__ dtb,
                                              unsigned short* __restrict__ Bc,
                                              unsigned short* __restrict__ Cc)
{
    __shared__ float dtWS[8 * 256];
    __shared__ float dt_bS[256];
    __shared__ float projS[32 * 8];
    const int tid = threadIdx.x;
    const int r0 = blockIdx.x * 32;
    for (int i = tid; i < 2048; i += 256) dtWS[i] = dt_W[i];
    dt_bS[tid] = dt_b[tid];
    projS[tid] = proj[(size_t)(r0 + (tid >> 3)) * 40 + (tid & 7)];
    __syncthreads();

    const int c = tid;
    for (int rr = 0; rr < 32; ++rr) {
        float acc = dt_bS[c];
        const float* pr = &projS[rr * 8];
#pragma unroll
        for (int q = 0; q < 8; ++q) acc += pr[q] * dtWS[q * 256 + c];
        float e  = exp2_fast(-fabsf(acc) * 1.4426950408f);
        float sp = fmaxf(acc, 0.f) + 0.6931471806f * __log2f(1.f + e);
        dtb[(size_t)(r0 + rr) * 256 + c] = f2bf(sp);
    }
    // B = proj[:, 8:24], C = proj[:, 24:40]  (bf16)
    for (int e2 = tid; e2 < 1024; e2 += 256) {
        int rr = e2 >> 5, cc = e2 & 31;
        float v = proj[(size_t)(r0 + rr) * 40 + 8 + cc];
        if (cc < 16) Bc[(size_t)(r0 + rr) * 16 + cc] = f2bf(v);
        else         Cc[(size_t)(r0 + rr) * 16 + cc - 16] = f2bf(v);
    }
}

// ---------------- 8-lane-group sum via DPP (zero DS-pipe ops) ---------------
__device__ __forceinline__ float dpp_add8(float x)
{
    float y = x;
    int t;
    t = __builtin_amdgcn_update_dpp(0, __float_as_int(y), 0xB1, 0xF, 0xF, true);
    y += __int_as_float(t);
    t = __builtin_amdgcn_update_dpp(0, __float_as_int(y), 0x4E, 0xF, 0xF, true);
    y += __int_as_float(t);
    t = __builtin_amdgcn_update_dpp(0, __float_as_int(y), 0x141, 0xF, 0xF, true);
    y += __int_as_float(t);
    return y;
}

// ------------------------------ selective scan -----------------------------
// Round-10 config: block = (g, dblk32): 32 d x 16 states = 256 thr (4 waves);
// 512 blocks -> 2 blocks/CU. (Finer d-split triples FETCH via B/C
// redundancy — r11. Fetch cuts don't move time — r14: issue/latency floor.)
// NOTE: yg aliases dtb - chunk c+1's dtb rows are prefetched to regs before
// chunk c's yg writeout; blocks touch disjoint (g, d-slice) columns.
__global__ __launch_bounds__(256) void k_scan(
    const unsigned short* __restrict__ dtb,
    const unsigned short* __restrict__ xcb,
    const unsigned short* __restrict__ xzb,
    const unsigned short* __restrict__ Bb,
    const unsigned short* __restrict__ Cb,
    const float* __restrict__ A_log, const float* __restrict__ Dp,
    unsigned short* __restrict__ yg)
{
    // floats: buf0 [0,3456) | buf1 [3456,6912) | ygL [6912, 6912+32*36)
    __shared__ __align__(16) float lds[2 * 3456 + 32 * 36];

    const int g    = blockIdx.x >> 3;
    const int dblk = blockIdx.x & 7;
    const int tid  = threadIdx.x;
    const int lane = tid & 63;
    const int dl   = (tid >> 6) * 8 + (lane >> 3);   // local d 0..31
    const int sp   = lane & 7;                       // state-pair index
    const int d0   = dblk * 32;
    const int d    = d0 + dl;
    const size_t rbase = (size_t)g * GL;

    // staging coords
    const int sdd = tid & 31, stq = tid >> 5;        // dt/xc: d-col, t-quad
    const int sbt = tid >> 4, sbi = tid & 15;        // B/C: t-row, state
    const int szt = tid >> 3, szi = tid & 7;         // z / writeout

    const float L2E = 1.44269504088896f;
    const float aA0 = -__expf(A_log[d * 16 + 2 * sp]) * L2E;
    const float aA1 = -__expf(A_log[d * 16 + 2 * sp + 1]) * L2E;
    const float Dpd = Dp[d];
    float h0 = 0.f, h1 = 0.f;

    float rdt[4], rxc[4];
    float rB0, rB1, rC0, rC1;
    ushort4 rz, zcur;

    // ---- prologue: load chunk 0 into registers ----
    {
        const size_t r0 = rbase;
#pragma unroll
        for (int j = 0; j < 4; ++j) {
            rdt[j] = bf2f(dtb[(r0 + stq * 4 + j) * 256 + d0 + sdd]);
            rxc[j] = bf2f(xcb[(r0 + stq * 4 + j) * 256 + d0 + sdd]);
        }
        rz  = *(const ushort4*)&xzb[(r0 + szt) * 512 + 256 + d0 + szi * 4];
        rB0 = bf2f(Bb[(r0 + sbt) * 16 + sbi]);
        rB1 = bf2f(Bb[(r0 + sbt + 16) * 16 + sbi]);
        rC0 = bf2f(Cb[(r0 + sbt) * 16 + sbi]);
        rC1 = bf2f(Cb[(r0 + sbt + 16) * 16 + sbi]);
    }
    zcur = rz;

    float* ygL = lds + 2 * 3456;

    for (int c = 0; c < NCH; ++c) {
        float* buf = lds + (c & 1) * 3456;
        // ---- commit staged registers to LDS (transposed fp32 tiles) ----
        *(float4*)&buf[sdd * 36 + stq * 4] =
            make_float4(rdt[0], rdt[1], rdt[2], rdt[3]);
        *(float4*)&buf[1152 + sdd * 36 + stq * 4] =
            make_float4(rxc[0], rxc[1], rxc[2], rxc[3]);
        buf[2304 + sbi * 36 + sbt]      = rB0;
        buf[2304 + sbi * 36 + sbt + 16] = rB1;
        buf[2880 + sbi * 36 + sbt]      = rC0;
        buf[2880 + sbi * 36 + sbt + 16] = rC1;
        zcur = rz;
        __syncthreads();

        // ---- prefetch chunk c+1 (lands during the 32 steps below) ----
        if (c + 1 < NCH) {
            const size_t r0 = rbase + (size_t)(c + 1) * SCH;
#pragma unroll
            for (int j = 0; j < 4; ++j) {
                rdt[j] = bf2f(dtb[(r0 + stq * 4 + j) * 256 + d0 + sdd]);
                rxc[j] = bf2f(xcb[(r0 + stq * 4 + j) * 256 + d0 + sdd]);
            }
            rz  = *(const ushort4*)&xzb[(r0 + szt) * 512 + 256 + d0 + szi * 4];
            rB0 = bf2f(Bb[(r0 + sbt) * 16 + sbi]);
            rB1 = bf2f(Bb[(r0 + sbt + 16) * 16 + sbi]);
            rC0 = bf2f(Cb[(r0 + sbt) * 16 + sbi]);
            rC1 = bf2f(Cb[(r0 + sbt + 16) * 16 + sbi]);
        }

        // ---- 32 scan steps from LDS ----
        const float* pdt = buf + dl * 36;
        const float* pxc = buf + 1152 + dl * 36;
        const float* pB0 = buf + 2304 + (2 * sp) * 36;
        const float* pB1 = buf + 2304 + (2 * sp + 1) * 36;
        const float* pC0 = buf + 2880 + (2 * sp) * 36;
        const float* pC1 = buf + 2880 + (2 * sp + 1) * 36;
        float yk[4] = {0.f, 0.f, 0.f, 0.f};
#pragma unroll
        for (int t4 = 0; t4 < 8; ++t4) {
            const float4 dt4 = *(const float4*)&pdt[t4 * 4];
            const float4 xc4 = *(const float4*)&pxc[t4 * 4];
            const float4 B04 = *(const float4*)&pB0[t4 * 4];
            const float4 B14 = *(const float4*)&pB1[t4 * 4];
            const float4 C04 = *(const float4*)&pC0[t4 * 4];
            const float4 C14 = *(const float4*)&pC1[t4 * 4];
#define SSTEP(J)                                                            \
            {                                                               \
                const float dt = ((const float*)&dt4)[J];                   \
                const float xc = ((const float*)&xc4)[J];                   \
                const float dtx = dt * xc;                                  \
                h0 = h0 * exp2_fast(dt * aA0) + dtx * ((const float*)&B04)[J]; \
                h1 = h1 * exp2_fast(dt * aA1) + dtx * ((const float*)&B14)[J]; \
                float yv = h0 * ((const float*)&C04)[J]                     \
                         + h1 * ((const float*)&C14)[J];                    \
                yv = dpp_add8(yv);                                          \
                yv = fmaf(xc, Dpd, yv);                                     \
                const int tt = t4 * 4 + (J);                                \
                yk[t4 >> 1] = (sp == (tt & 7)) ? yv : yk[t4 >> 1];          \
            }
            SSTEP(0) SSTEP(1) SSTEP(2) SSTEP(3)
#undef SSTEP
        }
        // stage captured y to LDS: lane sp holds t = 8k+sp for its d
#pragma unroll
        for (int k = 0; k < 4; ++k)
            ygL[(k * 8 + sp) * 36 + dl] = yk[k];
        __syncthreads();

        // ---- coalesced bf16 writeout with silu(z) from registers ----
        {
            const size_t rr0 = rbase + (size_t)c * SCH;
            float4 y4 = *(const float4*)&ygL[szt * 36 + szi * 4];
            float z0 = bf2f(zcur.x), z1 = bf2f(zcur.y);
            float z2 = bf2f(zcur.z), z3 = bf2f(zcur.w);
            float o0 = y4.x * (z0 / (1.f + __expf(-z0)));
            float o1 = y4.y * (z1 / (1.f + __expf(-z1)));
            float o2 = y4.z * (z2 / (1.f + __expf(-z2)));
            float o3 = y4.w * (z3 / (1.f + __expf(-z3)));
            uint2 packed;
            packed.x = cvt_pk_bf16(o0, o1);
            packed.y = cvt_pk_bf16(o2, o3);
            *(uint2*)&yg[(rr0 + szt) * 256 + d0 + szi * 4] = packed;
        }
    }
}

// --- add + BN1/BN2 (params per-thread; bf16 in, bf16 out, fp32 stats) ------
__global__ __launch_bounds__(256) void k_add(const unsigned short* __restrict__ h1p,
                                             const unsigned short* __restrict__ p2,
                                             const float* __restrict__ st,
                                             const float* __restrict__ g1,
                                             const float* __restrict__ be1,
                                             const float* __restrict__ g2,
                                             const float* __restrict__ be2,
                                             unsigned short* __restrict__ outp,
                                             float* __restrict__ sumP,
                                             float* __restrict__ sqP)
{
    const int c = threadIdx.x & 127, half = threadIdx.x >> 7;
    const float inv = 1.f / 32768.f;
    const float m1 = st[c] * inv, v1 = st[128 + c] * inv - m1 * m1;
    const float a1 = g1[c] * rsqrtf(v1 + 1e-5f), b1 = be1[c] - m1 * a1;
    const float m2 = st[256 + c] * inv, v2 = st[384 + c] * inv - m2 * m2;
    const float a2 = g2[c] * rsqrtf(v2 + 1e-5f), b2 = be2[c] - m2 * a2;

    const int rbase = blockIdx.x * 64 + half * 32;
    float s = 0.f, q = 0.f;
    for (int i = 0; i < 32; ++i) {
        size_t idx = (size_t)(rbase + i) * 128 + c;
        float v = bf2f(h1p[idx]) * a1 + b1 + bf2f(p2[idx]) * a2 + b2;
        outp[idx] = f2bf(v); s += v; q += v * v;
    }
    __shared__ float sh[2][2][128];
    sh[0][half][c] = s; sh[1][half][c] = q;
    __syncthreads();
    if (threadIdx.x < 128) {
        atomicAdd(&sumP[c], sh[0][0][c] + sh[0][1][c]);
        atomicAdd(&sqP[c],  sh[1][0][c] + sh[1][1][c]);
    }
}

// ---- fold1: block-per-column; W1eT bf16 [256][128] + b1e fp32 -------------
__global__ __launch_bounds__(128) void k_fold1(
    const float* __restrict__ sumP, const float* __restrict__ sqP,
    const float* __restrict__ gam, const float* __restrict__ bet,
    const float* __restrict__ W1, const float* __restrict__ b1in,
    unsigned short* __restrict__ W1eT, float* __restrict__ b1e)
{
    __shared__ float red[128];
    const int n = blockIdx.x, k = threadIdx.x;
    const float inv = 1.f / 32768.f;
    const float m = sumP[k] * inv, v = sqP[k] * inv - m * m;
    const float a = gam[k] * rsqrtf(v + 1e-5f), bs = bet[k] - m * a;
    const float wv = W1[k * 256 + n];
    W1eT[n * 128 + k] = f2bf(a * wv);
    red[k] = bs * wv;
    __syncthreads();
    for (int s = 64; s > 0; s >>= 1) {
        if (k < s) red[k] += red[k + s];
        __syncthreads();
    }
    if (k == 0) b1e[n] = red[0] + b1in[n];
}

// ---- fold2: block-per-column; W2eT bf16 [128][256] + b2e fp32 -------------
__global__ __launch_bounds__(256) void k_fold2(
    const float* __restrict__ sumP, const float* __restrict__ sqP,
    const float* __restrict__ gam, const float* __restrict__ bet,
    const float* __restrict__ W2, const float* __restrict__ b2in,
    unsigned short* __restrict__ W2eT, float* __restrict__ b2e)
{
    __shared__ float red[256];
    const int n = blockIdx.x, k = threadIdx.x;
    const float inv = 1.f / 32768.f;
    const float m = sumP[k] * inv, v = sqP[k] * inv - m * m;
    const float a = gam[k] * rsqrtf(v + 1e-5f), bs = bet[k] - m * a;
    const float wv = W2[k * 128 + n];
    W2eT[n * 256 + k] = f2bf(a * wv);
    red[k] = bs * wv;
    __syncthreads();
    for (int s = 128; s > 0; s >>= 1) {
        if (k < s) red[k] += red[k + s];
        __syncthreads();
    }
    if (k == 0) b2e[n] = red[0] + b2in[n];
}

// ------------- BN3 (params per-thread, amortized; bf16 input) ---------------
__global__ __launch_bounds__(256) void k_bn3(const unsigned short* __restrict__ out2,
                                             const float* __restrict__ sumP,
                                             const float* __restrict__ sqP,
                                             const float* __restrict__ gam,
                                             const float* __restrict__ bet,
                                             float* __restrict__ dout)
{
    const int cq = (threadIdx.x & 31) * 4;     // column quad
    const int rw = threadIdx.x >> 5;           // 0..7
    const float inv = 1.f / 32768.f;
    float a[4], b[4];
#pragma unroll
    for (int j = 0; j < 4; ++j) {
        float m = sumP[cq + j] * inv, v = sqP[cq + j] * inv - m * m;
        a[j] = gam[cq + j] * rsqrtf(v + 1e-5f);
        b[j] = bet[cq + j] - m * a[j];
    }
    const int r0 = blockIdx.x * 128 + rw;
#pragma unroll 4
    for (int k = 0; k < 16; ++k) {
        const size_t r = r0 + k * 8;
        ushort4 u = *(const ushort4*)&out2[r * 128 + cq];
        float4 v;
        v.x = bf2f(u.x) * a[0] + b[0]; v.y = bf2f(u.y) * a[1] + b[1];
        v.z = bf2f(u.z) * a[2] + b[2]; v.w = bf2f(u.w) * a[3] + b[3];
        *(float4*)&dout[r * 128 + cq] = v;
    }
}

// ------------------------------- launch ------------------------------------
extern "C" void kernel_launch(void* const* d_in, const int* in_sizes, int n_in,
                              void* d_out, int out_size, void* d_ws, size_t ws_size,
                              hipStream_t stream)
{
    (void)in_sizes; (void)n_in; (void)out_size; (void)ws_size;
    const float* x      = (const float*)d_in[0];
    const int*   ei     = (const int*)d_in[1];
    // d_in[2] = batch (unused: equal-size sorted graphs == reshape)
    const float* W_root = (const float*)d_in[3];
    const float* W_rel  = (const float*)d_in[4];
    const float* b_rel  = (const float*)d_in[5];
    const float* n1_g = (const float*)d_in[6],  *n1_b = (const float*)d_in[7];
    const float* n2_g = (const float*)d_in[8],  *n2_b = (const float*)d_in[9];
    const float* n3_g = (const float*)d_in[10], *n3_b = (const float*)d_in[11];
    const float* m1_g = (const float*)d_in[12], *m1_b = (const float*)d_in[13];
    const float* W1   = (const float*)d_in[14], *b1   = (const float*)d_in[15];
    const float* m2_g = (const float*)d_in[16], *m2_b = (const float*)d_in[17];
    const float* W2   = (const float*)d_in[18], *b2   = (const float*)d_in[19];
    const float* in_W   = (const float*)d_in[20];
    const float* conv_w = (const float*)d_in[21], *conv_b = (const float*)d_in[22];
    const float* xproj_W= (const float*)d_in[23];
    const float* dt_W   = (const float*)d_in[24], *dt_b = (const float*)d_in[25];
    const float* A_log  = (const float*)d_in[26], *Dp   = (const float*)d_in[27];
    const float* out_W  = (const float*)d_in[28];

    float* ws = (float*)d_ws;
    // small region
    float* st  = ws;             // 2048 used (S1..S5 sums/sumsqs)
    float* b1e = ws + 8192;      // 256
    float* b2e = ws + 8448;      // 128
    // bf16 transposed weights (shorts)
    unsigned short* wsh   = (unsigned short*)(ws + 8704);
    unsigned short* WrelT  = wsh;            // 128x128 = 16384
    unsigned short* WrootT = wsh + 16384;    // 16384
    unsigned short* inWT   = wsh + 32768;    // 512x128 = 65536
    unsigned short* xprojT = wsh + 98304;    // 40x256  = 10240
    unsigned short* outWT  = wsh + 108544;   // 128x256 = 32768
    unsigned short* W1eT   = wsh + 141312;   // 256x128 = 32768
    unsigned short* W2eT   = wsh + 174080;   // 128x256 = 32768 (end 206848)
    // big buffers (float-unit offsets; bf16 buffers occupy half the floats)
    float* big = ws + 112640;
    unsigned short* agg16 = (unsigned short*)(big);             // 4.19M sh
    unsigned short* p216  = agg16;                              // reuse
    unsigned short* h1p16 = (unsigned short*)(big + 2097152);   // 4.19M sh
    unsigned short* x16   = (unsigned short*)(big + 4194304);   // 4.19M sh
    unsigned short* xz16  = (unsigned short*)(big + 6291456);   // 16.78M sh
    unsigned short* xc16  = (unsigned short*)(big + 14680064);  // 8.39M sh
    float* proj = big + 18874368;                               // 1.31M f
    unsigned short* dtb16 = (unsigned short*)(big + 20185088);  // 8.39M sh (yg alias)
    unsigned short* yg16  = dtb16;
    unsigned short* Bc16  = (unsigned short*)(big + 24379392);  // 524288 sh
    unsigned short* Cc16  = (unsigned short*)(big + 24903680);  // 524288 sh
    unsigned short* outb16 = (unsigned short*)(big + 25427968); // 4.19M sh
    unsigned short* out216 = (unsigned short*)(big + 27525120); // 4.19M sh
    unsigned short* g16    = (unsigned short*)(big + 29622272); // 8.39M sh

    // CSR scratch lives in the h1p16 region (dead until the h1 GEMM writes it)
    int* ideg   = (int*)h1p16;            // 32768
    int* ibase  = ideg + 32768;           // 32769
    int* icur   = ideg + 65552;           // 32768 (16B-aligned)
    int* isrcs  = ideg + 98320;           // 524288

    hipMemsetAsync(st, 0, 2048 * sizeof(float), stream);
    hipMemsetAsync(ideg, 0, 32768 * sizeof(int), stream);

    // ---- preps: weights (bf16 transposes) + x -> bf16 ----
    k_prepw5<<<552, 256, 0, stream>>>(W_rel, WrelT, W_root, WrootT,
                                      in_W, inWT, xproj_W, xprojT,
                                      out_W, outWT);
    k_prepx<<<2048, 256, 0, stream>>>(x, x16);

    // ---- CSR build + gather (bf16, 4-deep ILP) ----
    k_hist<<<512, 256, 0, stream>>>(ei, ideg);
    k_scanidx<<<1, 1024, 0, stream>>>(ideg, ibase, icur);
    k_fill<<<512, 256, 0, stream>>>(ei, icur, isrcs);
    k_gather<<<8192, 256, 0, stream>>>(x16, ibase, isrcs, agg16);

    // h1_pre = agg@W_rel + b_rel + x@W_root + x  [S1]  (bf16 A/resid/out)
    gemm_mfma<true, 0, true, true, true><<<dim3(256, 2), 256, 0, stream>>>(
        agg16, WrelT, x16, WrootT, NROWS, 128, 128, 128,
        b_rel, x16, 128, h1p16, st + 0, st + 128);
    // xz = x @ in_W  (bf16 A, bf16 out)
    gemm_mfma<false, 0, false, true, false><<<dim3(256, 8), 256, 0, stream>>>(
        x16, inWT, nullptr, nullptr, NROWS, 512, 128, 512,
        nullptr, nullptr, 0, xz16, nullptr, nullptr);
    k_conv<<<16384, 256, 0, stream>>>(xz16, conv_w, conv_b, xc16);
    // proj = xc @ xproj_W (bf16 A, fp32 out, N=40)
    gemm_mfma<false, 0, false, false, false><<<dim3(256, 1), 256, 0, stream>>>(
        xc16, xprojT, nullptr, nullptr, NROWS, 40, 256, 40,
        nullptr, nullptr, 0, proj, nullptr, nullptr);
    k_dtbc<<<1024, 256, 0, stream>>>(proj, dt_W, dt_b, dtb16, Bc16, Cc16);
    k_scan<<<512, 256, 0, stream>>>(dtb16, xc16, xz16, Bc16, Cc16, A_log, Dp, yg16);
    // p2 = yg @ out_W + x  [S2]  (bf16 A/resid/out)
    gemm_mfma<false, 0, true, true, true><<<dim3(256, 2), 256, 0, stream>>>(
        yg16, outWT, nullptr, nullptr, NROWS, 128, 256, 128,
        nullptr, x16, 128, p216, st + 256, st + 384);
    // out = BN1(h1_pre) + BN2(p2)  [S3]  (bf16 out)
    k_add<<<512, 256, 0, stream>>>(h1p16, p216, st, n1_g, n1_b, n2_g, n2_b,
                                   outb16, st + 512, st + 640);
    k_fold1<<<256, 128, 0, stream>>>(st + 512, st + 640, m1_g, m1_b, W1, b1, W1eT, b1e);
    // g = gelu(out @ W1e + b1e)  [S4]  (bf16 A, bf16 out)
    gemm_mfma<false, 1, true, true, false><<<dim3(256, 4), 256, 0, stream>>>(
        outb16, W1eT, nullptr, nullptr, NROWS, 256, 128, 256,
        b1e, nullptr, 0, g16, st + 768, st + 1024);
    k_fold2<<<128, 256, 0, stream>>>(st + 768, st + 1024, m2_g, m2_b, W2, b2, W2eT, b2e);
    // out2 = g @ W2e + b2e + out  [S5]  (bf16 A/resid, bf16 out)
    gemm_mfma<false, 0, true, true, true><<<dim3(256, 2), 256, 0, stream>>>(
        g16, W2eT, nullptr, nullptr, NROWS, 128, 256, 128,
        b2e, outb16, 128, out216, st + 1280, st + 1408);
    // d_out = BN3(out2)  (params computed in-kernel from S5)
    k_bn3<<<256, 256, 0, stream>>>(out216, st + 1280, st + 1408, n3_g, n3_b,
                                   (float*)d_out);
}

// Round 16
// 335.541 us; speedup vs baseline: 1.3490x; 1.0165x over previous
//
#include <hip/hip_runtime.h>

// ---------------------------------------------------------------------------
// GraphMambaConv: N=32768 nodes, C=128, G=64 graphs x L=512, E=524288 edges,
// D_INNER=256, D_STATE=16, DT_RANK=8, D_CONV=4.
//
// Round 16: launch-overhead consolidation (last addressable tier).
//  - k_prep: prepw5 + prepx + hist merged into ONE launch (3112 blocks,
//    disjoint ranges; independent jobs co-execute).
//  - k_gather: 8-deep edge ILP (8 independent row loads in flight/iter).
//  Scan at r10 config (~58us structural floor; fetch-insensitive per r14).
// ---------------------------------------------------------------------------

#define NROWS 32768
#define CDIM  128
#define EDGES 524288
#define GL    512
#define SCH   32          // scan chunk (timesteps)
#define NCH   (GL / SCH)  // 16 chunks

typedef short s16x8 __attribute__((ext_vector_type(8)));
typedef float f32x4 __attribute__((ext_vector_type(4)));

__device__ __forceinline__ unsigned short f2bf(float f)
{
    unsigned u = __float_as_uint(f);
    u += 0x7FFF + ((u >> 16) & 1);          // RNE
    return (unsigned short)(u >> 16);
}

__device__ __forceinline__ float bf2f(unsigned short u)
{
    return __uint_as_float((unsigned)u << 16);
}

__device__ __forceinline__ unsigned cvt_pk_bf16(float lo, float hi)
{
    unsigned r;
    asm("v_cvt_pk_bf16_f32 %0, %1, %2" : "=v"(r) : "v"(lo), "v"(hi));
    return r;
}

__device__ __forceinline__ float exp2_fast(float x)
{
    float r;
    asm("v_exp_f32 %0, %1" : "=v"(r) : "v"(x));   // v_exp_f32 computes 2^x
    return r;
}

// ---- merged prep: weight transposes (552) | x->bf16 (2048) | hist (512) ---
__global__ __launch_bounds__(256) void k_prep(
    const float* __restrict__ Wa, unsigned short* __restrict__ Ta,
    const float* __restrict__ Wb, unsigned short* __restrict__ Tb,
    const float* __restrict__ Wc, unsigned short* __restrict__ Tc,
    const float* __restrict__ Wd, unsigned short* __restrict__ Td,
    const float* __restrict__ We, unsigned short* __restrict__ Te,
    const float* __restrict__ x, unsigned short* __restrict__ x16,
    const int* __restrict__ ei, int* __restrict__ deg)
{
    const int bid = blockIdx.x;
    if (bid < 552) {                         // weight transposes
        const int idx = bid * 256 + threadIdx.x;
        const float* W; unsigned short* T; int rel, ks, N;
        if (idx < 16384)       { W = Wa; T = Ta; rel = idx;          ks = 7; N = 128; }
        else if (idx < 32768)  { W = Wb; T = Tb; rel = idx - 16384;  ks = 7; N = 128; }
        else if (idx < 98304)  { W = Wc; T = Tc; rel = idx - 32768;  ks = 7; N = 512; }
        else if (idx < 108544) { W = Wd; T = Td; rel = idx - 98304;  ks = 8; N = 40;  }
        else                   { W = We; T = Te; rel = idx - 108544; ks = 8; N = 128; }
        const int K = 1 << ks;
        const int n = rel >> ks, k = rel & (K - 1);
        T[rel] = f2bf(W[(size_t)k * N + n]);
    } else if (bid < 2600) {                 // x -> bf16
        const size_t i = ((size_t)(bid - 552) * 256 + threadIdx.x) * 8;
        float4 a = *(const float4*)&x[i];
        float4 b = *(const float4*)&x[i + 4];
        uint4 p;
        p.x = cvt_pk_bf16(a.x, a.y); p.y = cvt_pk_bf16(a.z, a.w);
        p.z = cvt_pk_bf16(b.x, b.y); p.w = cvt_pk_bf16(b.z, b.w);
        *(uint4*)&x16[i] = p;
    } else {                                 // degree histogram
        const int e = (bid - 2600) * 1024 + threadIdx.x * 4;
        const int4 d4 = *(const int4*)&ei[EDGES + e];
        atomicAdd(&deg[d4.x], 1);
        atomicAdd(&deg[d4.y], 1);
        atomicAdd(&deg[d4.z], 1);
        atomicAdd(&deg[d4.w], 1);
    }
}

// ---------------- CSR build: exclusive prefix scan (1 block) ---------------
__global__ __launch_bounds__(1024) void k_scanidx(const int* __restrict__ deg,
                                                  int* __restrict__ base,
                                                  int* __restrict__ cursor)
{
    __shared__ int ps[1024];
    const int tid = threadIdx.x;
    int loc[32];
    int s = 0;
#pragma unroll
    for (int i = 0; i < 32; ++i) { loc[i] = deg[tid * 32 + i]; s += loc[i]; }
    ps[tid] = s;
    __syncthreads();
    for (int off = 1; off < 1024; off <<= 1) {
        int v = (tid >= off) ? ps[tid - off] : 0;
        __syncthreads();
        ps[tid] += v;
        __syncthreads();
    }
    int run = tid ? ps[tid - 1] : 0;
#pragma unroll
    for (int i = 0; i < 32; ++i) {
        base[tid * 32 + i] = run;
        cursor[tid * 32 + i] = run;
        run += loc[i];
    }
    if (tid == 0) base[32768] = EDGES;
}

// ------------------------- CSR build: fill src lists -----------------------
__global__ __launch_bounds__(256) void k_fill(const int* __restrict__ ei,
                                              int* __restrict__ cursor,
                                              int* __restrict__ srcs)
{
    const int e = blockIdx.x * 1024 + threadIdx.x * 4;
    const int4 s4 = *(const int4*)&ei[e];
    const int4 d4 = *(const int4*)&ei[EDGES + e];
    int p;
    p = atomicAdd(&cursor[d4.x], 1); srcs[p] = s4.x;
    p = atomicAdd(&cursor[d4.y], 1); srcs[p] = s4.y;
    p = atomicAdd(&cursor[d4.z], 1); srcs[p] = s4.z;
    p = atomicAdd(&cursor[d4.w], 1); srcs[p] = s4.w;
}

// ------- gather (bf16 in/out, fp32 accumulate, 8-deep edge ILP) ------------
__global__ __launch_bounds__(256) void k_gather(const unsigned short* __restrict__ x16,
                                                const int* __restrict__ base,
                                                const int* __restrict__ srcs,
                                                unsigned short* __restrict__ agg16)
{
    const int node = blockIdx.x * 4 + (threadIdx.x >> 6);
    const int lane = threadIdx.x & 63;
    const int b0 = base[node], b1 = base[node + 1];
    float a0 = 0.f, a1 = 0.f, p0 = 0.f, p1 = 0.f;
    float q0 = 0.f, q1 = 0.f, r0 = 0.f, r1 = 0.f;
    int i = b0;
    for (; i + 8 <= b1; i += 8) {
        int s[8];
#pragma unroll
        for (int j = 0; j < 8; ++j) s[j] = srcs[i + j];
        unsigned v[8];
#pragma unroll
        for (int j = 0; j < 8; ++j)
            v[j] = *(const unsigned*)&x16[(size_t)s[j] * 128 + lane * 2];
        a0 += bf2f((unsigned short)(v[0] & 0xFFFF)) + bf2f((unsigned short)(v[4] & 0xFFFF));
        a1 += bf2f((unsigned short)(v[0] >> 16))    + bf2f((unsigned short)(v[4] >> 16));
        p0 += bf2f((unsigned short)(v[1] & 0xFFFF)) + bf2f((unsigned short)(v[5] & 0xFFFF));
        p1 += bf2f((unsigned short)(v[1] >> 16))    + bf2f((unsigned short)(v[5] >> 16));
        q0 += bf2f((unsigned short)(v[2] & 0xFFFF)) + bf2f((unsigned short)(v[6] & 0xFFFF));
        q1 += bf2f((unsigned short)(v[2] >> 16))    + bf2f((unsigned short)(v[6] >> 16));
        r0 += bf2f((unsigned short)(v[3] & 0xFFFF)) + bf2f((unsigned short)(v[7] & 0xFFFF));
        r1 += bf2f((unsigned short)(v[3] >> 16))    + bf2f((unsigned short)(v[7] >> 16));
    }
    for (; i + 2 <= b1; i += 2) {
        const int s0 = srcs[i], s1 = srcs[i + 1];
        const unsigned v0 = *(const unsigned*)&x16[(size_t)s0 * 128 + lane * 2];
        const unsigned v1 = *(const unsigned*)&x16[(size_t)s1 * 128 + lane * 2];
        a0 += bf2f((unsigned short)(v0 & 0xFFFF));
        a1 += bf2f((unsigned short)(v0 >> 16));
        p0 += bf2f((unsigned short)(v1 & 0xFFFF));
        p1 += bf2f((unsigned short)(v1 >> 16));
    }
    if (i < b1) {
        const int s0 = srcs[i];
        const unsigned v0 = *(const unsigned*)&x16[(size_t)s0 * 128 + lane * 2];
        a0 += bf2f((unsigned short)(v0 & 0xFFFF));
        a1 += bf2f((unsigned short)(v0 >> 16));
    }
    a0 += (p0 + q0) + r0;
    a1 += (p1 + q1) + r1;
    *(unsigned*)&agg16[(size_t)node * 128 + lane * 2] = cvt_pk_bf16(a0, a1);
}

// ------------------------- MFMA GEMM (bf16 in, fp32 acc) --------------------
// out = epi( A0@W0 [+ A1@W1] [+bias] [+resid] ), optional column stats.
// A: MxK bf16 row-major (copy-staged). WT: NxK bf16 row-major.
// Out fp32/bf16 (OBF). Resid fp32/bf16 (RBF).
// Tile 128x64, BK=64, 4 waves each 64x32 -> 8 mfma_f32_16x16x32_bf16/K-step.
template<bool DUAL, int ACT, bool STAT, bool OBF, bool RBF>
__global__ __launch_bounds__(256)
void gemm_mfma(const unsigned short* __restrict__ A0,
               const unsigned short* __restrict__ W0T,
               const unsigned short* __restrict__ A1p,
               const unsigned short* __restrict__ W1Tp,
               int M, int N, int K, int ldo,
               const float* __restrict__ bias,
               const void* __restrict__ resid, int ldr,
               void* __restrict__ outp,
               float* __restrict__ sumP, float* __restrict__ sqP)
{
    __shared__ __align__(16) unsigned short As[128 * 72];  // [m][k], pad 8
    __shared__ __align__(16) unsigned short Bs[64 * 72];   // [n][k], pad 8
    __shared__ float sB[2][64];

    const int tid = threadIdx.x;
    const int m0 = blockIdx.x * 128;
    const int n0 = blockIdx.y * 64;

    const int ar = tid >> 1, ak = (tid & 1) * 32;   // A staging: 32 elems/thr
    const int br = tid >> 2, bk = (tid & 3) * 16;   // B staging: 16 elems/thr

    const int w  = tid >> 6, l = tid & 63;
    const int wr = (w >> 1) * 64, wc = (w & 1) * 32;
    const int fr = l & 15;               // frag row/col
    const int fk = (l >> 4) * 8;         // frag k base

    f32x4 acc[4][2];
#pragma unroll
    for (int i = 0; i < 4; ++i)
#pragma unroll
        for (int j = 0; j < 2; ++j) acc[i][j] = (f32x4){0.f, 0.f, 0.f, 0.f};

    const int npass = DUAL ? 2 : 1;
    for (int pass = 0; pass < npass; ++pass) {
        const unsigned short* A = (DUAL && pass) ? A1p : A0;
        const unsigned short* WT = (DUAL && pass) ? W1Tp : W0T;
        for (int k0 = 0; k0 < K; k0 += 64) {
            {   // stage A: straight bf16 copy, 4x uint4 per thread
                const unsigned short* ap = A + (size_t)(m0 + ar) * K + k0 + ak;
                *(uint4*)&As[ar * 72 + ak]      = *(const uint4*)(ap);
                *(uint4*)&As[ar * 72 + ak + 8]  = *(const uint4*)(ap + 8);
                *(uint4*)&As[ar * 72 + ak + 16] = *(const uint4*)(ap + 16);
                *(uint4*)&As[ar * 72 + ak + 24] = *(const uint4*)(ap + 24);
            }
            {   // stage B: bf16 copy from WT (zero-fill n >= N)
                const int nn = n0 + br;
                if (nn < N) {
                    const unsigned short* wp = WT + (size_t)nn * K + k0 + bk;
                    *(uint4*)&Bs[br * 72 + bk]     = *(const uint4*)(wp);
                    *(uint4*)&Bs[br * 72 + bk + 8] = *(const uint4*)(wp + 8);
                } else {
                    uint4 z = make_uint4(0, 0, 0, 0);
                    *(uint4*)&Bs[br * 72 + bk]     = z;
                    *(uint4*)&Bs[br * 72 + bk + 8] = z;
                }
            }
            __syncthreads();
#pragma unroll
            for (int ks = 0; ks < 2; ++ks) {
                s16x8 b0 = *(const s16x8*)&Bs[(wc + fr     ) * 72 + ks * 32 + fk];
                s16x8 b1 = *(const s16x8*)&Bs[(wc + 16 + fr) * 72 + ks * 32 + fk];
#pragma unroll
                for (int mt = 0; mt < 4; ++mt) {
                    s16x8 a = *(const s16x8*)&As[(wr + mt * 16 + fr) * 72 + ks * 32 + fk];
                    acc[mt][0] = __builtin_amdgcn_mfma_f32_16x16x32_bf16(a, b0, acc[mt][0], 0, 0, 0);
                    acc[mt][1] = __builtin_amdgcn_mfma_f32_16x16x32_bf16(a, b1, acc[mt][1], 0, 0, 0);
                }
            }
            __syncthreads();
        }
    }

    // ---- epilogue: C/D layout col=lane&15, row=(lane>>4)*4+reg ----
    const int orow = (l >> 4) * 4;
    float cs[2] = {0.f, 0.f}, cq[2] = {0.f, 0.f};
#pragma unroll
    for (int mt = 0; mt < 4; ++mt) {
#pragma unroll
        for (int nt = 0; nt < 2; ++nt) {
            const int cg = n0 + wc + nt * 16 + fr;
            if (cg < N) {
                const float bv = bias ? bias[cg] : 0.f;
#pragma unroll
                for (int r = 0; r < 4; ++r) {
                    const int rg = m0 + wr + mt * 16 + orow + r;
                    float v = acc[mt][nt][r] + bv;
                    if (resid) {
                        float rv = RBF
                            ? bf2f(((const unsigned short*)resid)[(size_t)rg * ldr + cg])
                            : ((const float*)resid)[(size_t)rg * ldr + cg];
                        v += rv;
                    }
                    if (ACT == 1)
                        v = 0.5f * v * (1.f + erff(v * 0.7071067811865475f));
                    if (OBF)
                        ((unsigned short*)outp)[(size_t)rg * ldo + cg] = f2bf(v);
                    else
                        ((float*)outp)[(size_t)rg * ldo + cg] = v;
                    if (STAT) { cs[nt] += v; cq[nt] += v * v; }
                }
            }
        }
    }
    if (STAT) {
        if (tid < 64) { sB[0][tid] = 0.f; sB[1][tid] = 0.f; }
        __syncthreads();
#pragma unroll
        for (int nt = 0; nt < 2; ++nt) {
            atomicAdd(&sB[0][wc + nt * 16 + fr], cs[nt]);
            atomicAdd(&sB[1][wc + nt * 16 + fr], cq[nt]);
        }
        __syncthreads();
        if (tid < 64 && (n0 + tid) < N) {
            atomicAdd(&sumP[n0 + tid], sB[0][tid]);
            atomicAdd(&sqP[n0 + tid],  sB[1][tid]);
        }
    }
}

// ----- causal conv + SiLU (bf16 in/out, 2 rows/block, shared window) -------
__global__ __launch_bounds__(256) void k_conv(const unsigned short* __restrict__ xz,
                                              const float* __restrict__ cw,
                                              const float* __restrict__ cb,
                                              unsigned short* __restrict__ xc)
{
    const int r0 = blockIdx.x * 2;    // even; pair never straddles a graph
    const int l0 = r0 & (GL - 1);
    const int d = threadIdx.x;        // 0..255
    float4 w4 = *(const float4*)&cw[d * 4];
    float vals[5];
#pragma unroll
    for (int j = 0; j < 5; ++j) {
        const int ll = l0 - 3 + j;
        vals[j] = (ll >= 0) ? bf2f(xz[(size_t)(r0 - 3 + j) * 512 + d]) : 0.f;
    }
    float acc0 = cb[d] + vals[0] * w4.x + vals[1] * w4.y
                       + vals[2] * w4.z + vals[3] * w4.w;
    float acc1 = cb[d] + vals[1] * w4.x + vals[2] * w4.y
                       + vals[3] * w4.z + vals[4] * w4.w;
    const float s0 = 1.f / (1.f + __expf(-acc0));
    const float s1 = 1.f / (1.f + __expf(-acc1));
    xc[(size_t)r0 * 256 + d]       = f2bf(acc0 * s0);
    xc[(size_t)(r0 + 1) * 256 + d] = f2bf(acc1 * s1);
}

// ---------------- dt = softplus(proj[:,:8] @ dt_W + dt_b); B,C slices ------
__global__ __launch_bounds__(256) void k_dtbc(const float* __restrict__ proj,
                                              const float* __restrict__ dt_W,
                                              const float* __restrict__ dt_b,
                                              unsigned short* __restrict__ dtb,
                                              unsigned short* __restrict__ Bc,
                                              unsigned short* __restrict__ Cc)
{
    __shared__ float dtWS[8 * 256];
    __shared__ float dt_bS[256];
    __shared__ float projS[32 * 8];
    const int tid = threadIdx.x;
    const int r0 = blockIdx.x * 32;
    for (int i = tid; i < 2048; i += 256) dtWS[i] = dt_W[i];
    dt_bS[tid] = dt_b[tid];
    projS[tid] = proj[(size_t)(r0 + (tid >> 3)) * 40 + (tid & 7)];
    __syncthreads();

    const int c = tid;
    for (int rr = 0; rr < 32; ++rr) {
        float acc = dt_bS[c];
        const float* pr = &projS[rr * 8];
#pragma unroll
        for (int q = 0; q < 8; ++q) acc += pr[q] * dtWS[q * 256 + c];
        float e  = exp2_fast(-fabsf(acc) * 1.4426950408f);
        float sp = fmaxf(acc, 0.f) + 0.6931471806f * __log2f(1.f + e);
        dtb[(size_t)(r0 + rr) * 256 + c] = f2bf(sp);
    }
    // B = proj[:, 8:24], C = proj[:, 24:40]  (bf16)
    for (int e2 = tid; e2 < 1024; e2 += 256) {
        int rr = e2 >> 5, cc = e2 & 31;
        float v = proj[(size_t)(r0 + rr) * 40 + 8 + cc];
        if (cc < 16) Bc[(size_t)(r0 + rr) * 16 + cc] = f2bf(v);
        else         Cc[(size_t)(r0 + rr) * 16 + cc - 16] = f2bf(v);
    }
}

// ---------------- 8-lane-group sum via DPP (zero DS-pipe ops) ---------------
__device__ __forceinline__ float dpp_add8(float x)
{
    float y = x;
    int t;
    t = __builtin_amdgcn_update_dpp(0, __float_as_int(y), 0xB1, 0xF, 0xF, true);
    y += __int_as_float(t);
    t = __builtin_amdgcn_update_dpp(0, __float_as_int(y), 0x4E, 0xF, 0xF, true);
    y += __int_as_float(t);
    t = __builtin_amdgcn_update_dpp(0, __float_as_int(y), 0x141, 0xF, 0xF, true);
    y += __int_as_float(t);
    return y;
}

// ------------------------------ selective scan -----------------------------
// Round-10 config: block = (g, dblk32): 32 d x 16 states = 256 thr (4 waves);
// 512 blocks -> 2 blocks/CU. (Finer d-split triples FETCH via B/C
// redundancy — r11. Fetch cuts don't move time — r14: issue/latency floor.)
// NOTE: yg aliases dtb - chunk c+1's dtb rows are prefetched to regs before
// chunk c's yg writeout; blocks touch disjoint (g, d-slice) columns.
__global__ __launch_bounds__(256) void k_scan(
    const unsigned short* __restrict__ dtb,
    const unsigned short* __restrict__ xcb,
    const unsigned short* __restrict__ xzb,
    const unsigned short* __restrict__ Bb,
    const unsigned short* __restrict__ Cb,
    const float* __restrict__ A_log, const float* __restrict__ Dp,
    unsigned short* __restrict__ yg)
{
    // floats: buf0 [0,3456) | buf1 [3456,6912) | ygL [6912, 6912+32*36)
    __shared__ __align__(16) float lds[2 * 3456 + 32 * 36];

    const int g    = blockIdx.x >> 3;
    const int dblk = blockIdx.x & 7;
    const int tid  = threadIdx.x;
    const int lane = tid & 63;
    const int dl   = (tid >> 6) * 8 + (lane >> 3);   // local d 0..31
    const int sp   = lane & 7;                       // state-pair index
    const int d0   = dblk * 32;
    const int d    = d0 + dl;
    const size_t rbase = (size_t)g * GL;

    // staging coords
    const int sdd = tid & 31, stq = tid >> 5;        // dt/xc: d-col, t-quad
    const int sbt = tid >> 4, sbi = tid & 15;        // B/C: t-row, state
    const int szt = tid >> 3, szi = tid & 7;         // z / writeout

    const float L2E = 1.44269504088896f;
    const float aA0 = -__expf(A_log[d * 16 + 2 * sp]) * L2E;
    const float aA1 = -__expf(A_log[d * 16 + 2 * sp + 1]) * L2E;
    const float Dpd = Dp[d];
    float h0 = 0.f, h1 = 0.f;

    float rdt[4], rxc[4];
    float rB0, rB1, rC0, rC1;
    ushort4 rz, zcur;

    // ---- prologue: load chunk 0 into registers ----
    {
        const size_t r0 = rbase;
#pragma unroll
        for (int j = 0; j < 4; ++j) {
            rdt[j] = bf2f(dtb[(r0 + stq * 4 + j) * 256 + d0 + sdd]);
            rxc[j] = bf2f(xcb[(r0 + stq * 4 + j) * 256 + d0 + sdd]);
        }
        rz  = *(const ushort4*)&xzb[(r0 + szt) * 512 + 256 + d0 + szi * 4];
        rB0 = bf2f(Bb[(r0 + sbt) * 16 + sbi]);
        rB1 = bf2f(Bb[(r0 + sbt + 16) * 16 + sbi]);
        rC0 = bf2f(Cb[(r0 + sbt) * 16 + sbi]);
        rC1 = bf2f(Cb[(r0 + sbt + 16) * 16 + sbi]);
    }
    zcur = rz;

    float* ygL = lds + 2 * 3456;

    for (int c = 0; c < NCH; ++c) {
        float* buf = lds + (c & 1) * 3456;
        // ---- commit staged registers to LDS (transposed fp32 tiles) ----
        *(float4*)&buf[sdd * 36 + stq * 4] =
            make_float4(rdt[0], rdt[1], rdt[2], rdt[3]);
        *(float4*)&buf[1152 + sdd * 36 + stq * 4] =
            make_float4(rxc[0], rxc[1], rxc[2], rxc[3]);
        buf[2304 + sbi * 36 + sbt]      = rB0;
        buf[2304 + sbi * 36 + sbt + 16] = rB1;
        buf[2880 + sbi * 36 + sbt]      = rC0;
        buf[2880 + sbi * 36 + sbt + 16] = rC1;
        zcur = rz;
        __syncthreads();

        // ---- prefetch chunk c+1 (lands during the 32 steps below) ----
        if (c + 1 < NCH) {
            const size_t r0 = rbase + (size_t)(c + 1) * SCH;
#pragma unroll
            for (int j = 0; j < 4; ++j) {
                rdt[j] = bf2f(dtb[(r0 + stq * 4 + j) * 256 + d0 + sdd]);
                rxc[j] = bf2f(xcb[(r0 + stq * 4 + j) * 256 + d0 + sdd]);
            }
            rz  = *(const ushort4*)&xzb[(r0 + szt) * 512 + 256 + d0 + szi * 4];
            rB0 = bf2f(Bb[(r0 + sbt) * 16 + sbi]);
            rB1 = bf2f(Bb[(r0 + sbt + 16) * 16 + sbi]);
            rC0 = bf2f(Cb[(r0 + sbt) * 16 + sbi]);
            rC1 = bf2f(Cb[(r0 + sbt + 16) * 16 + sbi]);
        }

        // ---- 32 scan steps from LDS ----
        const float* pdt = buf + dl * 36;
        const float* pxc = buf + 1152 + dl * 36;
        const float* pB0 = buf + 2304 + (2 * sp) * 36;
        const float* pB1 = buf + 2304 + (2 * sp + 1) * 36;
        const float* pC0 = buf + 2880 + (2 * sp) * 36;
        const float* pC1 = buf + 2880 + (2 * sp + 1) * 36;
        float yk[4] = {0.f, 0.f, 0.f, 0.f};
#pragma unroll
        for (int t4 = 0; t4 < 8; ++t4) {
            const float4 dt4 = *(const float4*)&pdt[t4 * 4];
            const float4 xc4 = *(const float4*)&pxc[t4 * 4];
            const float4 B04 = *(const float4*)&pB0[t4 * 4];
            const float4 B14 = *(const float4*)&pB1[t4 * 4];
            const float4 C04 = *(const float4*)&pC0[t4 * 4];
            const float4 C14 = *(const float4*)&pC1[t4 * 4];
#define SSTEP(J)                                                            \
            {                                                               \
                const float dt = ((const float*)&dt4)[J];                   \
                const float xc = ((const float*)&xc4)[J];                   \
                const float dtx = dt * xc;                                  \
                h0 = h0 * exp2_fast(dt * aA0) + dtx * ((const float*)&B04)[J]; \
                h1 = h1 * exp2_fast(dt * aA1) + dtx * ((const float*)&B14)[J]; \
                float yv = h0 * ((const float*)&C04)[J]                     \
                         + h1 * ((const float*)&C14)[J];                    \
                yv = dpp_add8(yv);                                          \
                yv = fmaf(xc, Dpd, yv);                                     \
                const int tt = t4 * 4 + (J);                                \
                yk[t4 >> 1] = (sp == (tt & 7)) ? yv : yk[t4 >> 1];          \
            }
            SSTEP(0) SSTEP(1) SSTEP(2) SSTEP(3)
#undef SSTEP
        }
        // stage captured y to LDS: lane sp holds t = 8k+sp for its d
#pragma unroll
        for (int k = 0; k < 4; ++k)
            ygL[(k * 8 + sp) * 36 + dl] = yk[k];
        __syncthreads();

        // ---- coalesced bf16 writeout with silu(z) from registers ----
        {
            const size_t rr0 = rbase + (size_t)c * SCH;
            float4 y4 = *(const float4*)&ygL[szt * 36 + szi * 4];
            float z0 = bf2f(zcur.x), z1 = bf2f(zcur.y);
            float z2 = bf2f(zcur.z), z3 = bf2f(zcur.w);
            float o0 = y4.x * (z0 / (1.f + __expf(-z0)));
            float o1 = y4.y * (z1 / (1.f + __expf(-z1)));
            float o2 = y4.z * (z2 / (1.f + __expf(-z2)));
            float o3 = y4.w * (z3 / (1.f + __expf(-z3)));
            uint2 packed;
            packed.x = cvt_pk_bf16(o0, o1);
            packed.y = cvt_pk_bf16(o2, o3);
            *(uint2*)&yg[(rr0 + szt) * 256 + d0 + szi * 4] = packed;
        }
    }
}

// --- add + BN1/BN2 (params per-thread; bf16 in, bf16 out, fp32 stats) ------
__global__ __launch_bounds__(256) void k_add(const unsigned short* __restrict__ h1p,
                                             const unsigned short* __restrict__ p2,
                                             const float* __restrict__ st,
                                             const float* __restrict__ g1,
                                             const float* __restrict__ be1,
                                             const float* __restrict__ g2,
                                             const float* __restrict__ be2,
                                             unsigned short* __restrict__ outp,
                                             float* __restrict__ sumP,
                                             float* __restrict__ sqP)
{
    const int c = threadIdx.x & 127, half = threadIdx.x >> 7;
    const float inv = 1.f / 32768.f;
    const float m1 = st[c] * inv, v1 = st[128 + c] * inv - m1 * m1;
    const float a1 = g1[c] * rsqrtf(v1 + 1e-5f), b1 = be1[c] - m1 * a1;
    const float m2 = st[256 + c] * inv, v2 = st[384 + c] * inv - m2 * m2;
    const float a2 = g2[c] * rsqrtf(v2 + 1e-5f), b2 = be2[c] - m2 * a2;

    const int rbase = blockIdx.x * 64 + half * 32;
    float s = 0.f, q = 0.f;
    for (int i = 0; i < 32; ++i) {
        size_t idx = (size_t)(rbase + i) * 128 + c;
        float v = bf2f(h1p[idx]) * a1 + b1 + bf2f(p2[idx]) * a2 + b2;
        outp[idx] = f2bf(v); s += v; q += v * v;
    }
    __shared__ float sh[2][2][128];
    sh[0][half][c] = s; sh[1][half][c] = q;
    __syncthreads();
    if (threadIdx.x < 128) {
        atomicAdd(&sumP[c], sh[0][0][c] + sh[0][1][c]);
        atomicAdd(&sqP[c],  sh[1][0][c] + sh[1][1][c]);
    }
}

// ---- fold1: block-per-column; W1eT bf16 [256][128] + b1e fp32 -------------
__global__ __launch_bounds__(128) void k_fold1(
    const float* __restrict__ sumP, const float* __restrict__ sqP,
    const float* __restrict__ gam, const float* __restrict__ bet,
    const float* __restrict__ W1, const float* __restrict__ b1in,
    unsigned short* __restrict__ W1eT, float* __restrict__ b1e)
{
    __shared__ float red[128];
    const int n = blockIdx.x, k = threadIdx.x;
    const float inv = 1.f / 32768.f;
    const float m = sumP[k] * inv, v = sqP[k] * inv - m * m;
    const float a = gam[k] * rsqrtf(v + 1e-5f), bs = bet[k] - m * a;
    const float wv = W1[k * 256 + n];
    W1eT[n * 128 + k] = f2bf(a * wv);
    red[k] = bs * wv;
    __syncthreads();
    for (int s = 64; s > 0; s >>= 1) {
        if (k < s) red[k] += red[k + s];
        __syncthreads();
    }
    if (k == 0) b1e[n] = red[0] + b1in[n];
}

// ---- fold2: block-per-column; W2eT bf16 [128][256] + b2e fp32 -------------
__global__ __launch_bounds__(256) void k_fold2(
    const float* __restrict__ sumP, const float* __restrict__ sqP,
    const float* __restrict__ gam, const float* __restrict__ bet,
    const float* __restrict__ W2, const float* __restrict__ b2in,
    unsigned short* __restrict__ W2eT, float* __restrict__ b2e)
{
    __shared__ float red[256];
    const int n = blockIdx.x, k = threadIdx.x;
    const float inv = 1.f / 32768.f;
    const float m = sumP[k] * inv, v = sqP[k] * inv - m * m;
    const float a = gam[k] * rsqrtf(v + 1e-5f), bs = bet[k] - m * a;
    const float wv = W2[k * 128 + n];
    W2eT[n * 256 + k] = f2bf(a * wv);
    red[k] = bs * wv;
    __syncthreads();
    for (int s = 128; s > 0; s >>= 1) {
        if (k < s) red[k] += red[k + s];
        __syncthreads();
    }
    if (k == 0) b2e[n] = red[0] + b2in[n];
}

// ------------- BN3 (params per-thread, amortized; bf16 input) ---------------
__global__ __launch_bounds__(256) void k_bn3(const unsigned short* __restrict__ out2,
                                             const float* __restrict__ sumP,
                                             const float* __restrict__ sqP,
                                             const float* __restrict__ gam,
                                             const float* __restrict__ bet,
                                             float* __restrict__ dout)
{
    const int cq = (threadIdx.x & 31) * 4;     // column quad
    const int rw = threadIdx.x >> 5;           // 0..7
    const float inv = 1.f / 32768.f;
    float a[4], b[4];
#pragma unroll
    for (int j = 0; j < 4; ++j) {
        float m = sumP[cq + j] * inv, v = sqP[cq + j] * inv - m * m;
        a[j] = gam[cq + j] * rsqrtf(v + 1e-5f);
        b[j] = bet[cq + j] - m * a[j];
    }
    const int r0 = blockIdx.x * 128 + rw;
#pragma unroll 4
    for (int k = 0; k < 16; ++k) {
        const size_t r = r0 + k * 8;
        ushort4 u = *(const ushort4*)&out2[r * 128 + cq];
        float4 v;
        v.x = bf2f(u.x) * a[0] + b[0]; v.y = bf2f(u.y) * a[1] + b[1];
        v.z = bf2f(u.z) * a[2] + b[2]; v.w = bf2f(u.w) * a[3] + b[3];
        *(float4*)&dout[r * 128 + cq] = v;
    }
}

// ------------------------------- launch ------------------------------------
extern "C" void kernel_launch(void* const* d_in, const int* in_sizes, int n_in,
                              void* d_out, int out_size, void* d_ws, size_t ws_size,
                              hipStream_t stream)
{
    (void)in_sizes; (void)n_in; (void)out_size; (void)ws_size;
    const float* x      = (const float*)d_in[0];
    const int*   ei     = (const int*)d_in[1];
    // d_in[2] = batch (unused: equal-size sorted graphs == reshape)
    const float* W_root = (const float*)d_in[3];
    const float* W_rel  = (const float*)d_in[4];
    const float* b_rel  = (const float*)d_in[5];
    const float* n1_g = (const float*)d_in[6],  *n1_b = (const float*)d_in[7];
    const float* n2_g = (const float*)d_in[8],  *n2_b = (const float*)d_in[9];
    const float* n3_g = (const float*)d_in[10], *n3_b = (const float*)d_in[11];
    const float* m1_g = (const float*)d_in[12], *m1_b = (const float*)d_in[13];
    const float* W1   = (const float*)d_in[14], *b1   = (const float*)d_in[15];
    const float* m2_g = (const float*)d_in[16], *m2_b = (const float*)d_in[17];
    const float* W2   = (const float*)d_in[18], *b2   = (const float*)d_in[19];
    const float* in_W   = (const float*)d_in[20];
    const float* conv_w = (const float*)d_in[21], *conv_b = (const float*)d_in[22];
    const float* xproj_W= (const float*)d_in[23];
    const float* dt_W   = (const float*)d_in[24], *dt_b = (const float*)d_in[25];
    const float* A_log  = (const float*)d_in[26], *Dp   = (const float*)d_in[27];
    const float* out_W  = (const float*)d_in[28];

    float* ws = (float*)d_ws;
    // small region
    float* st  = ws;             // 2048 used (S1..S5 sums/sumsqs)
    float* b1e = ws + 8192;      // 256
    float* b2e = ws + 8448;      // 128
    // bf16 transposed weights (shorts)
    unsigned short* wsh   = (unsigned short*)(ws + 8704);
    unsigned short* WrelT  = wsh;            // 128x128 = 16384
    unsigned short* WrootT = wsh + 16384;    // 16384
    unsigned short* inWT   = wsh + 32768;    // 512x128 = 65536
    unsigned short* xprojT = wsh + 98304;    // 40x256  = 10240
    unsigned short* outWT  = wsh + 108544;   // 128x256 = 32768
    unsigned short* W1eT   = wsh + 141312;   // 256x128 = 32768
    unsigned short* W2eT   = wsh + 174080;   // 128x256 = 32768 (end 206848)
    // big buffers (float-unit offsets; bf16 buffers occupy half the floats)
    float* big = ws + 112640;
    unsigned short* agg16 = (unsigned short*)(big);             // 4.19M sh
    unsigned short* p216  = agg16;                              // reuse
    unsigned short* h1p16 = (unsigned short*)(big + 2097152);   // 4.19M sh
    unsigned short* x16   = (unsigned short*)(big + 4194304);   // 4.19M sh
    unsigned short* xz16  = (unsigned short*)(big + 6291456);   // 16.78M sh
    unsigned short* xc16  = (unsigned short*)(big + 14680064);  // 8.39M sh
    float* proj = big + 18874368;                               // 1.31M f
    unsigned short* dtb16 = (unsigned short*)(big + 20185088);  // 8.39M sh (yg alias)
    unsigned short* yg16  = dtb16;
    unsigned short* Bc16  = (unsigned short*)(big + 24379392);  // 524288 sh
    unsigned short* Cc16  = (unsigned short*)(big + 24903680);  // 524288 sh
    unsigned short* outb16 = (unsigned short*)(big + 25427968); // 4.19M sh
    unsigned short* out216 = (unsigned short*)(big + 27525120); // 4.19M sh
    unsigned short* g16    = (unsigned short*)(big + 29622272); // 8.39M sh

    // CSR scratch lives in the h1p16 region (dead until the h1 GEMM writes it)
    int* ideg   = (int*)h1p16;            // 32768
    int* ibase  = ideg + 32768;           // 32769
    int* icur   = ideg + 65552;           // 32768 (16B-aligned)
    int* isrcs  = ideg + 98320;           // 524288

    hipMemsetAsync(st, 0, 2048 * sizeof(float), stream);
    hipMemsetAsync(ideg, 0, 32768 * sizeof(int), stream);

    // ---- merged prep: weight transposes | x->bf16 | degree histogram ----
    k_prep<<<3112, 256, 0, stream>>>(W_rel, WrelT, W_root, WrootT,
                                     in_W, inWT, xproj_W, xprojT,
                                     out_W, outWT, x, x16, ei, ideg);

    // ---- CSR build + gather (bf16, 8-deep ILP) ----
    k_scanidx<<<1, 1024, 0, stream>>>(ideg, ibase, icur);
    k_fill<<<512, 256, 0, stream>>>(ei, icur, isrcs);
    k_gather<<<8192, 256, 0, stream>>>(x16, ibase, isrcs, agg16);

    // h1_pre = agg@W_rel + b_rel + x@W_root + x  [S1]  (bf16 A/resid/out)
    gemm_mfma<true, 0, true, true, true><<<dim3(256, 2), 256, 0, stream>>>(
        agg16, WrelT, x16, WrootT, NROWS, 128, 128, 128,
        b_rel, x16, 128, h1p16, st + 0, st + 128);
    // xz = x @ in_W  (bf16 A, bf16 out)
    gemm_mfma<false, 0, false, true, false><<<dim3(256, 8), 256, 0, stream>>>(
        x16, inWT, nullptr, nullptr, NROWS, 512, 128, 512,
        nullptr, nullptr, 0, xz16, nullptr, nullptr);
    k_conv<<<16384, 256, 0, stream>>>(xz16, conv_w, conv_b, xc16);
    // proj = xc @ xproj_W (bf16 A, fp32 out, N=40)
    gemm_mfma<false, 0, false, false, false><<<dim3(256, 1), 256, 0, stream>>>(
        xc16, xprojT, nullptr, nullptr, NROWS, 40, 256, 40,
        nullptr, nullptr, 0, proj, nullptr, nullptr);
    k_dtbc<<<1024, 256, 0, stream>>>(proj, dt_W, dt_b, dtb16, Bc16, Cc16);
    k_scan<<<512, 256, 0, stream>>>(dtb16, xc16, xz16, Bc16, Cc16, A_log, Dp, yg16);
    // p2 = yg @ out_W + x  [S2]  (bf16 A/resid/out)
    gemm_mfma<false, 0, true, true, true><<<dim3(256, 2), 256, 0, stream>>>(
        yg16, outWT, nullptr, nullptr, NROWS, 128, 256, 128,
        nullptr, x16, 128, p216, st + 256, st + 384);
    // out = BN1(h1_pre) + BN2(p2)  [S3]  (bf16 out)
    k_add<<<512, 256, 0, stream>>>(h1p16, p216, st, n1_g, n1_b, n2_g, n2_b,
                                   outb16, st + 512, st + 640);
    k_fold1<<<256, 128, 0, stream>>>(st + 512, st + 640, m1_g, m1_b, W1, b1, W1eT, b1e);
    // g = gelu(out @ W1e + b1e)  [S4]  (bf16 A, bf16 out)
    gemm_mfma<false, 1, true, true, false><<<dim3(256, 4), 256, 0, stream>>>(
        outb16, W1eT, nullptr, nullptr, NROWS, 256, 128, 256,
        b1e, nullptr, 0, g16, st + 768, st + 1024);
    k_fold2<<<128, 256, 0, stream>>>(st + 768, st + 1024, m2_g, m2_b, W2, b2, W2eT, b2e);
    // out2 = g @ W2e + b2e + out  [S5]  (bf16 A/resid, bf16 out)
    gemm_mfma<false, 0, true, true, true><<<dim3(256, 2), 256, 0, stream>>>(
        g16, W2eT, nullptr, nullptr, NROWS, 128, 256, 128,
        b2e, outb16, 128, out216, st + 1280, st + 1408);
    // d_out = BN3(out2)  (params computed in-kernel from S5)
    k_bn3<<<256, 256, 0, stream>>>(out216, st + 1280, st + 1408, n3_g, n3_b,
                                   (float*)d_out);
}